// Round 14
// baseline (293.596 us; speedup 1.0000x reference)
//
#include <hip/hip_runtime.h>
#include <math.h>

// ============================================================================
// CausalAttention (B=2, T=2048, C=2048, H=16, D=128) with ALiBi.
// Round 28: QK projection moved to an 8-phase 256^2 BK=64 schedule (m201
// class). Phases = 2 K-tiles x 4 cooperative 128x128 C-quadrants (all 8
// waves per quadrant) -> LDS half-tiles are PHASE-disjoint, so each half
// frees mid-iteration and its successor stages into the window: counted
// vmcnt (8/6/6/6 at phase 0/1/4/5 boundaries, never 0; last iter 4->0).
// Swizzle slot^=(row&7) on pre-swizzled source + ds_read (both sides).
// Epilogue = verified MODE3 scatter. V^T/o@Wo keep gemm256x128 (their
// 8-phase grids would be 128 blocks = half machine). attn = r27 (pair ILP).
// r27 = 279.6us best (QK 84.5 @ 34% MfmaUtil, attn <84).
// ============================================================================

typedef unsigned short u16;
using bf16x8 = __attribute__((ext_vector_type(8))) short;
using f32x4  = __attribute__((ext_vector_type(4))) float;

__device__ __forceinline__ u16 f2bf(float f) {
  union { float f; unsigned u; } c; c.f = f;
  unsigned r = c.u + 0x7fffu + ((c.u >> 16) & 1u);   // RTN-even
  return (u16)(r >> 16);
}
__device__ __forceinline__ float bf2f(u16 b) {
  union { unsigned u; float f; } c; c.u = ((unsigned)b) << 16; return c.f;
}
__device__ __forceinline__ unsigned cvtpk(float a, float b) {
  unsigned r;
  asm("v_cvt_pk_bf16_f32 %0, %1, %2" : "=v"(r) : "v"(a), "v"(b));
  return r;
}
__device__ __forceinline__ void g2l16(const void* g, void* l) {
  __builtin_amdgcn_global_load_lds(
      (const __attribute__((address_space(1))) void*)g,
      (__attribute__((address_space(3))) void*)l, 16, 0, 0);
}

// band: drop tiles whose every column is > dist below the strip's first row
__device__ __forceinline__ int band_jmin(int s, float slope2) {
  const int idist = (int)(36.0f / slope2);
  const int cut = 64 * s - idist - 31;
  return (cut > 0) ? (cut >> 5) : 0;
}

// heaviest-first unit order: units sorted by serial tile count descending.
__device__ const unsigned char uord[48] = {
  15, 16, 32, 17, 33, 14, 18, 34, 19, 35,
  13, 20, 36, 21, 37, 12, 22, 38, 23, 39,
  11, 24, 40, 25, 41, 10, 26, 42, 27, 43,
   9, 28, 44, 29, 45,  8, 30, 46, 31, 47,
   7,  6,  5,  4,  3,  2,  1,  0};

// ---------------------------------------------------------------------------
// f32 -> bf16 cast, vectorized
// ---------------------------------------------------------------------------
__global__ __launch_bounds__(256) void split_f32(const float* __restrict__ in,
                                                 u16* __restrict__ hi, int n4) {
  for (int i = blockIdx.x * 256 + threadIdx.x; i < n4; i += gridDim.x * 256) {
    const float4 v = ((const float4*)in)[i];
    ushort4 h;
    h.x = f2bf(v.x); h.y = f2bf(v.y); h.z = f2bf(v.z); h.w = f2bf(v.w);
    ((ushort4*)hi)[i] = h;
  }
}

// ---------------------------------------------------------------------------
// Fused transpose + scale + cast for all 4 weights: z selects the matrix.
// ---------------------------------------------------------------------------
__global__ __launch_bounds__(256) void tsplit4_f32(
    const float* __restrict__ W0, const float* __restrict__ W1,
    const float* __restrict__ W2, const float* __restrict__ W3,
    u16* __restrict__ D0, u16* __restrict__ D1,
    u16* __restrict__ D2, u16* __restrict__ D3,
    int N, int K, float sc0) {
  __shared__ float tile[64][68];
  const int z = blockIdx.z;
  const float* W = (z == 0) ? W0 : (z == 1) ? W1 : (z == 2) ? W2 : W3;
  u16* Wth = (z == 0) ? D0 : (z == 1) ? D1 : (z == 2) ? D2 : D3;
  const float sc = (z == 0) ? sc0 : 1.f;
  const int tid = threadIdx.x;
  const int k0 = blockIdx.y * 64, n0 = blockIdx.x * 64;
  const int rr = tid >> 4, cc = (tid & 15) * 4;
#pragma unroll
  for (int u = 0; u < 4; ++u) {
    const float4 v = *(const float4*)&W[(size_t)(k0 + rr + 16 * u) * N + n0 + cc];
    tile[rr + 16 * u][cc + 0] = v.x;
    tile[rr + 16 * u][cc + 1] = v.y;
    tile[rr + 16 * u][cc + 2] = v.z;
    tile[rr + 16 * u][cc + 3] = v.w;
  }
  __syncthreads();
#pragma unroll
  for (int u = 0; u < 4; ++u) {
    const int nn = rr + 16 * u;
    ushort4 h;
    h.x = f2bf(tile[cc + 0][nn] * sc);
    h.y = f2bf(tile[cc + 1][nn] * sc);
    h.z = f2bf(tile[cc + 2][nn] * sc);
    h.w = f2bf(tile[cc + 3][nn] * sc);
    *(ushort4*)&Wth[(size_t)(n0 + nn) * K + k0 + cc] = h;
  }
}

// ---------------------------------------------------------------------------
// 8-phase 256x256 bf16 GEMM, BK=64, for the merged QK projection (MODE3).
// 8 waves as 2x4 within each cooperative 128x128 C-quadrant; phases =
// (K-tile kk, quadrant qm,qn). LDS [dbuf][half][128][64] per operand, 128KB.
// ---------------------------------------------------------------------------
__global__ __launch_bounds__(512) void gemm8p_qk(
    const u16* __restrict__ Ah, const u16* __restrict__ Bth,
    const float* __restrict__ bq, const float* __restrict__ bk,
    float bsc, u16* __restrict__ qh, u16* __restrict__ kh,
    int MM, int NN, int KK) {
  __shared__ u16 LA[2][2][8192];   // [dbuf][half][128 rows x 64 K]
  __shared__ u16 LB[2][2][8192];

  const int tid = threadIdx.x;
  const int wave = tid >> 6, lane = tid & 63;
  const int g = lane >> 4, q15 = lane & 15;
  const int wr = wave >> 2, wc = wave & 3;   // 2M x 4N inside a quadrant
  const int m0 = blockIdx.y * 256, n0 = blockIdx.x * 256;
  const int NT = KK >> 6;                    // 64-wide K tiles (even)
  const int NI = NT >> 1;

  f32x4 acc[8][4];
#pragma unroll
  for (int a = 0; a < 8; ++a)
#pragma unroll
    for (int b = 0; b < 4; ++b) acc[a][b] = (f32x4){0.f, 0.f, 0.f, 0.f};

  // stage one 16KB half-tile (128 rows x 64 K): 2 g2l16/thread, linear LDS
  // dest; global source pre-swizzled with slot ^= (row&7).
  auto stageA = [&](int t, int h) {
#pragma unroll
    for (int l = 0; l < 2; ++l) {
      const int ch = l * 512 + tid;
      const int row = ch >> 3, slot = ch & 7;
      const size_t ga = (size_t)(m0 + h * 128 + row) * KK + t * 64 +
                        ((slot ^ (row & 7)) * 8);
      g2l16(Ah + ga, (char*)(LA[t & 1][h]) + ch * 16);
    }
  };
  auto stageB = [&](int t, int h) {
#pragma unroll
    for (int l = 0; l < 2; ++l) {
      const int ch = l * 512 + tid;
      const int row = ch >> 3, slot = ch & 7;
      const size_t gb = (size_t)(n0 + h * 128 + row) * KK + t * 64 +
                        ((slot ^ (row & 7)) * 8);
      g2l16(Bth + gb, (char*)(LB[t & 1][h]) + ch * 16);
    }
  };

#define QK_PHASE(D, QM, QN, STAGE_STMT, WAIT_STMT)                          \
  {                                                                         \
    bf16x8 af[4][2], bf[2][2];                                              \
    _Pragma("unroll")                                                       \
    for (int f = 0; f < 4; ++f) {                                           \
      const int lr = wr * 64 + f * 16 + q15;                                \
      _Pragma("unroll")                                                     \
      for (int ks = 0; ks < 2; ++ks)                                        \
        af[f][ks] = *(const bf16x8*)((const char*)(LA[D][QM]) +             \
                     lr * 128 + (((ks * 4 + g) ^ (lr & 7)) * 16));          \
    }                                                                       \
    _Pragma("unroll")                                                       \
    for (int j = 0; j < 2; ++j) {                                           \
      const int lr = wc * 32 + j * 16 + q15;                                \
      _Pragma("unroll")                                                     \
      for (int ks = 0; ks < 2; ++ks)                                        \
        bf[j][ks] = *(const bf16x8*)((const char*)(LB[D][QN]) +             \
                     lr * 128 + (((ks * 4 + g) ^ (lr & 7)) * 16));          \
    }                                                                       \
    STAGE_STMT;                                                             \
    __builtin_amdgcn_sched_barrier(0);                                      \
    __builtin_amdgcn_s_barrier();                                           \
    asm volatile("s_waitcnt lgkmcnt(0)" ::: "memory");                      \
    __builtin_amdgcn_sched_barrier(0);                                      \
    __builtin_amdgcn_s_setprio(1);                                          \
    _Pragma("unroll")                                                       \
    for (int f = 0; f < 4; ++f)                                             \
      _Pragma("unroll")                                                     \
      for (int j = 0; j < 2; ++j)                                           \
        _Pragma("unroll")                                                   \
        for (int ks = 0; ks < 2; ++ks)                                      \
          acc[(QM) * 4 + f][(QN) * 2 + j] =                                 \
              __builtin_amdgcn_mfma_f32_16x16x32_bf16(                      \
                  af[f][ks], bf[j][ks], acc[(QM) * 4 + f][(QN) * 2 + j],    \
                  0, 0, 0);                                                 \
    __builtin_amdgcn_s_setprio(0);                                          \
    WAIT_STMT;                                                              \
    __builtin_amdgcn_sched_barrier(0);                                      \
    __builtin_amdgcn_s_barrier();                                           \
  }

  // prologue: Ah0(0),Bh0(0),Ah1(0),Bh1(0),Ah0(1),Bh0(1) = 12 loads;
  // drain the first two halves (tile0 A-h0,B-h0) -> vmcnt(8).
  stageA(0, 0); stageB(0, 0);
  __builtin_amdgcn_sched_barrier(0);
  stageA(0, 1); stageB(0, 1);
  __builtin_amdgcn_sched_barrier(0);
  stageA(1, 0); stageB(1, 0);
  __builtin_amdgcn_sched_barrier(0);
  asm volatile("s_waitcnt vmcnt(8)" ::: "memory");
  __builtin_amdgcn_sched_barrier(0);
  __builtin_amdgcn_s_barrier();

  for (int i = 0; i < NI; ++i) {
    const int t0 = 2 * i, t1 = t0 + 1;
    const bool lastI = (i == NI - 1);

    // ph0: tile t0 (dbuf0), quadrant (0,0); stage Ah1(t1); closing vmcnt(6)
    QK_PHASE(0, 0, 0, { stageA(t1, 1); },
             { asm volatile("s_waitcnt vmcnt(6)" ::: "memory"); });
    // ph1: (0,1); stage Bh1(t1); no closing wait
    QK_PHASE(0, 0, 1, { stageB(t1, 1); }, {});
    // ph2: (1,0); stage Ah0(t0+2)
    QK_PHASE(0, 1, 0, { if (!lastI) stageA(t0 + 2, 0); }, {});
    // ph3: (1,1); stage Bh0(t0+2); closing vmcnt(6) (last iter: 4)
    QK_PHASE(0, 1, 1, { if (!lastI) stageB(t0 + 2, 0); },
             {
               if (lastI) { asm volatile("s_waitcnt vmcnt(4)" ::: "memory"); }
               else       { asm volatile("s_waitcnt vmcnt(6)" ::: "memory"); }
             });
    // ph4: tile t1 (dbuf1), (0,0); stage Ah1(t0+2); closing vmcnt(6) (last: 0)
    QK_PHASE(1, 0, 0, { if (!lastI) stageA(t0 + 2, 1); },
             {
               if (lastI) { asm volatile("s_waitcnt vmcnt(0)" ::: "memory"); }
               else       { asm volatile("s_waitcnt vmcnt(6)" ::: "memory"); }
             });
    // ph5: (0,1); stage Bh1(t0+2)
    QK_PHASE(1, 0, 1, { if (!lastI) stageB(t0 + 2, 1); }, {});
    // ph6: (1,0); stage Ah0(t0+3)
    QK_PHASE(1, 1, 0, { if (t0 + 3 < NT) stageA(t0 + 3, 0); }, {});
    // ph7: (1,1); stage Bh0(t0+3); closing vmcnt(8) (drains next ph0's halves)
    QK_PHASE(1, 1, 1, { if (t0 + 3 < NT) stageB(t0 + 3, 0); },
             {
               if (!lastI) { asm volatile("s_waitcnt vmcnt(8)" ::: "memory"); }
             });
  }
#undef QK_PHASE

  // epilogue: MODE3 merged-QK scatter (verified mapping).
#pragma unroll
  for (int ai = 0; ai < 8; ++ai)
#pragma unroll
    for (int bj = 0; bj < 4; ++bj)
#pragma unroll
      for (int r = 0; r < 4; ++r) {
        const int row = m0 + (ai >> 2) * 128 + wr * 64 + (ai & 3) * 16 + g * 4 + r;
        const int col = n0 + (bj >> 1) * 128 + wc * 32 + (bj & 1) * 16 + q15;
        const float v = acc[ai][bj][r];
        const int sel = col >> 11;
        const int c2 = col & 2047;
        const float vv = v + (sel ? bk[c2] : bq[c2] * bsc);
        const int bb = row >> 11, tt = row & 2047;
        const int hh = c2 >> 7, dd = c2 & 127;
        (sel ? kh : qh)[(((size_t)bb * 16 + hh) * 2048 + tt) * 128 + dd] =
            f2bf(vv);
      }
}

// ---------------------------------------------------------------------------
// 256x128-tile bf16 GEMM, BK=32, ring-3 LDS, counted vmcnt (r18 proven).
// MODE 0: f32 out (+bias[col]*bsc); MODE 2: bf16 out (+bias[row]*bsc).
// ---------------------------------------------------------------------------
template <int MODE>
__global__ __launch_bounds__(512, 4) void gemm256x128(
    const u16* __restrict__ Ah, const u16* __restrict__ Bth,
    const float* __restrict__ bias, const float* __restrict__ bias2,
    float bsc, u16* __restrict__ outH, u16* __restrict__ outH2,
    float* __restrict__ outF, int MM, int NN, int KK) {
  __shared__ u16 LA[3][8192];   // ring: 256 rows x 32 (64B rows)
  __shared__ u16 LB[3][4096];   // ring: 128 rows x 32

  const int tid = threadIdx.x;
  const int wave = tid >> 6, lane = tid & 63;
  const int g = lane >> 4, q15 = lane & 15;
  const int wr = wave >> 1, wc = wave & 1;     // 4M x 2N
  const int m0 = blockIdx.y * 256, n0 = blockIdx.x * 128;
  const int NT = KK >> 5;
  const int sxg = ((g ^ ((q15 >> 1) & 3)) << 4);

  f32x4 acc[4][4];
#pragma unroll
  for (int f = 0; f < 4; ++f)
#pragma unroll
    for (int j = 0; j < 4; ++j) acc[f][j] = (f32x4){0.f, 0.f, 0.f, 0.f};

  auto stageA = [&](int t, int rbuf) {
#pragma unroll
    for (int l = 0; l < 2; ++l) {
      const int ch = l * 512 + tid;
      const int row = ch >> 2, slot = ch & 3;
      const size_t ga = (size_t)(m0 + row) * KK + t * 32 +
                        ((slot ^ ((row >> 1) & 3)) * 8);
      g2l16(Ah + ga, (char*)(LA[rbuf]) + ch * 16);
    }
  };
  auto stageB = [&](int t, int rbuf) {
    const int ch = tid;
    const int row = ch >> 2, slot = ch & 3;
    const size_t gb = (size_t)(n0 + row) * KK + t * 32 +
                      ((slot ^ ((row >> 1) & 3)) * 8);
    g2l16(Bth + gb, (char*)(LB[rbuf]) + ch * 16);
  };

  // prologue: stage tiles 0,1 (6 ops/thread), drain tile 0 only
  stageA(0, 0); stageB(0, 0);
  __builtin_amdgcn_sched_barrier(0);
  if (NT > 1) { stageA(1, 1); stageB(1, 1); }
  __builtin_amdgcn_sched_barrier(0);
  if (NT > 1) { asm volatile("s_waitcnt vmcnt(3)" ::: "memory"); }
  else        { asm volatile("s_waitcnt vmcnt(0)" ::: "memory"); }
  __builtin_amdgcn_sched_barrier(0);
  __builtin_amdgcn_s_barrier();

  int rb = 0, rb2 = 2;
  for (int t = 0; t < NT; ++t) {
    const char* baseA = (const char*)(LA[rb]);
    const char* baseB = (const char*)(LB[rb]);

    bf16x8 af[4], bf[4];
#pragma unroll
    for (int f = 0; f < 4; ++f)
      af[f] = *(const bf16x8*)(baseA + (wr * 64 + f * 16 + q15) * 64 + sxg);
#pragma unroll
    for (int j = 0; j < 4; ++j)
      bf[j] = *(const bf16x8*)(baseB + (wc * 64 + j * 16 + q15) * 64 + sxg);
    if (t + 2 < NT) { stageA(t + 2, rb2); stageB(t + 2, rb2); }
    __builtin_amdgcn_sched_barrier(0);
    __builtin_amdgcn_s_barrier();
    asm volatile("s_waitcnt lgkmcnt(0)" ::: "memory");
    __builtin_amdgcn_sched_barrier(0);
    __builtin_amdgcn_s_setprio(1);
#pragma unroll
    for (int f = 0; f < 4; ++f)
#pragma unroll
      for (int j = 0; j < 4; ++j)
        acc[f][j] = __builtin_amdgcn_mfma_f32_16x16x32_bf16(
            af[f], bf[j], acc[f][j], 0, 0, 0);
    __builtin_amdgcn_s_setprio(0);
    if (t + 1 < NT) {
      if (t + 2 < NT) { asm volatile("s_waitcnt vmcnt(3)" ::: "memory"); }
      else            { asm volatile("s_waitcnt vmcnt(0)" ::: "memory"); }
    }
    __builtin_amdgcn_sched_barrier(0);
    __builtin_amdgcn_s_barrier();
    rb  = (rb  == 2) ? 0 : rb  + 1;
    rb2 = (rb2 == 2) ? 0 : rb2 + 1;
  }

#pragma unroll
  for (int f = 0; f < 4; ++f)
#pragma unroll
    for (int j = 0; j < 4; ++j)
#pragma unroll
      for (int r = 0; r < 4; ++r) {
        const int row = m0 + wr * 64 + f * 16 + g * 4 + r;
        const int col = n0 + wc * 64 + j * 16 + q15;
        const float v = acc[f][j][r];
        if (MODE == 0) {
          outF[(size_t)row * NN + col] = v + bias[col] * bsc;
        } else if (MODE == 2) {
          outH[(size_t)row * NN + col] = f2bf(v + bias[row] * bsc);
        }
      }
}

// ---------------------------------------------------------------------------
// Banded split-K flash attention with ALiBi. r27: tile-pair ILP on top of
// the r24/r26 structure (1-wave blocks, XCD-pair decode, uord, setprio,
// K LDS ring-3, V reg-dbuf, counted vmcnt).
// ---------------------------------------------------------------------------
__global__ __launch_bounds__(64) void attn_splitk(
    const u16* __restrict__ Qh, const u16* __restrict__ Kh,
    const u16* __restrict__ Vth, u16* __restrict__ Oh,
    float* __restrict__ Obuf, float* __restrict__ mArr,
    float* __restrict__ lArr, int T, int NB, int BH) {
  __shared__ u16 KS[3][4096];   // 32 x 128, 256B rows, XOR ((row&7)<<4)

  const int tid = threadIdx.x;
  const int lane = tid & 63;
  const int g = lane >> 4, q15 = lane & 15;
  const int L = blockIdx.x;
  // XCD-co-located pair decode: halves are (L, L+8) -> same XCD (mod 8)
  const int LL = (L & 7) | ((L >> 4) << 3);
  const int wid = (L >> 3) & 1;

  int bh, u;
  if (BH == 32) {
    const int k = LL >> 8;       // round 0..5
    const int c = LL & 255;      // CU-slot within round
    bh = (c + 5 * k) & 31;
    u = uord[k * 8 + (c >> 5)];
  } else {
    bh = LL / 48;
    u = uord[LL % 48];
  }
  int s, half;
  if (u < 16)      { s = u;      half = 2; }   // full strip
  else if (u < 32) { s = 47 - u; half = 0; }   // low half (no diagonal)
  else             { s = 63 - u; half = 1; }   // high half (diagonal)

  const int b = bh >> 4, h = bh & 15;
  const float slope2 = exp2f(-0.5f * (float)(h + 1)) * 1.44269504f;
  const int jmin = band_jmin(s, slope2);
  const bool loEmpty = (jmin >= s + 1);

  if (half == 0 && loEmpty) return;            // nothing to do

  int lo, hi;
  if (half == 2)      { lo = jmin;                hi = 2 * s + 2; }
  else if (half == 0) { lo = jmin;                hi = s + 1; }
  else                { lo = loEmpty ? jmin : (s + 1); hi = 2 * s + 2; }
  const int ns = hi - lo;                      // >= 1
  const bool maskable = (half != 0);
  const bool normStore = (half == 2) || (half == 1 && loEmpty);

  const int qw0 = s * 64 + wid * 32;
  const size_t vrow0 = (size_t)h * 128;
  const size_t vcol0 = (size_t)b * T;
  const size_t kbase = (size_t)bh * T;

  // ---- Q loads (8 globals, issued first / oldest in vmcnt order) ----
  bf16x8 qfr[2][4];
#pragma unroll
  for (int qf2 = 0; qf2 < 2; ++qf2) {
    const size_t rb = ((size_t)bh * T + qw0 + qf2 * 16 + q15) * 128;
#pragma unroll
    for (int ks = 0; ks < 4; ++ks)
      qfr[qf2][ks] = *(const bf16x8*)&Qh[rb + ks * 32 + g * 8];
  }

  f32x4 oacc[2][8];
#pragma unroll
  for (int a = 0; a < 2; ++a)
#pragma unroll
    for (int n = 0; n < 8; ++n) oacc[a][n] = (f32x4){0.f, 0.f, 0.f, 0.f};
  float m_st[2] = {-1e5f, -1e5f};
  float l_part[2] = {0.f, 0.f};

  // stage one 32x128 K tile (8KB = 8 chunks of 1KB), all by this wave
  auto stageK = [&](int jt, int bf) {
    const int j0 = jt * 32;
#pragma unroll
    for (int c = 0; c < 8; ++c) {
      const int row = c * 4 + g;
      const int off = (q15 * 16) ^ ((row & 7) << 4);
      const size_t gb = (kbase + j0 + row) * 128;
      g2l16((const char*)(Kh + gb) + off, (char*)(KS[bf]) + c * 1024);
    }
  };
  auto loadV = [&](int jt, bf16x8 (&vf)[8]) {
    const int j0 = jt * 32;
#pragma unroll
    for (int nf = 0; nf < 8; ++nf)
      vf[nf] = *(const bf16x8*)
          &Vth[(vrow0 + nf * 16 + q15) * (size_t)NB + vcol0 + j0 + g * 8];
  };
  // QK^T for one tile from KS[slot] into sacc
  auto QKT = [&](int slot, f32x4 (&sacc)[2][2]) {
#pragma unroll
    for (int jf = 0; jf < 2; ++jf)
#pragma unroll
      for (int qf2 = 0; qf2 < 2; ++qf2) sacc[jf][qf2] = (f32x4){0.f, 0.f, 0.f, 0.f};
#pragma unroll
    for (int ks = 0; ks < 4; ++ks) {
      bf16x8 ka[2];
#pragma unroll
      for (int jf = 0; jf < 2; ++jf) {
        const int row = jf * 16 + q15;
        const int off = (row * 256 + ks * 64 + g * 16) ^ ((row & 7) << 4);
        ka[jf] = *(const bf16x8*)((const char*)(KS[slot]) + off);
      }
#pragma unroll
      for (int jf = 0; jf < 2; ++jf)
#pragma unroll
        for (int qf2 = 0; qf2 < 2; ++qf2)
          sacc[jf][qf2] = __builtin_amdgcn_mfma_f32_16x16x32_bf16(
              ka[jf], qfr[qf2][ks], sacc[jf][qf2], 0, 0, 0);
    }
  };
  // softmax + PV for one tile (no internal waits; V must be drained)
  auto SOFTPV = [&](int it, int j0, f32x4 (&sacc)[2][2], bf16x8 (&vc)[8]) {
    const float jb2 = (float)(j0 + 4 * g - (T - 1));
    unsigned Fw[2][4];
#pragma unroll
    for (int qf2 = 0; qf2 < 2; ++qf2) {
      const int qg = qw0 + qf2 * 16 + q15;
      float sv[2][4];
      float mt = -1e30f;
#pragma unroll
      for (int jf = 0; jf < 2; ++jf)
#pragma unroll
        for (int r = 0; r < 4; ++r) {
          float x = fmaf(slope2, jb2 + (float)(jf * 16 + r), sacc[jf][qf2][r]);
          if (maskable && it < 2) {
            const int jg = j0 + jf * 16 + 4 * g + r;
            x = (jg > qg) ? -1e30f : x;
          }
          sv[jf][r] = x;
          mt = fmaxf(mt, x);
        }
      if (!__all(mt <= m_st[qf2] + 11.0f)) {
        mt = fmaxf(mt, __shfl_xor(mt, 16));
        mt = fmaxf(mt, __shfl_xor(mt, 32));
        const float mnew = fmaxf(m_st[qf2], mt);
        const float scl = exp2f(m_st[qf2] - mnew);
        l_part[qf2] *= scl;
        m_st[qf2] = mnew;
#pragma unroll
        for (int r = 0; r < 4; ++r) {
          const float sc = __shfl(scl, g * 4 + r);
#pragma unroll
          for (int nf = 0; nf < 8; ++nf) oacc[qf2][nf][r] *= sc;
        }
      }
      float rs = 0.f;
      float p[2][4];
#pragma unroll
      for (int jf = 0; jf < 2; ++jf)
#pragma unroll
        for (int r = 0; r < 4; ++r) {
          p[jf][r] = exp2f(sv[jf][r] - m_st[qf2]);
          rs += p[jf][r];
        }
      l_part[qf2] += rs;
      const unsigned W00 = cvtpk(p[0][0], p[0][1]), W01 = cvtpk(p[0][2], p[0][3]);
      const unsigned W10 = cvtpk(p[1][0], p[1][1]), W11 = cvtpk(p[1][2], p[1][3]);
      const int srcA = q15 + ((g & 1) << 5);
      const int srcB = srcA + 16;
      const unsigned A0 = (unsigned)__shfl((int)W00, srcA);
      const unsigned A1 = (unsigned)__shfl((int)W01, srcA);
      const unsigned B0 = (unsigned)__shfl((int)W00, srcB);
      const unsigned B1 = (unsigned)__shfl((int)W01, srcB);
      const unsigned C0 = (unsigned)__shfl((int)W10, srcA);
      const unsigned C1 = (unsigned)__shfl((int)W11, srcA);
      const unsigned D0 = (unsigned)__shfl((int)W10, srcB);
      const unsigned D1 = (unsigned)__shfl((int)W11, srcB);
      const bool hi2 = g >= 2;
      Fw[qf2][0] = hi2 ? C0 : A0;
      Fw[qf2][1] = hi2 ? C1 : A1;
      Fw[qf2][2] = hi2 ? D0 : B0;
      Fw[qf2][3] = hi2 ? D1 : B1;
    }
    union { unsigned uu[4]; bf16x8 v; } pa0, pa1;
#pragma unroll
    for (int w = 0; w < 4; ++w) { pa0.uu[w] = Fw[0][w]; pa1.uu[w] = Fw[1][w]; }
    __builtin_amdgcn_s_setprio(1);
#pragma unroll
    for (int nf = 0; nf < 8; ++nf) {
      oacc[0][nf] = __builtin_amdgcn_mfma_f32_16x16x32_bf16(pa0.v, vc[nf], oacc[0][nf], 0, 0, 0);
      oacc[1][nf] = __builtin_amdgcn_mfma_f32_16x16x32_bf16(pa1.v, vc[nf], oacc[1][nf], 0, 0, 0);
    }
    __builtin_amdgcn_s_setprio(0);
  };

  // ---- prologue: pinned issue order [Q][K0,K1][V0] ----
  bf16x8 vfA[8], vfB[8];
  __builtin_amdgcn_sched_barrier(0);
  stageK(hi - 1, 0);
  if (ns > 1) stageK(hi - 2, 1);
  __builtin_amdgcn_sched_barrier(0);
  loadV(hi - 1, vfA);
  // outstanding: ns>1: Q(8)+K0(8)+K1(8)+V0(8)=32 -> vmcnt(16) drains Q,K0
  //              ns==1: Q(8)+K0(8)+V0(8)=24      -> vmcnt(8)  drains Q,K0
  if (ns > 1) { asm volatile("s_waitcnt vmcnt(16)" ::: "memory"); }
  else        { asm volatile("s_waitcnt vmcnt(8)"  ::: "memory"); }
  __builtin_amdgcn_sched_barrier(0);

  int cur = 0;   // slot of tile it: it % 3

  int it = 0;
  while (it + 2 <= ns) {
    // ---- pair (t0=it, t1=it+1); entry: vfA=V(t0); outstanding {V(t0),K(t0+1)}
    const int jt0 = hi - 1 - it, jt1 = jt0 - 1;
    const int j0a = jt0 * 32, j0b = jt1 * 32;
    const int cur1 = (cur == 2) ? 0 : cur + 1;
    const int cur2 = (cur1 == 2) ? 0 : cur1 + 1;
    const bool e2 = (it + 2 < ns);
    const bool e3 = (it + 3 < ns);

    // sub0 issues: V(t1)->vfB [8], K(t0+2)->cur2 [8 if e2]
    loadV(jt1, vfB);
    if (e2) stageK(jt0 - 2, cur2);
    __builtin_amdgcn_sched_barrier(0);
    if (e2) { asm volatile("s_waitcnt vmcnt(16)" ::: "memory"); }
    else    { asm volatile("s_waitcnt vmcnt(8)"  ::: "memory"); }
    __builtin_amdgcn_sched_barrier(0);

    // QK for BOTH tiles: QK(t1) MFMAs drain under SM(t0)'s VALU below.
    f32x4 sacc0[2][2], sacc1[2][2];
    __builtin_amdgcn_s_setprio(1);
    QKT(cur, sacc0);
    QKT(cur1, sacc1);
    __builtin_amdgcn_s_setprio(0);

    SOFTPV(it, j0a, sacc0, vfA);       // uses V(t0) (drained)

    // sub1 issues (after PV(t0) consumed vfA): V(t0+2)->vfA, K(t0+3)->cur
    if (e2) loadV(jt0 - 2, vfA);
    if (e3) stageK(jt0 - 3, cur);
    __builtin_amdgcn_sched_barrier(0);
    if (e2 && e3)      { asm volatile("s_waitcnt vmcnt(16)" ::: "memory"); }
    else if (e2)       { asm volatile("s_waitcnt vmcnt(8)"  ::: "memory"); }
    else               { asm volatile("s_waitcnt vmcnt(0)"  ::: "memory"); }
    __builtin_amdgcn_sched_barrier(0);

    SOFTPV(it + 1, j0b, sacc1, vfB);   // uses V(t1) (drained)

    cur = cur2;  // cur advanced by 2 (mod 3)
    it += 2;
  }
  if (it < ns) {
    // singleton tail: outstanding {V(it)} (or V0 for ns==1); no prefetch
    const int jt = hi - 1 - it;
    asm volatile("s_waitcnt vmcnt(0)" ::: "memory");
    __builtin_amdgcn_sched_barrier(0);
    f32x4 sacc0[2][2];
    __builtin_amdgcn_s_setprio(1);
    QKT(cur, sacc0);
    __builtin_amdgcn_s_setprio(0);
    SOFTPV(it, jt * 32, sacc0, vfA);
  }

  // ---- epilogue ----
  float lrow[2];
#pragma unroll
  for (int qf2 = 0; qf2 < 2; ++qf2) {
    float lr = l_part[qf2];
    lr += __shfl_xor(lr, 16);
    lr += __shfl_xor(lr, 32);
    lrow[qf2] = lr;
  }

  if (normStore) {
#pragma unroll
    for (int qf2 = 0; qf2 < 2; ++qf2) {
      const float inv = 1.0f / lrow[qf2];
#pragma unroll
      for (int r = 0; r < 4; ++r) {
        const float iv = __shfl(inv, g * 4 + r);
        const int qrow = qw0 + qf2 * 16 + g * 4 + r;
        const size_t ob = ((size_t)b * T + qrow) * 2048 + h * 128;
#pragma unroll
        for (int nf = 0; nf < 8; ++nf)
          Oh[ob + nf * 16 + q15] = f2bf(oacc[qf2][nf][r] * iv);
      }
    }
  } else {
    const int sp = s - 16;
    const size_t sbase = ((size_t)(bh * 16 + sp) * 2 + half) * 64;
    if (g == 0) {
#pragma unroll
      for (int qf2 = 0; qf2 < 2; ++qf2) {
        mArr[sbase + wid * 32 + qf2 * 16 + q15] = m_st[qf2];
        lArr[sbase + wid * 32 + qf2 * 16 + q15] = lrow[qf2];
      }
    }
    const size_t obase = sbase * 128;
#pragma unroll
    for (int qf2 = 0; qf2 < 2; ++qf2)
#pragma unroll
      for (int r = 0; r < 4; ++r) {
        const int row = wid * 32 + qf2 * 16 + g * 4 + r;
#pragma unroll
        for (int nf = 0; nf < 8; ++nf)
          Obuf[obase + (size_t)row * 128 + nf * 16 + q15] = oacc[qf2][nf][r];
      }
  }
}

// ---------------------------------------------------------------------------
// Combine split-K halves; skips strips whose low half was band-empty.
// ---------------------------------------------------------------------------
__global__ __launch_bounds__(128) void combine_halves(
    const float* __restrict__ Obuf, const float* __restrict__ mArr,
    const float* __restrict__ lArr, u16* __restrict__ Oh, int T) {
  const int idx = blockIdx.x;
  const int row = idx & 63;
  const int sp = (idx >> 6) & 15;
  const int bh = idx >> 10;
  const int d = threadIdx.x;
  const int s = sp + 16;
  const int b = bh >> 4, h = bh & 15;
  const float slope2 = exp2f(-0.5f * (float)(h + 1)) * 1.44269504f;
  if (band_jmin(s, slope2) >= s + 1) return;   // high half stored directly
  const size_t sbase = ((size_t)(bh * 16 + sp) * 2) * 64;
  const float m1 = mArr[sbase + row],      l1 = lArr[sbase + row];
  const float m2 = mArr[sbase + 64 + row], l2 = lArr[sbase + 64 + row];
  const float M = fmaxf(m1, m2);
  const float w1 = exp2f(m1 - M), w2 = exp2f(m2 - M);
  const float inv = 1.0f / (l1 * w1 + l2 * w2);
  const size_t ob = sbase * 128;
  const float o1 = Obuf[ob + (size_t)row * 128 + d];
  const float o2 = Obuf[ob + 8192 + (size_t)row * 128 + d];
  const float v = (o1 * w1 + o2 * w2) * inv;
  const int qrow = s * 64 + row;
  Oh[((size_t)b * T + qrow) * 2048 + h * 128 + d] = f2bf(v);
}

// ============================================================================
// Fallback f32 path (round-0, proven): used only if ws_size is insufficient.
// ============================================================================
#define TM 128
#define BKG 8

template <int QKV>
__global__ __launch_bounds__(256) void gemm_f32(
    const float* __restrict__ A, const float* __restrict__ W,
    const float* __restrict__ bias, float* __restrict__ out,
    int M, int N, int K, int T) {
  __shared__ float As[BKG][TM];
  __shared__ float Bs[BKG][TM];
  const int tid = threadIdx.x;
  const int tx = tid & 15, ty = tid >> 4;
  const int m0 = blockIdx.y * TM, n0 = blockIdx.x * TM;
  float acc[8][8];
#pragma unroll
  for (int i = 0; i < 8; ++i)
#pragma unroll
    for (int j = 0; j < 8; ++j) acc[i][j] = 0.f;
  const int arow = tid >> 1, acol = (tid & 1) * 4;
  const int brow = tid >> 5, bcol = (tid & 31) * 4;
  for (int k0 = 0; k0 < K; k0 += BKG) {
    const float4 av = *(const float4*)&A[(size_t)(m0 + arow) * K + k0 + acol];
    const float4 bv = *(const float4*)&W[(size_t)(k0 + brow) * N + n0 + bcol];
    __syncthreads();
    As[acol + 0][arow] = av.x; As[acol + 1][arow] = av.y;
    As[acol + 2][arow] = av.z; As[acol + 3][arow] = av.w;
    *(float4*)&Bs[brow][bcol] = bv;
    __syncthreads();
#pragma unroll
    for (int kk = 0; kk < BKG; ++kk) {
      const float4 a0 = *(const float4*)&As[kk][ty * 4];
      const float4 a1 = *(const float4*)&As[kk][64 + ty * 4];
      const float4 b0 = *(const float4*)&Bs[kk][tx * 4];
      const float4 b1 = *(const float4*)&Bs[kk][64 + tx * 4];
      const float af[8] = {a0.x, a0.y, a0.z, a0.w, a1.x, a1.y, a1.z, a1.w};
      const float bf[8] = {b0.x, b0.y, b0.z, b0.w, b1.x, b1.y, b1.z, b1.w};
#pragma unroll
      for (int i = 0; i < 8; ++i)
#pragma unroll
        for (int j = 0; j < 8; ++j) acc[i][j] += af[i] * bf[j];
    }
  }
#pragma unroll
  for (int a = 0; a < 2; ++a)
#pragma unroll
    for (int i = 0; i < 4; ++i) {
      const int row = m0 + a * 64 + ty * 4 + i;
      const int bb = row / T, t = row % T;
#pragma unroll
      for (int bj = 0; bj < 2; ++bj) {
        const int col = n0 + bj * 64 + tx * 4;
        float4 r;
        r.x = acc[a * 4 + i][bj * 4 + 0] + bias[col + 0];
        r.y = acc[a * 4 + i][bj * 4 + 1] + bias[col + 1];
        r.z = acc[a * 4 + i][bj * 4 + 2] + bias[col + 2];
        r.w = acc[a * 4 + i][bj * 4 + 3] + bias[col + 3];
        if (QKV) {
          const int hh = col >> 7, dd = col & 127;
          *(float4*)&out[(((size_t)bb * 16 + hh) * T + t) * 128 + dd] = r;
        } else {
          *(float4*)&out[(size_t)row * N + col] = r;
        }
      }
    }
}

#define QT 32
#define KT 32
#define DP 132

__global__ __launch_bounds__(256) void flash_f32(
    const float* __restrict__ Q, const float* __restrict__ K,
    const float* __restrict__ V, float* __restrict__ O, int T) {
  __shared__ float Qs[QT][DP];
  __shared__ float Ks[KT][DP];
  __shared__ float Vs[KT][DP];
  __shared__ float Ps[QT][KT + 1];
  const int tid = threadIdx.x;
  const int jh = tid & 15, ih = tid >> 4;
  const int bh = blockIdx.y;
  const int h = bh & 15;
  const int q0 = blockIdx.x * QT;
  const float slope = exp2f(-0.5f * (float)(h + 1));
  const float rsD = 0.08838834764831845f;
  {
    const float* Qg = Q + ((size_t)bh * T + q0) * 128;
    const int r = tid >> 3, p = tid & 7;
#pragma unroll
    for (int u = 0; u < 4; ++u)
      *(float4*)&Qs[r][(p + 8 * u) * 4] = *(const float4*)&Qg[r * 128 + (p + 8 * u) * 4];
  }
  float m_st[2] = {-1e30f, -1e30f};
  float l_st[2] = {0.f, 0.f};
  float accv[2][8] = {};
  const int ktiles = blockIdx.x + 1;
  for (int kt = 0; kt < ktiles; ++kt) {
    const int j0 = kt * KT;
    const float* Kg = K + ((size_t)bh * T + j0) * 128;
    const float* Vg = V + ((size_t)bh * T + j0) * 128;
    __syncthreads();
    {
      const int r = tid >> 3, p = tid & 7;
#pragma unroll
      for (int u = 0; u < 4; ++u) {
        *(float4*)&Ks[r][(p + 8 * u) * 4] = *(const float4*)&Kg[r * 128 + (p + 8 * u) * 4];
        *(float4*)&Vs[r][(p + 8 * u) * 4] = *(const float4*)&Vg[r * 128 + (p + 8 * u) * 4];
      }
    }
    __syncthreads();
    float s00 = 0.f, s01 = 0.f, s10 = 0.f, s11 = 0.f;
#pragma unroll 8
    for (int d4 = 0; d4 < 32; ++d4) {
      const float4 qa = *(const float4*)&Qs[2 * ih + 0][4 * d4];
      const float4 qb = *(const float4*)&Qs[2 * ih + 1][4 * d4];
      const float4 ka = *(const float4*)&Ks[2 * jh + 0][4 * d4];
      const float4 kb = *(const float4*)&Ks[2 * jh + 1][4 * d4];
      s00 += qa.x * ka.x + qa.y * ka.y + qa.z * ka.z + qa.w * ka.w;
      s01 += qa.x * kb.x + qa.y * kb.y + qa.z * kb.z + qa.w * kb.w;
      s10 += qb.x * ka.x + qb.y * ka.y + qb.z * ka.z + qb.w * ka.w;
      s11 += qb.x * kb.x + qb.y * kb.y + qb.z * kb.z + qb.w * kb.w;
    }
    float sc[2][2] = {{s00, s01}, {s10, s11}};
    float mt[2];
#pragma unroll
    for (int r = 0; r < 2; ++r) {
      const int qg = q0 + 2 * ih + r;
#pragma unroll
      for (int c = 0; c < 2; ++c) {
        const int jg = j0 + 2 * jh + c;
        const float svv = sc[r][c] * rsD + slope * (float)(jg - (T - 1));
        sc[r][c] = (jg > qg) ? -1e30f : svv;
      }
      mt[r] = fmaxf(sc[r][0], sc[r][1]);
    }
#pragma unroll
    for (int m = 1; m < 16; m <<= 1) {
      mt[0] = fmaxf(mt[0], __shfl_xor(mt[0], m));
      mt[1] = fmaxf(mt[1], __shfl_xor(mt[1], m));
    }
#pragma unroll
    for (int r = 0; r < 2; ++r) {
      const float mnew = fmaxf(m_st[r], mt[r]);
      const float scl = (m_st[r] > -1e29f) ? expf(m_st[r] - mnew) : 0.f;
      const float p0 = expf(sc[r][0] - mnew);
      const float p1 = expf(sc[r][1] - mnew);
      float rs = p0 + p1;
#pragma unroll
      for (int m = 1; m < 16; m <<= 1) rs += __shfl_xor(rs, m);
      l_st[r] = l_st[r] * scl + rs;
      m_st[r] = mnew;
#pragma unroll
      for (int d = 0; d < 8; ++d) accv[r][d] *= scl;
      Ps[2 * ih + r][2 * jh + 0] = p0;
      Ps[2 * ih + r][2 * jh + 1] = p1;
    }
    __syncthreads();
#pragma unroll 4
    for (int j = 0; j < KT; ++j) {
      const float p0 = Ps[2 * ih + 0][j];
      const float p1 = Ps[2 * ih + 1][j];
      const float4 v0 = *(const float4*)&Vs[j][8 * jh];
      const float4 v1 = *(const float4*)&Vs[j][8 * jh + 4];
      accv[0][0] += p0 * v0.x; accv[0][1] += p0 * v0.y;
      accv[0][2] += p0 * v0.z; accv[0][3] += p0 * v0.w;
      accv[0][4] += p0 * v1.x; accv[0][5] += p0 * v1.y;
      accv[0][6] += p0 * v1.z; accv[0][7] += p0 * v1.w;
      accv[1][0] += p1 * v0.x; accv[1][1] += p1 * v0.y;
      accv[1][2] += p1 * v0.z; accv[1][3] += p1 * v0.w;
      accv[1][4] += p1 * v1.x; accv[1][5] += p1 * v1.y;
      accv[1][6] += p1 * v1.z; accv[1][7] += p1 * v1.w;
    }
  }
  const int b = bh >> 4;
#pragma unroll
  for (int r = 0; r < 2; ++r) {
    const int qg = q0 + 2 * ih + r;
    const float inv = 1.0f / l_st[r];
    float4 o0, o1;
    o0.x = accv[r][0] * inv; o0.y = accv[r][1] * inv;
    o0.z = accv[r][2] * inv; o0.w = accv[r][3] * inv;
    o1.x = accv[r][4] * inv; o1.y = accv[r][5] * inv;
    o1.z = accv[r][6] * inv; o1.w = accv[r][7] * inv;
    float* dst = O + ((size_t)b * T + qg) * 2048 + h * 128 + 8 * jh;
    *(float4*)&dst[0] = o0;
    *(float4*)&dst[4] = o1;
  }
}

// ============================================================================
extern "C" void kernel_launch(void* const* d_in, const int* in_sizes, int n_in,
                              void* d_out, int out_size, void* d_ws,
                              size_t ws_size, hipStream_t stream) {
  const float* x  = (const float*)d_in[0];
  const float* Wq = (const float*)d_in[1];
  const float* bq = (const float*)d_in[2];
  const float* Wk = (const float*)d_in[3];
  const float* bk = (const float*)d_in[4];
  const float* Wv = (const float*)d_in[5];
  const float* bv = (const float*)d_in[6];
  const float* Wo = (const float*)d_in[7];
  const float* bo = (const float*)d_in[8];
  float* out = (float*)d_out;

  const int C = 2048, T = 2048, H = 16;
  const int M = in_sizes[0] / C;  // B*T
  const int B = M / T;
  const int BH = B * H;
  const size_t MC = (size_t)M * C, CC = (size_t)C * C;
  const size_t splitO = (size_t)BH * 16 * 2 * 8192;        // f32 elems
  const size_t splitML = (size_t)BH * 16 * 2 * 64;         // f32 elems
  const size_t need = (5 * MC + 4 * CC) * sizeof(u16) +
                      (splitO + 2 * splitML) * sizeof(float);

  // rsD * log2(e): puts QK^T logits in exp2 domain
  const float QSC = 0.08838834764831845f * 1.44269504088896f;

  if (ws_size >= need && (M % 256) == 0) {
    u16* p = (u16*)d_ws;
    u16* xh   = p; p += MC;
    u16* wqth = p; p += CC;   // wqth/wkth contiguous -> merged QK GEMM
    u16* wkth = p; p += CC;
    u16* wvth = p; p += CC;
    u16* woth = p; p += CC;
    u16* qh   = p; p += MC;
    u16* kh   = p; p += MC;
    u16* vth  = p; p += MC;
    u16* oh   = p; p += MC;
    float* Obuf = (float*)p;
    float* mArr = Obuf + splitO;
    float* lArr = mArr + splitML;

    split_f32<<<1024, 256, 0, stream>>>(x, xh, (int)(MC / 4));
    dim3 tg(C / 64, C / 64, 4);
    tsplit4_f32<<<tg, 256, 0, stream>>>(Wq, Wk, Wv, Wo, wqth, wkth, wvth,
                                        woth, C, C, QSC);

    // merged Q+K projection: [M x 4096] = xh @ [wqth|wkth]^T
    // 8-phase 256^2 kernel -> (16,16) = 256 blocks, 1/CU
    dim3 gqk(2 * C / 256, M / 256);
    gemm8p_qk<<<gqk, 512, 0, stream>>>(xh, wqth, bq, bk, QSC, qh, kh,
                                       M, 2 * C, C);
    // V^T = Wv^T @ x^T : out [C][M] (+bv by row) — (32,8) = 256 blocks
    dim3 gv(M / 128, C / 256);
    gemm256x128<2><<<gv, 512, 0, stream>>>(wvth, xh, bv, nullptr, 1.f, vth,
                                           nullptr, nullptr, C, M, C);

    attn_splitk<<<96 * BH, 64, 0, stream>>>(qh, kh, vth, oh, Obuf, mArr,
                                            lArr, T, M, BH);
    combine_halves<<<BH * 16 * 64, 128, 0, stream>>>(Obuf, mArr, lArr, oh, T);

    // final o @ Wo — (16,16) = 256 blocks
    dim3 gq(C / 128, M / 256);
    gemm256x128<0><<<gq, 512, 0, stream>>>(oh, woth, bo, nullptr, 1.f,
                                           nullptr, nullptr, out, M, C, C);
  } else {
    // f32 fallback (round-0 path)
    float* Qw = (float*)d_ws;
    float* Kw = Qw + MC;
    float* Vw = Kw + MC;
    float* Ow = Vw + MC;
    dim3 ggrid(C / TM, M / TM);
    gemm_f32<1><<<ggrid, 256, 0, stream>>>(x, Wq, bq, Qw, M, C, C, T);
    gemm_f32<1><<<ggrid, 256, 0, stream>>>(x, Wk, bk, Kw, M, C, C, T);
    gemm_f32<1><<<ggrid, 256, 0, stream>>>(x, Wv, bv, Vw, M, C, C, T);
    dim3 fgrid(T / QT, B * H);
    flash_f32<<<fgrid, 256, 0, stream>>>(Qw, Kw, Vw, Ow, T);
    gemm_f32<0><<<ggrid, 256, 0, stream>>>(Ow, Wo, bo, out, M, C, C, T);
  }
}

// Round 15
// 281.579 us; speedup vs baseline: 1.0427x; 1.0427x over previous
//
#include <hip/hip_runtime.h>
#include <math.h>

// ============================================================================
// CausalAttention (B=2, T=2048, C=2048, H=16, D=128) with ALiBi.
// Round 29: revert to r27 (verified best, 279.6us). r28's 8-phase QK port was
// correct but slower (100.4 vs 84.5us, MfmaUtil 27 vs 34): cooperative
// quadrants need 16 barriers per 2 K-tiles vs 4, and lack m201's per-wave
// role split. Exploration ledger: 2-barrier ring-3 GEMM beat BK-ring (r16),
// 128^2 (r21), fused QKV (r23), 8-phase (r28); attn pair-ILP beat KVBLK=64
// (r19), occupancy boosts (r20), K-to-reg (r25). This config is the
// empirical optimum of the design family.
// ============================================================================

typedef unsigned short u16;
using bf16x8 = __attribute__((ext_vector_type(8))) short;
using f32x4  = __attribute__((ext_vector_type(4))) float;

__device__ __forceinline__ u16 f2bf(float f) {
  union { float f; unsigned u; } c; c.f = f;
  unsigned r = c.u + 0x7fffu + ((c.u >> 16) & 1u);   // RTN-even
  return (u16)(r >> 16);
}
__device__ __forceinline__ float bf2f(u16 b) {
  union { unsigned u; float f; } c; c.u = ((unsigned)b) << 16; return c.f;
}
__device__ __forceinline__ unsigned cvtpk(float a, float b) {
  unsigned r;
  asm("v_cvt_pk_bf16_f32 %0, %1, %2" : "=v"(r) : "v"(a), "v"(b));
  return r;
}
__device__ __forceinline__ void g2l16(const void* g, void* l) {
  __builtin_amdgcn_global_load_lds(
      (const __attribute__((address_space(1))) void*)g,
      (__attribute__((address_space(3))) void*)l, 16, 0, 0);
}

// band: drop tiles whose every column is > dist below the strip's first row
__device__ __forceinline__ int band_jmin(int s, float slope2) {
  const int idist = (int)(36.0f / slope2);
  const int cut = 64 * s - idist - 31;
  return (cut > 0) ? (cut >> 5) : 0;
}

// heaviest-first unit order: units sorted by serial tile count descending.
__device__ const unsigned char uord[48] = {
  15, 16, 32, 17, 33, 14, 18, 34, 19, 35,
  13, 20, 36, 21, 37, 12, 22, 38, 23, 39,
  11, 24, 40, 25, 41, 10, 26, 42, 27, 43,
   9, 28, 44, 29, 45,  8, 30, 46, 31, 47,
   7,  6,  5,  4,  3,  2,  1,  0};

// ---------------------------------------------------------------------------
// f32 -> bf16 cast, vectorized
// ---------------------------------------------------------------------------
__global__ __launch_bounds__(256) void split_f32(const float* __restrict__ in,
                                                 u16* __restrict__ hi, int n4) {
  for (int i = blockIdx.x * 256 + threadIdx.x; i < n4; i += gridDim.x * 256) {
    const float4 v = ((const float4*)in)[i];
    ushort4 h;
    h.x = f2bf(v.x); h.y = f2bf(v.y); h.z = f2bf(v.z); h.w = f2bf(v.w);
    ((ushort4*)hi)[i] = h;
  }
}

// ---------------------------------------------------------------------------
// Fused transpose + scale + cast for all 4 weights: z selects the matrix.
// ---------------------------------------------------------------------------
__global__ __launch_bounds__(256) void tsplit4_f32(
    const float* __restrict__ W0, const float* __restrict__ W1,
    const float* __restrict__ W2, const float* __restrict__ W3,
    u16* __restrict__ D0, u16* __restrict__ D1,
    u16* __restrict__ D2, u16* __restrict__ D3,
    int N, int K, float sc0) {
  __shared__ float tile[64][68];
  const int z = blockIdx.z;
  const float* W = (z == 0) ? W0 : (z == 1) ? W1 : (z == 2) ? W2 : W3;
  u16* Wth = (z == 0) ? D0 : (z == 1) ? D1 : (z == 2) ? D2 : D3;
  const float sc = (z == 0) ? sc0 : 1.f;
  const int tid = threadIdx.x;
  const int k0 = blockIdx.y * 64, n0 = blockIdx.x * 64;
  const int rr = tid >> 4, cc = (tid & 15) * 4;
#pragma unroll
  for (int u = 0; u < 4; ++u) {
    const float4 v = *(const float4*)&W[(size_t)(k0 + rr + 16 * u) * N + n0 + cc];
    tile[rr + 16 * u][cc + 0] = v.x;
    tile[rr + 16 * u][cc + 1] = v.y;
    tile[rr + 16 * u][cc + 2] = v.z;
    tile[rr + 16 * u][cc + 3] = v.w;
  }
  __syncthreads();
#pragma unroll
  for (int u = 0; u < 4; ++u) {
    const int nn = rr + 16 * u;
    ushort4 h;
    h.x = f2bf(tile[cc + 0][nn] * sc);
    h.y = f2bf(tile[cc + 1][nn] * sc);
    h.z = f2bf(tile[cc + 2][nn] * sc);
    h.w = f2bf(tile[cc + 3][nn] * sc);
    *(ushort4*)&Wth[(size_t)(n0 + nn) * K + k0 + cc] = h;
  }
}

// ---------------------------------------------------------------------------
// 256x128-tile bf16 GEMM, BK=32, ring-3 LDS, counted vmcnt (r18 proven).
// MODE 0: f32 out (+bias[col]*bsc); MODE 2: bf16 out (+bias[row]*bsc);
// MODE 3: merged QK scatter (+bias[col&2047]*bsc or bias2).
// ---------------------------------------------------------------------------
template <int MODE>
__global__ __launch_bounds__(512, 4) void gemm256x128(
    const u16* __restrict__ Ah, const u16* __restrict__ Bth,
    const float* __restrict__ bias, const float* __restrict__ bias2,
    float bsc, u16* __restrict__ outH, u16* __restrict__ outH2,
    float* __restrict__ outF, int MM, int NN, int KK) {
  __shared__ u16 LA[3][8192];   // ring: 256 rows x 32 (64B rows)
  __shared__ u16 LB[3][4096];   // ring: 128 rows x 32

  const int tid = threadIdx.x;
  const int wave = tid >> 6, lane = tid & 63;
  const int g = lane >> 4, q15 = lane & 15;
  const int wr = wave >> 1, wc = wave & 1;     // 4M x 2N
  const int m0 = blockIdx.y * 256, n0 = blockIdx.x * 128;
  const int NT = KK >> 5;
  const int sxg = ((g ^ ((q15 >> 1) & 3)) << 4);

  f32x4 acc[4][4];
#pragma unroll
  for (int f = 0; f < 4; ++f)
#pragma unroll
    for (int j = 0; j < 4; ++j) acc[f][j] = (f32x4){0.f, 0.f, 0.f, 0.f};

  auto stageA = [&](int t, int rbuf) {
#pragma unroll
    for (int l = 0; l < 2; ++l) {
      const int ch = l * 512 + tid;
      const int row = ch >> 2, slot = ch & 3;
      const size_t ga = (size_t)(m0 + row) * KK + t * 32 +
                        ((slot ^ ((row >> 1) & 3)) * 8);
      g2l16(Ah + ga, (char*)(LA[rbuf]) + ch * 16);
    }
  };
  auto stageB = [&](int t, int rbuf) {
    const int ch = tid;
    const int row = ch >> 2, slot = ch & 3;
    const size_t gb = (size_t)(n0 + row) * KK + t * 32 +
                      ((slot ^ ((row >> 1) & 3)) * 8);
    g2l16(Bth + gb, (char*)(LB[rbuf]) + ch * 16);
  };

  // prologue: stage tiles 0,1 (6 ops/thread), drain tile 0 only
  stageA(0, 0); stageB(0, 0);
  __builtin_amdgcn_sched_barrier(0);
  if (NT > 1) { stageA(1, 1); stageB(1, 1); }
  __builtin_amdgcn_sched_barrier(0);
  if (NT > 1) { asm volatile("s_waitcnt vmcnt(3)" ::: "memory"); }
  else        { asm volatile("s_waitcnt vmcnt(0)" ::: "memory"); }
  __builtin_amdgcn_sched_barrier(0);
  __builtin_amdgcn_s_barrier();

  int rb = 0, rb2 = 2;
  for (int t = 0; t < NT; ++t) {
    const char* baseA = (const char*)(LA[rb]);
    const char* baseB = (const char*)(LB[rb]);

    bf16x8 af[4], bf[4];
#pragma unroll
    for (int f = 0; f < 4; ++f)
      af[f] = *(const bf16x8*)(baseA + (wr * 64 + f * 16 + q15) * 64 + sxg);
#pragma unroll
    for (int j = 0; j < 4; ++j)
      bf[j] = *(const bf16x8*)(baseB + (wc * 64 + j * 16 + q15) * 64 + sxg);
    if (t + 2 < NT) { stageA(t + 2, rb2); stageB(t + 2, rb2); }
    __builtin_amdgcn_sched_barrier(0);
    __builtin_amdgcn_s_barrier();
    asm volatile("s_waitcnt lgkmcnt(0)" ::: "memory");
    __builtin_amdgcn_sched_barrier(0);
    __builtin_amdgcn_s_setprio(1);
#pragma unroll
    for (int f = 0; f < 4; ++f)
#pragma unroll
      for (int j = 0; j < 4; ++j)
        acc[f][j] = __builtin_amdgcn_mfma_f32_16x16x32_bf16(
            af[f], bf[j], acc[f][j], 0, 0, 0);
    __builtin_amdgcn_s_setprio(0);
    if (t + 1 < NT) {
      if (t + 2 < NT) { asm volatile("s_waitcnt vmcnt(3)" ::: "memory"); }
      else            { asm volatile("s_waitcnt vmcnt(0)" ::: "memory"); }
    }
    __builtin_amdgcn_sched_barrier(0);
    __builtin_amdgcn_s_barrier();
    rb  = (rb  == 2) ? 0 : rb  + 1;
    rb2 = (rb2 == 2) ? 0 : rb2 + 1;
  }

#pragma unroll
  for (int f = 0; f < 4; ++f)
#pragma unroll
    for (int j = 0; j < 4; ++j)
#pragma unroll
      for (int r = 0; r < 4; ++r) {
        const int row = m0 + wr * 64 + f * 16 + g * 4 + r;
        const int col = n0 + wc * 64 + j * 16 + q15;
        const float v = acc[f][j][r];
        if (MODE == 0) {
          outF[(size_t)row * NN + col] = v + bias[col] * bsc;
        } else if (MODE == 2) {
          outH[(size_t)row * NN + col] = f2bf(v + bias[row] * bsc);
        } else {  // MODE 3: merged QK scatter
          const int sel = col >> 11;
          const int c2 = col & 2047;
          const float vv = v + (sel ? bias2[c2] : bias[c2] * bsc);
          const int bb = row >> 11, tt = row & 2047;
          const int hh = c2 >> 7, dd = c2 & 127;
          (sel ? outH2 : outH)[(((size_t)bb * 16 + hh) * 2048 + tt) * 128 + dd] =
              f2bf(vv);
        }
      }
}

// ---------------------------------------------------------------------------
// Banded split-K flash attention with ALiBi. r27: tile-pair ILP on top of
// the r24/r26 structure (1-wave blocks, XCD-pair decode, uord, setprio,
// K LDS ring-3, V reg-dbuf, counted vmcnt).
// ---------------------------------------------------------------------------
__global__ __launch_bounds__(64) void attn_splitk(
    const u16* __restrict__ Qh, const u16* __restrict__ Kh,
    const u16* __restrict__ Vth, u16* __restrict__ Oh,
    float* __restrict__ Obuf, float* __restrict__ mArr,
    float* __restrict__ lArr, int T, int NB, int BH) {
  __shared__ u16 KS[3][4096];   // 32 x 128, 256B rows, XOR ((row&7)<<4)

  const int tid = threadIdx.x;
  const int lane = tid & 63;
  const int g = lane >> 4, q15 = lane & 15;
  const int L = blockIdx.x;
  // XCD-co-located pair decode: halves are (L, L+8) -> same XCD (mod 8)
  const int LL = (L & 7) | ((L >> 4) << 3);
  const int wid = (L >> 3) & 1;

  int bh, u;
  if (BH == 32) {
    const int k = LL >> 8;       // round 0..5
    const int c = LL & 255;      // CU-slot within round
    bh = (c + 5 * k) & 31;
    u = uord[k * 8 + (c >> 5)];
  } else {
    bh = LL / 48;
    u = uord[LL % 48];
  }
  int s, half;
  if (u < 16)      { s = u;      half = 2; }   // full strip
  else if (u < 32) { s = 47 - u; half = 0; }   // low half (no diagonal)
  else             { s = 63 - u; half = 1; }   // high half (diagonal)

  const int b = bh >> 4, h = bh & 15;
  const float slope2 = exp2f(-0.5f * (float)(h + 1)) * 1.44269504f;
  const int jmin = band_jmin(s, slope2);
  const bool loEmpty = (jmin >= s + 1);

  if (half == 0 && loEmpty) return;            // nothing to do

  int lo, hi;
  if (half == 2)      { lo = jmin;                hi = 2 * s + 2; }
  else if (half == 0) { lo = jmin;                hi = s + 1; }
  else                { lo = loEmpty ? jmin : (s + 1); hi = 2 * s + 2; }
  const int ns = hi - lo;                      // >= 1
  const bool maskable = (half != 0);
  const bool normStore = (half == 2) || (half == 1 && loEmpty);

  const int qw0 = s * 64 + wid * 32;
  const size_t vrow0 = (size_t)h * 128;
  const size_t vcol0 = (size_t)b * T;
  const size_t kbase = (size_t)bh * T;

  // ---- Q loads (8 globals, issued first / oldest in vmcnt order) ----
  bf16x8 qfr[2][4];
#pragma unroll
  for (int qf2 = 0; qf2 < 2; ++qf2) {
    const size_t rb = ((size_t)bh * T + qw0 + qf2 * 16 + q15) * 128;
#pragma unroll
    for (int ks = 0; ks < 4; ++ks)
      qfr[qf2][ks] = *(const bf16x8*)&Qh[rb + ks * 32 + g * 8];
  }

  f32x4 oacc[2][8];
#pragma unroll
  for (int a = 0; a < 2; ++a)
#pragma unroll
    for (int n = 0; n < 8; ++n) oacc[a][n] = (f32x4){0.f, 0.f, 0.f, 0.f};
  float m_st[2] = {-1e5f, -1e5f};
  float l_part[2] = {0.f, 0.f};

  // stage one 32x128 K tile (8KB = 8 chunks of 1KB), all by this wave
  auto stageK = [&](int jt, int bf) {
    const int j0 = jt * 32;
#pragma unroll
    for (int c = 0; c < 8; ++c) {
      const int row = c * 4 + g;
      const int off = (q15 * 16) ^ ((row & 7) << 4);
      const size_t gb = (kbase + j0 + row) * 128;
      g2l16((const char*)(Kh + gb) + off, (char*)(KS[bf]) + c * 1024);
    }
  };
  auto loadV = [&](int jt, bf16x8 (&vf)[8]) {
    const int j0 = jt * 32;
#pragma unroll
    for (int nf = 0; nf < 8; ++nf)
      vf[nf] = *(const bf16x8*)
          &Vth[(vrow0 + nf * 16 + q15) * (size_t)NB + vcol0 + j0 + g * 8];
  };
  // QK^T for one tile from KS[slot] into sacc
  auto QKT = [&](int slot, f32x4 (&sacc)[2][2]) {
#pragma unroll
    for (int jf = 0; jf < 2; ++jf)
#pragma unroll
      for (int qf2 = 0; qf2 < 2; ++qf2) sacc[jf][qf2] = (f32x4){0.f, 0.f, 0.f, 0.f};
#pragma unroll
    for (int ks = 0; ks < 4; ++ks) {
      bf16x8 ka[2];
#pragma unroll
      for (int jf = 0; jf < 2; ++jf) {
        const int row = jf * 16 + q15;
        const int off = (row * 256 + ks * 64 + g * 16) ^ ((row & 7) << 4);
        ka[jf] = *(const bf16x8*)((const char*)(KS[slot]) + off);
      }
#pragma unroll
      for (int jf = 0; jf < 2; ++jf)
#pragma unroll
        for (int qf2 = 0; qf2 < 2; ++qf2)
          sacc[jf][qf2] = __builtin_amdgcn_mfma_f32_16x16x32_bf16(
              ka[jf], qfr[qf2][ks], sacc[jf][qf2], 0, 0, 0);
    }
  };
  // softmax + PV for one tile (no internal waits; V must be drained)
  auto SOFTPV = [&](int it, int j0, f32x4 (&sacc)[2][2], bf16x8 (&vc)[8]) {
    const float jb2 = (float)(j0 + 4 * g - (T - 1));
    unsigned Fw[2][4];
#pragma unroll
    for (int qf2 = 0; qf2 < 2; ++qf2) {
      const int qg = qw0 + qf2 * 16 + q15;
      float sv[2][4];
      float mt = -1e30f;
#pragma unroll
      for (int jf = 0; jf < 2; ++jf)
#pragma unroll
        for (int r = 0; r < 4; ++r) {
          float x = fmaf(slope2, jb2 + (float)(jf * 16 + r), sacc[jf][qf2][r]);
          if (maskable && it < 2) {
            const int jg = j0 + jf * 16 + 4 * g + r;
            x = (jg > qg) ? -1e30f : x;
          }
          sv[jf][r] = x;
          mt = fmaxf(mt, x);
        }
      if (!__all(mt <= m_st[qf2] + 11.0f)) {
        mt = fmaxf(mt, __shfl_xor(mt, 16));
        mt = fmaxf(mt, __shfl_xor(mt, 32));
        const float mnew = fmaxf(m_st[qf2], mt);
        const float scl = exp2f(m_st[qf2] - mnew);
        l_part[qf2] *= scl;
        m_st[qf2] = mnew;
#pragma unroll
        for (int r = 0; r < 4; ++r) {
          const float sc = __shfl(scl, g * 4 + r);
#pragma unroll
          for (int nf = 0; nf < 8; ++nf) oacc[qf2][nf][r] *= sc;
        }
      }
      float rs = 0.f;
      float p[2][4];
#pragma unroll
      for (int jf = 0; jf < 2; ++jf)
#pragma unroll
        for (int r = 0; r < 4; ++r) {
          p[jf][r] = exp2f(sv[jf][r] - m_st[qf2]);
          rs += p[jf][r];
        }
      l_part[qf2] += rs;
      const unsigned W00 = cvtpk(p[0][0], p[0][1]), W01 = cvtpk(p[0][2], p[0][3]);
      const unsigned W10 = cvtpk(p[1][0], p[1][1]), W11 = cvtpk(p[1][2], p[1][3]);
      const int srcA = q15 + ((g & 1) << 5);
      const int srcB = srcA + 16;
      const unsigned A0 = (unsigned)__shfl((int)W00, srcA);
      const unsigned A1 = (unsigned)__shfl((int)W01, srcA);
      const unsigned B0 = (unsigned)__shfl((int)W00, srcB);
      const unsigned B1 = (unsigned)__shfl((int)W01, srcB);
      const unsigned C0 = (unsigned)__shfl((int)W10, srcA);
      const unsigned C1 = (unsigned)__shfl((int)W11, srcA);
      const unsigned D0 = (unsigned)__shfl((int)W10, srcB);
      const unsigned D1 = (unsigned)__shfl((int)W11, srcB);
      const bool hi2 = g >= 2;
      Fw[qf2][0] = hi2 ? C0 : A0;
      Fw[qf2][1] = hi2 ? C1 : A1;
      Fw[qf2][2] = hi2 ? D0 : B0;
      Fw[qf2][3] = hi2 ? D1 : B1;
    }
    union { unsigned uu[4]; bf16x8 v; } pa0, pa1;
#pragma unroll
    for (int w = 0; w < 4; ++w) { pa0.uu[w] = Fw[0][w]; pa1.uu[w] = Fw[1][w]; }
    __builtin_amdgcn_s_setprio(1);
#pragma unroll
    for (int nf = 0; nf < 8; ++nf) {
      oacc[0][nf] = __builtin_amdgcn_mfma_f32_16x16x32_bf16(pa0.v, vc[nf], oacc[0][nf], 0, 0, 0);
      oacc[1][nf] = __builtin_amdgcn_mfma_f32_16x16x32_bf16(pa1.v, vc[nf], oacc[1][nf], 0, 0, 0);
    }
    __builtin_amdgcn_s_setprio(0);
  };

  // ---- prologue: pinned issue order [Q][K0,K1][V0] ----
  bf16x8 vfA[8], vfB[8];
  __builtin_amdgcn_sched_barrier(0);
  stageK(hi - 1, 0);
  if (ns > 1) stageK(hi - 2, 1);
  __builtin_amdgcn_sched_barrier(0);
  loadV(hi - 1, vfA);
  // outstanding: ns>1: Q(8)+K0(8)+K1(8)+V0(8)=32 -> vmcnt(16) drains Q,K0
  //              ns==1: Q(8)+K0(8)+V0(8)=24      -> vmcnt(8)  drains Q,K0
  if (ns > 1) { asm volatile("s_waitcnt vmcnt(16)" ::: "memory"); }
  else        { asm volatile("s_waitcnt vmcnt(8)"  ::: "memory"); }
  __builtin_amdgcn_sched_barrier(0);

  int cur = 0;   // slot of tile it: it % 3

  int it = 0;
  while (it + 2 <= ns) {
    // ---- pair (t0=it, t1=it+1); entry: vfA=V(t0); outstanding {V(t0),K(t0+1)}
    const int jt0 = hi - 1 - it, jt1 = jt0 - 1;
    const int j0a = jt0 * 32, j0b = jt1 * 32;
    const int cur1 = (cur == 2) ? 0 : cur + 1;
    const int cur2 = (cur1 == 2) ? 0 : cur1 + 1;
    const bool e2 = (it + 2 < ns);
    const bool e3 = (it + 3 < ns);

    // sub0 issues: V(t1)->vfB [8], K(t0+2)->cur2 [8 if e2]
    loadV(jt1, vfB);
    if (e2) stageK(jt0 - 2, cur2);
    __builtin_amdgcn_sched_barrier(0);
    if (e2) { asm volatile("s_waitcnt vmcnt(16)" ::: "memory"); }
    else    { asm volatile("s_waitcnt vmcnt(8)"  ::: "memory"); }
    __builtin_amdgcn_sched_barrier(0);

    // QK for BOTH tiles: QK(t1) MFMAs drain under SM(t0)'s VALU below.
    f32x4 sacc0[2][2], sacc1[2][2];
    __builtin_amdgcn_s_setprio(1);
    QKT(cur, sacc0);
    QKT(cur1, sacc1);
    __builtin_amdgcn_s_setprio(0);

    SOFTPV(it, j0a, sacc0, vfA);       // uses V(t0) (drained)

    // sub1 issues (after PV(t0) consumed vfA): V(t0+2)->vfA, K(t0+3)->cur
    if (e2) loadV(jt0 - 2, vfA);
    if (e3) stageK(jt0 - 3, cur);
    __builtin_amdgcn_sched_barrier(0);
    if (e2 && e3)      { asm volatile("s_waitcnt vmcnt(16)" ::: "memory"); }
    else if (e2)       { asm volatile("s_waitcnt vmcnt(8)"  ::: "memory"); }
    else               { asm volatile("s_waitcnt vmcnt(0)"  ::: "memory"); }
    __builtin_amdgcn_sched_barrier(0);

    SOFTPV(it + 1, j0b, sacc1, vfB);   // uses V(t1) (drained)

    cur = cur2;  // cur advanced by 2 (mod 3)
    it += 2;
  }
  if (it < ns) {
    // singleton tail: outstanding {V(it)} (or V0 for ns==1); no prefetch
    const int jt = hi - 1 - it;
    asm volatile("s_waitcnt vmcnt(0)" ::: "memory");
    __builtin_amdgcn_sched_barrier(0);
    f32x4 sacc0[2][2];
    __builtin_amdgcn_s_setprio(1);
    QKT(cur, sacc0);
    __builtin_amdgcn_s_setprio(0);
    SOFTPV(it, jt * 32, sacc0, vfA);
  }

  // ---- epilogue ----
  float lrow[2];
#pragma unroll
  for (int qf2 = 0; qf2 < 2; ++qf2) {
    float lr = l_part[qf2];
    lr += __shfl_xor(lr, 16);
    lr += __shfl_xor(lr, 32);
    lrow[qf2] = lr;
  }

  if (normStore) {
#pragma unroll
    for (int qf2 = 0; qf2 < 2; ++qf2) {
      const float inv = 1.0f / lrow[qf2];
#pragma unroll
      for (int r = 0; r < 4; ++r) {
        const float iv = __shfl(inv, g * 4 + r);
        const int qrow = qw0 + qf2 * 16 + g * 4 + r;
        const size_t ob = ((size_t)b * T + qrow) * 2048 + h * 128;
#pragma unroll
        for (int nf = 0; nf < 8; ++nf)
          Oh[ob + nf * 16 + q15] = f2bf(oacc[qf2][nf][r] * iv);
      }
    }
  } else {
    const int sp = s - 16;
    const size_t sbase = ((size_t)(bh * 16 + sp) * 2 + half) * 64;
    if (g == 0) {
#pragma unroll
      for (int qf2 = 0; qf2 < 2; ++qf2) {
        mArr[sbase + wid * 32 + qf2 * 16 + q15] = m_st[qf2];
        lArr[sbase + wid * 32 + qf2 * 16 + q15] = lrow[qf2];
      }
    }
    const size_t obase = sbase * 128;
#pragma unroll
    for (int qf2 = 0; qf2 < 2; ++qf2)
#pragma unroll
      for (int r = 0; r < 4; ++r) {
        const int row = wid * 32 + qf2 * 16 + g * 4 + r;
#pragma unroll
        for (int nf = 0; nf < 8; ++nf)
          Obuf[obase + (size_t)row * 128 + nf * 16 + q15] = oacc[qf2][nf][r];
      }
  }
}

// ---------------------------------------------------------------------------
// Combine split-K halves; skips strips whose low half was band-empty.
// ---------------------------------------------------------------------------
__global__ __launch_bounds__(128) void combine_halves(
    const float* __restrict__ Obuf, const float* __restrict__ mArr,
    const float* __restrict__ lArr, u16* __restrict__ Oh, int T) {
  const int idx = blockIdx.x;
  const int row = idx & 63;
  const int sp = (idx >> 6) & 15;
  const int bh = idx >> 10;
  const int d = threadIdx.x;
  const int s = sp + 16;
  const int b = bh >> 4, h = bh & 15;
  const float slope2 = exp2f(-0.5f * (float)(h + 1)) * 1.44269504f;
  if (band_jmin(s, slope2) >= s + 1) return;   // high half stored directly
  const size_t sbase = ((size_t)(bh * 16 + sp) * 2) * 64;
  const float m1 = mArr[sbase + row],      l1 = lArr[sbase + row];
  const float m2 = mArr[sbase + 64 + row], l2 = lArr[sbase + 64 + row];
  const float M = fmaxf(m1, m2);
  const float w1 = exp2f(m1 - M), w2 = exp2f(m2 - M);
  const float inv = 1.0f / (l1 * w1 + l2 * w2);
  const size_t ob = sbase * 128;
  const float o1 = Obuf[ob + (size_t)row * 128 + d];
  const float o2 = Obuf[ob + 8192 + (size_t)row * 128 + d];
  const float v = (o1 * w1 + o2 * w2) * inv;
  const int qrow = s * 64 + row;
  Oh[((size_t)b * T + qrow) * 2048 + h * 128 + d] = f2bf(v);
}

// ============================================================================
// Fallback f32 path (round-0, proven): used only if ws_size is insufficient.
// ============================================================================
#define TM 128
#define BKG 8

template <int QKV>
__global__ __launch_bounds__(256) void gemm_f32(
    const float* __restrict__ A, const float* __restrict__ W,
    const float* __restrict__ bias, float* __restrict__ out,
    int M, int N, int K, int T) {
  __shared__ float As[BKG][TM];
  __shared__ float Bs[BKG][TM];
  const int tid = threadIdx.x;
  const int tx = tid & 15, ty = tid >> 4;
  const int m0 = blockIdx.y * TM, n0 = blockIdx.x * TM;
  float acc[8][8];
#pragma unroll
  for (int i = 0; i < 8; ++i)
#pragma unroll
    for (int j = 0; j < 8; ++j) acc[i][j] = 0.f;
  const int arow = tid >> 1, acol = (tid & 1) * 4;
  const int brow = tid >> 5, bcol = (tid & 31) * 4;
  for (int k0 = 0; k0 < K; k0 += BKG) {
    const float4 av = *(const float4*)&A[(size_t)(m0 + arow) * K + k0 + acol];
    const float4 bv = *(const float4*)&W[(size_t)(k0 + brow) * N + n0 + bcol];
    __syncthreads();
    As[acol + 0][arow] = av.x; As[acol + 1][arow] = av.y;
    As[acol + 2][arow] = av.z; As[acol + 3][arow] = av.w;
    *(float4*)&Bs[brow][bcol] = bv;
    __syncthreads();
#pragma unroll
    for (int kk = 0; kk < BKG; ++kk) {
      const float4 a0 = *(const float4*)&As[kk][ty * 4];
      const float4 a1 = *(const float4*)&As[kk][64 + ty * 4];
      const float4 b0 = *(const float4*)&Bs[kk][tx * 4];
      const float4 b1 = *(const float4*)&Bs[kk][64 + tx * 4];
      const float af[8] = {a0.x, a0.y, a0.z, a0.w, a1.x, a1.y, a1.z, a1.w};
      const float bf[8] = {b0.x, b0.y, b0.z, b0.w, b1.x, b1.y, b1.z, b1.w};
#pragma unroll
      for (int i = 0; i < 8; ++i)
#pragma unroll
        for (int j = 0; j < 8; ++j) acc[i][j] += af[i] * bf[j];
    }
  }
#pragma unroll
  for (int a = 0; a < 2; ++a)
#pragma unroll
    for (int i = 0; i < 4; ++i) {
      const int row = m0 + a * 64 + ty * 4 + i;
      const int bb = row / T, t = row % T;
#pragma unroll
      for (int bj = 0; bj < 2; ++bj) {
        const int col = n0 + bj * 64 + tx * 4;
        float4 r;
        r.x = acc[a * 4 + i][bj * 4 + 0] + bias[col + 0];
        r.y = acc[a * 4 + i][bj * 4 + 1] + bias[col + 1];
        r.z = acc[a * 4 + i][bj * 4 + 2] + bias[col + 2];
        r.w = acc[a * 4 + i][bj * 4 + 3] + bias[col + 3];
        if (QKV) {
          const int hh = col >> 7, dd = col & 127;
          *(float4*)&out[(((size_t)bb * 16 + hh) * T + t) * 128 + dd] = r;
        } else {
          *(float4*)&out[(size_t)row * N + col] = r;
        }
      }
    }
}

#define QT 32
#define KT 32
#define DP 132

__global__ __launch_bounds__(256) void flash_f32(
    const float* __restrict__ Q, const float* __restrict__ K,
    const float* __restrict__ V, float* __restrict__ O, int T) {
  __shared__ float Qs[QT][DP];
  __shared__ float Ks[KT][DP];
  __shared__ float Vs[KT][DP];
  __shared__ float Ps[QT][KT + 1];
  const int tid = threadIdx.x;
  const int jh = tid & 15, ih = tid >> 4;
  const int bh = blockIdx.y;
  const int h = bh & 15;
  const int q0 = blockIdx.x * QT;
  const float slope = exp2f(-0.5f * (float)(h + 1));
  const float rsD = 0.08838834764831845f;
  {
    const float* Qg = Q + ((size_t)bh * T + q0) * 128;
    const int r = tid >> 3, p = tid & 7;
#pragma unroll
    for (int u = 0; u < 4; ++u)
      *(float4*)&Qs[r][(p + 8 * u) * 4] = *(const float4*)&Qg[r * 128 + (p + 8 * u) * 4];
  }
  float m_st[2] = {-1e30f, -1e30f};
  float l_st[2] = {0.f, 0.f};
  float accv[2][8] = {};
  const int ktiles = blockIdx.x + 1;
  for (int kt = 0; kt < ktiles; ++kt) {
    const int j0 = kt * KT;
    const float* Kg = K + ((size_t)bh * T + j0) * 128;
    const float* Vg = V + ((size_t)bh * T + j0) * 128;
    __syncthreads();
    {
      const int r = tid >> 3, p = tid & 7;
#pragma unroll
      for (int u = 0; u < 4; ++u) {
        *(float4*)&Ks[r][(p + 8 * u) * 4] = *(const float4*)&Kg[r * 128 + (p + 8 * u) * 4];
        *(float4*)&Vs[r][(p + 8 * u) * 4] = *(const float4*)&Vg[r * 128 + (p + 8 * u) * 4];
      }
    }
    __syncthreads();
    float s00 = 0.f, s01 = 0.f, s10 = 0.f, s11 = 0.f;
#pragma unroll 8
    for (int d4 = 0; d4 < 32; ++d4) {
      const float4 qa = *(const float4*)&Qs[2 * ih + 0][4 * d4];
      const float4 qb = *(const float4*)&Qs[2 * ih + 1][4 * d4];
      const float4 ka = *(const float4*)&Ks[2 * jh + 0][4 * d4];
      const float4 kb = *(const float4*)&Ks[2 * jh + 1][4 * d4];
      s00 += qa.x * ka.x + qa.y * ka.y + qa.z * ka.z + qa.w * ka.w;
      s01 += qa.x * kb.x + qa.y * kb.y + qa.z * kb.z + qa.w * kb.w;
      s10 += qb.x * ka.x + qb.y * ka.y + qb.z * ka.z + qb.w * ka.w;
      s11 += qb.x * kb.x + qb.y * kb.y + qb.z * kb.z + qb.w * kb.w;
    }
    float sc[2][2] = {{s00, s01}, {s10, s11}};
    float mt[2];
#pragma unroll
    for (int r = 0; r < 2; ++r) {
      const int qg = q0 + 2 * ih + r;
#pragma unroll
      for (int c = 0; c < 2; ++c) {
        const int jg = j0 + 2 * jh + c;
        const float svv = sc[r][c] * rsD + slope * (float)(jg - (T - 1));
        sc[r][c] = (jg > qg) ? -1e30f : svv;
      }
      mt[r] = fmaxf(sc[r][0], sc[r][1]);
    }
#pragma unroll
    for (int m = 1; m < 16; m <<= 1) {
      mt[0] = fmaxf(mt[0], __shfl_xor(mt[0], m));
      mt[1] = fmaxf(mt[1], __shfl_xor(mt[1], m));
    }
#pragma unroll
    for (int r = 0; r < 2; ++r) {
      const float mnew = fmaxf(m_st[r], mt[r]);
      const float scl = (m_st[r] > -1e29f) ? expf(m_st[r] - mnew) : 0.f;
      const float p0 = expf(sc[r][0] - mnew);
      const float p1 = expf(sc[r][1] - mnew);
      float rs = p0 + p1;
#pragma unroll
      for (int m = 1; m < 16; m <<= 1) rs += __shfl_xor(rs, m);
      l_st[r] = l_st[r] * scl + rs;
      m_st[r] = mnew;
#pragma unroll
      for (int d = 0; d < 8; ++d) accv[r][d] *= scl;
      Ps[2 * ih + r][2 * jh + 0] = p0;
      Ps[2 * ih + r][2 * jh + 1] = p1;
    }
    __syncthreads();
#pragma unroll 4
    for (int j = 0; j < KT; ++j) {
      const float p0 = Ps[2 * ih + 0][j];
      const float p1 = Ps[2 * ih + 1][j];
      const float4 v0 = *(const float4*)&Vs[j][8 * jh];
      const float4 v1 = *(const float4*)&Vs[j][8 * jh + 4];
      accv[0][0] += p0 * v0.x; accv[0][1] += p0 * v0.y;
      accv[0][2] += p0 * v0.z; accv[0][3] += p0 * v0.w;
      accv[0][4] += p0 * v1.x; accv[0][5] += p0 * v1.y;
      accv[0][6] += p0 * v1.z; accv[0][7] += p0 * v1.w;
      accv[1][0] += p1 * v0.x; accv[1][1] += p1 * v0.y;
      accv[1][2] += p1 * v0.z; accv[1][3] += p1 * v0.w;
      accv[1][4] += p1 * v1.x; accv[1][5] += p1 * v1.y;
      accv[1][6] += p1 * v1.z; accv[1][7] += p1 * v1.w;
    }
  }
  const int b = bh >> 4;
#pragma unroll
  for (int r = 0; r < 2; ++r) {
    const int qg = q0 + 2 * ih + r;
    const float inv = 1.0f / l_st[r];
    float4 o0, o1;
    o0.x = accv[r][0] * inv; o0.y = accv[r][1] * inv;
    o0.z = accv[r][2] * inv; o0.w = accv[r][3] * inv;
    o1.x = accv[r][4] * inv; o1.y = accv[r][5] * inv;
    o1.z = accv[r][6] * inv; o1.w = accv[r][7] * inv;
    float* dst = O + ((size_t)b * T + qg) * 2048 + h * 128 + 8 * jh;
    *(float4*)&dst[0] = o0;
    *(float4*)&dst[4] = o1;
  }
}

// ============================================================================
extern "C" void kernel_launch(void* const* d_in, const int* in_sizes, int n_in,
                              void* d_out, int out_size, void* d_ws,
                              size_t ws_size, hipStream_t stream) {
  const float* x  = (const float*)d_in[0];
  const float* Wq = (const float*)d_in[1];
  const float* bq = (const float*)d_in[2];
  const float* Wk = (const float*)d_in[3];
  const float* bk = (const float*)d_in[4];
  const float* Wv = (const float*)d_in[5];
  const float* bv = (const float*)d_in[6];
  const float* Wo = (const float*)d_in[7];
  const float* bo = (const float*)d_in[8];
  float* out = (float*)d_out;

  const int C = 2048, T = 2048, H = 16;
  const int M = in_sizes[0] / C;  // B*T
  const int B = M / T;
  const int BH = B * H;
  const size_t MC = (size_t)M * C, CC = (size_t)C * C;
  const size_t splitO = (size_t)BH * 16 * 2 * 8192;        // f32 elems
  const size_t splitML = (size_t)BH * 16 * 2 * 64;         // f32 elems
  const size_t need = (5 * MC + 4 * CC) * sizeof(u16) +
                      (splitO + 2 * splitML) * sizeof(float);

  // rsD * log2(e): puts QK^T logits in exp2 domain
  const float QSC = 0.08838834764831845f * 1.44269504088896f;

  if (ws_size >= need && (M % 256) == 0) {
    u16* p = (u16*)d_ws;
    u16* xh   = p; p += MC;
    u16* wqth = p; p += CC;   // wqth/wkth contiguous -> merged QK GEMM
    u16* wkth = p; p += CC;
    u16* wvth = p; p += CC;
    u16* woth = p; p += CC;
    u16* qh   = p; p += MC;
    u16* kh   = p; p += MC;
    u16* vth  = p; p += MC;
    u16* oh   = p; p += MC;
    float* Obuf = (float*)p;
    float* mArr = Obuf + splitO;
    float* lArr = mArr + splitML;

    split_f32<<<1024, 256, 0, stream>>>(x, xh, (int)(MC / 4));
    dim3 tg(C / 64, C / 64, 4);
    tsplit4_f32<<<tg, 256, 0, stream>>>(Wq, Wk, Wv, Wo, wqth, wkth, wvth,
                                        woth, C, C, QSC);

    // merged Q+K projection: [M x 4096] = xh @ [wqth|wkth]^T
    // 256x128 tiles -> (32,16) = 512 blocks -> 2 blocks/CU
    dim3 gqk(2 * C / 128, M / 256);
    gemm256x128<3><<<gqk, 512, 0, stream>>>(xh, wqth, bq, bk, QSC, qh, kh,
                                            nullptr, M, 2 * C, C);
    // V^T = Wv^T @ x^T : out [C][M] (+bv by row) — (32,8) = 256 blocks
    dim3 gv(M / 128, C / 256);
    gemm256x128<2><<<gv, 512, 0, stream>>>(wvth, xh, bv, nullptr, 1.f, vth,
                                           nullptr, nullptr, C, M, C);

    attn_splitk<<<96 * BH, 64, 0, stream>>>(qh, kh, vth, oh, Obuf, mArr,
                                            lArr, T, M, BH);
    combine_halves<<<BH * 16 * 64, 128, 0, stream>>>(Obuf, mArr, lArr, oh, T);

    // final o @ Wo — (16,16) = 256 blocks
    dim3 gq(C / 128, M / 256);
    gemm256x128<0><<<gq, 512, 0, stream>>>(oh, woth, bo, nullptr, 1.f,
                                           nullptr, nullptr, out, M, C, C);
  } else {
    // f32 fallback (round-0 path)
    float* Qw = (float*)d_ws;
    float* Kw = Qw + MC;
    float* Vw = Kw + MC;
    float* Ow = Vw + MC;
    dim3 ggrid(C / TM, M / TM);
    gemm_f32<1><<<ggrid, 256, 0, stream>>>(x, Wq, bq, Qw, M, C, C, T);
    gemm_f32<1><<<ggrid, 256, 0, stream>>>(x, Wk, bk, Kw, M, C, C, T);
    gemm_f32<1><<<ggrid, 256, 0, stream>>>(x, Wv, bv, Vw, M, C, C, T);
    dim3 fgrid(T / QT, B * H);
    flash_f32<<<fgrid, 256, 0, stream>>>(Qw, Kw, Vw, Ow, T);
    gemm_f32<0><<<ggrid, 256, 0, stream>>>(Ow, Wo, bo, out, M, C, C, T);
  }
}

// Round 16
// 277.553 us; speedup vs baseline: 1.0578x; 1.0145x over previous
//
#include <hip/hip_runtime.h>
#include <math.h>

// ============================================================================
// CausalAttention (B=2, T=2048, C=2048, H=16, D=128) with ALiBi.
// Round 30: T1 XCD-aware grid swizzle on all three GEMMs (pure index
// permutation, zero correctness risk). QK FETCH 74MB vs 33.6MB unique =
// 2.2x over-fetch: consecutive blocks sharing an A-panel round-robin onto
// 8 different XCD L2s. swz=(lin&7)*q+(lin>>3) (bijective; all grids %8==0)
// gives each XCD a contiguous output chunk -> A-panels L2-resident.
// Everything else = r27/r29 anchor (279.6-281.6us; QK 84 @ MfmaUtil 34%,
// attn <84 with pair-ILP).
// ============================================================================

typedef unsigned short u16;
using bf16x8 = __attribute__((ext_vector_type(8))) short;
using f32x4  = __attribute__((ext_vector_type(4))) float;

__device__ __forceinline__ u16 f2bf(float f) {
  union { float f; unsigned u; } c; c.f = f;
  unsigned r = c.u + 0x7fffu + ((c.u >> 16) & 1u);   // RTN-even
  return (u16)(r >> 16);
}
__device__ __forceinline__ float bf2f(u16 b) {
  union { unsigned u; float f; } c; c.u = ((unsigned)b) << 16; return c.f;
}
__device__ __forceinline__ unsigned cvtpk(float a, float b) {
  unsigned r;
  asm("v_cvt_pk_bf16_f32 %0, %1, %2" : "=v"(r) : "v"(a), "v"(b));
  return r;
}
__device__ __forceinline__ void g2l16(const void* g, void* l) {
  __builtin_amdgcn_global_load_lds(
      (const __attribute__((address_space(1))) void*)g,
      (__attribute__((address_space(3))) void*)l, 16, 0, 0);
}

// band: drop tiles whose every column is > dist below the strip's first row
__device__ __forceinline__ int band_jmin(int s, float slope2) {
  const int idist = (int)(36.0f / slope2);
  const int cut = 64 * s - idist - 31;
  return (cut > 0) ? (cut >> 5) : 0;
}

// heaviest-first unit order: units sorted by serial tile count descending.
__device__ const unsigned char uord[48] = {
  15, 16, 32, 17, 33, 14, 18, 34, 19, 35,
  13, 20, 36, 21, 37, 12, 22, 38, 23, 39,
  11, 24, 40, 25, 41, 10, 26, 42, 27, 43,
   9, 28, 44, 29, 45,  8, 30, 46, 31, 47,
   7,  6,  5,  4,  3,  2,  1,  0};

// ---------------------------------------------------------------------------
// f32 -> bf16 cast, vectorized
// ---------------------------------------------------------------------------
__global__ __launch_bounds__(256) void split_f32(const float* __restrict__ in,
                                                 u16* __restrict__ hi, int n4) {
  for (int i = blockIdx.x * 256 + threadIdx.x; i < n4; i += gridDim.x * 256) {
    const float4 v = ((const float4*)in)[i];
    ushort4 h;
    h.x = f2bf(v.x); h.y = f2bf(v.y); h.z = f2bf(v.z); h.w = f2bf(v.w);
    ((ushort4*)hi)[i] = h;
  }
}

// ---------------------------------------------------------------------------
// Fused transpose + scale + cast for all 4 weights: z selects the matrix.
// ---------------------------------------------------------------------------
__global__ __launch_bounds__(256) void tsplit4_f32(
    const float* __restrict__ W0, const float* __restrict__ W1,
    const float* __restrict__ W2, const float* __restrict__ W3,
    u16* __restrict__ D0, u16* __restrict__ D1,
    u16* __restrict__ D2, u16* __restrict__ D3,
    int N, int K, float sc0) {
  __shared__ float tile[64][68];
  const int z = blockIdx.z;
  const float* W = (z == 0) ? W0 : (z == 1) ? W1 : (z == 2) ? W2 : W3;
  u16* Wth = (z == 0) ? D0 : (z == 1) ? D1 : (z == 2) ? D2 : D3;
  const float sc = (z == 0) ? sc0 : 1.f;
  const int tid = threadIdx.x;
  const int k0 = blockIdx.y * 64, n0 = blockIdx.x * 64;
  const int rr = tid >> 4, cc = (tid & 15) * 4;
#pragma unroll
  for (int u = 0; u < 4; ++u) {
    const float4 v = *(const float4*)&W[(size_t)(k0 + rr + 16 * u) * N + n0 + cc];
    tile[rr + 16 * u][cc + 0] = v.x;
    tile[rr + 16 * u][cc + 1] = v.y;
    tile[rr + 16 * u][cc + 2] = v.z;
    tile[rr + 16 * u][cc + 3] = v.w;
  }
  __syncthreads();
#pragma unroll
  for (int u = 0; u < 4; ++u) {
    const int nn = rr + 16 * u;
    ushort4 h;
    h.x = f2bf(tile[cc + 0][nn] * sc);
    h.y = f2bf(tile[cc + 1][nn] * sc);
    h.z = f2bf(tile[cc + 2][nn] * sc);
    h.w = f2bf(tile[cc + 3][nn] * sc);
    *(ushort4*)&Wth[(size_t)(n0 + nn) * K + k0 + cc] = h;
  }
}

// ---------------------------------------------------------------------------
// 256x128-tile bf16 GEMM, BK=32, ring-3 LDS, counted vmcnt (r18 proven).
// r30: XCD-aware block swizzle (bijective; grid %8==0) -> each XCD gets a
// contiguous chunk of output tiles, A-panels stay in one L2.
// MODE 0: f32 out (+bias[col]*bsc); MODE 2: bf16 out (+bias[row]*bsc);
// MODE 3: merged QK scatter (+bias[col&2047]*bsc or bias2).
// ---------------------------------------------------------------------------
template <int MODE>
__global__ __launch_bounds__(512, 4) void gemm256x128(
    const u16* __restrict__ Ah, const u16* __restrict__ Bth,
    const float* __restrict__ bias, const float* __restrict__ bias2,
    float bsc, u16* __restrict__ outH, u16* __restrict__ outH2,
    float* __restrict__ outF, int MM, int NN, int KK) {
  __shared__ u16 LA[3][8192];   // ring: 256 rows x 32 (64B rows)
  __shared__ u16 LB[3][4096];   // ring: 128 rows x 32

  const int tid = threadIdx.x;
  const int wave = tid >> 6, lane = tid & 63;
  const int g = lane >> 4, q15 = lane & 15;
  const int wr = wave >> 1, wc = wave & 1;     // 4M x 2N
  // XCD-aware swizzle: linear id round-robins across XCDs (mod 8);
  // swz gives XCD x the contiguous chunk [x*q8, (x+1)*q8).
  const int nwg = gridDim.x * gridDim.y;
  const int lin = blockIdx.y * gridDim.x + blockIdx.x;
  const int q8 = nwg >> 3;
  const int swz = (lin & 7) * q8 + (lin >> 3);
  const int bx = swz % gridDim.x, by = swz / gridDim.x;
  const int m0 = by * 256, n0 = bx * 128;
  const int NT = KK >> 5;
  const int sxg = ((g ^ ((q15 >> 1) & 3)) << 4);

  f32x4 acc[4][4];
#pragma unroll
  for (int f = 0; f < 4; ++f)
#pragma unroll
    for (int j = 0; j < 4; ++j) acc[f][j] = (f32x4){0.f, 0.f, 0.f, 0.f};

  auto stageA = [&](int t, int rbuf) {
#pragma unroll
    for (int l = 0; l < 2; ++l) {
      const int ch = l * 512 + tid;
      const int row = ch >> 2, slot = ch & 3;
      const size_t ga = (size_t)(m0 + row) * KK + t * 32 +
                        ((slot ^ ((row >> 1) & 3)) * 8);
      g2l16(Ah + ga, (char*)(LA[rbuf]) + ch * 16);
    }
  };
  auto stageB = [&](int t, int rbuf) {
    const int ch = tid;
    const int row = ch >> 2, slot = ch & 3;
    const size_t gb = (size_t)(n0 + row) * KK + t * 32 +
                      ((slot ^ ((row >> 1) & 3)) * 8);
    g2l16(Bth + gb, (char*)(LB[rbuf]) + ch * 16);
  };

  // prologue: stage tiles 0,1 (6 ops/thread), drain tile 0 only
  stageA(0, 0); stageB(0, 0);
  __builtin_amdgcn_sched_barrier(0);
  if (NT > 1) { stageA(1, 1); stageB(1, 1); }
  __builtin_amdgcn_sched_barrier(0);
  if (NT > 1) { asm volatile("s_waitcnt vmcnt(3)" ::: "memory"); }
  else        { asm volatile("s_waitcnt vmcnt(0)" ::: "memory"); }
  __builtin_amdgcn_sched_barrier(0);
  __builtin_amdgcn_s_barrier();

  int rb = 0, rb2 = 2;
  for (int t = 0; t < NT; ++t) {
    const char* baseA = (const char*)(LA[rb]);
    const char* baseB = (const char*)(LB[rb]);

    bf16x8 af[4], bf[4];
#pragma unroll
    for (int f = 0; f < 4; ++f)
      af[f] = *(const bf16x8*)(baseA + (wr * 64 + f * 16 + q15) * 64 + sxg);
#pragma unroll
    for (int j = 0; j < 4; ++j)
      bf[j] = *(const bf16x8*)(baseB + (wc * 64 + j * 16 + q15) * 64 + sxg);
    if (t + 2 < NT) { stageA(t + 2, rb2); stageB(t + 2, rb2); }
    __builtin_amdgcn_sched_barrier(0);
    __builtin_amdgcn_s_barrier();
    asm volatile("s_waitcnt lgkmcnt(0)" ::: "memory");
    __builtin_amdgcn_sched_barrier(0);
    __builtin_amdgcn_s_setprio(1);
#pragma unroll
    for (int f = 0; f < 4; ++f)
#pragma unroll
      for (int j = 0; j < 4; ++j)
        acc[f][j] = __builtin_amdgcn_mfma_f32_16x16x32_bf16(
            af[f], bf[j], acc[f][j], 0, 0, 0);
    __builtin_amdgcn_s_setprio(0);
    if (t + 1 < NT) {
      if (t + 2 < NT) { asm volatile("s_waitcnt vmcnt(3)" ::: "memory"); }
      else            { asm volatile("s_waitcnt vmcnt(0)" ::: "memory"); }
    }
    __builtin_amdgcn_sched_barrier(0);
    __builtin_amdgcn_s_barrier();
    rb  = (rb  == 2) ? 0 : rb  + 1;
    rb2 = (rb2 == 2) ? 0 : rb2 + 1;
  }

#pragma unroll
  for (int f = 0; f < 4; ++f)
#pragma unroll
    for (int j = 0; j < 4; ++j)
#pragma unroll
      for (int r = 0; r < 4; ++r) {
        const int row = m0 + wr * 64 + f * 16 + g * 4 + r;
        const int col = n0 + wc * 64 + j * 16 + q15;
        const float v = acc[f][j][r];
        if (MODE == 0) {
          outF[(size_t)row * NN + col] = v + bias[col] * bsc;
        } else if (MODE == 2) {
          outH[(size_t)row * NN + col] = f2bf(v + bias[row] * bsc);
        } else {  // MODE 3: merged QK scatter
          const int sel = col >> 11;
          const int c2 = col & 2047;
          const float vv = v + (sel ? bias2[c2] : bias[c2] * bsc);
          const int bb = row >> 11, tt = row & 2047;
          const int hh = c2 >> 7, dd = c2 & 127;
          (sel ? outH2 : outH)[(((size_t)bb * 16 + hh) * 2048 + tt) * 128 + dd] =
              f2bf(vv);
        }
      }
}

// ---------------------------------------------------------------------------
// Banded split-K flash attention with ALiBi. r27: tile-pair ILP on top of
// the r24/r26 structure (1-wave blocks, XCD-pair decode, uord, setprio,
// K LDS ring-3, V reg-dbuf, counted vmcnt).
// ---------------------------------------------------------------------------
__global__ __launch_bounds__(64) void attn_splitk(
    const u16* __restrict__ Qh, const u16* __restrict__ Kh,
    const u16* __restrict__ Vth, u16* __restrict__ Oh,
    float* __restrict__ Obuf, float* __restrict__ mArr,
    float* __restrict__ lArr, int T, int NB, int BH) {
  __shared__ u16 KS[3][4096];   // 32 x 128, 256B rows, XOR ((row&7)<<4)

  const int tid = threadIdx.x;
  const int lane = tid & 63;
  const int g = lane >> 4, q15 = lane & 15;
  const int L = blockIdx.x;
  // XCD-co-located pair decode: halves are (L, L+8) -> same XCD (mod 8)
  const int LL = (L & 7) | ((L >> 4) << 3);
  const int wid = (L >> 3) & 1;

  int bh, u;
  if (BH == 32) {
    const int k = LL >> 8;       // round 0..5
    const int c = LL & 255;      // CU-slot within round
    bh = (c + 5 * k) & 31;
    u = uord[k * 8 + (c >> 5)];
  } else {
    bh = LL / 48;
    u = uord[LL % 48];
  }
  int s, half;
  if (u < 16)      { s = u;      half = 2; }   // full strip
  else if (u < 32) { s = 47 - u; half = 0; }   // low half (no diagonal)
  else             { s = 63 - u; half = 1; }   // high half (diagonal)

  const int b = bh >> 4, h = bh & 15;
  const float slope2 = exp2f(-0.5f * (float)(h + 1)) * 1.44269504f;
  const int jmin = band_jmin(s, slope2);
  const bool loEmpty = (jmin >= s + 1);

  if (half == 0 && loEmpty) return;            // nothing to do

  int lo, hi;
  if (half == 2)      { lo = jmin;                hi = 2 * s + 2; }
  else if (half == 0) { lo = jmin;                hi = s + 1; }
  else                { lo = loEmpty ? jmin : (s + 1); hi = 2 * s + 2; }
  const int ns = hi - lo;                      // >= 1
  const bool maskable = (half != 0);
  const bool normStore = (half == 2) || (half == 1 && loEmpty);

  const int qw0 = s * 64 + wid * 32;
  const size_t vrow0 = (size_t)h * 128;
  const size_t vcol0 = (size_t)b * T;
  const size_t kbase = (size_t)bh * T;

  // ---- Q loads (8 globals, issued first / oldest in vmcnt order) ----
  bf16x8 qfr[2][4];
#pragma unroll
  for (int qf2 = 0; qf2 < 2; ++qf2) {
    const size_t rb = ((size_t)bh * T + qw0 + qf2 * 16 + q15) * 128;
#pragma unroll
    for (int ks = 0; ks < 4; ++ks)
      qfr[qf2][ks] = *(const bf16x8*)&Qh[rb + ks * 32 + g * 8];
  }

  f32x4 oacc[2][8];
#pragma unroll
  for (int a = 0; a < 2; ++a)
#pragma unroll
    for (int n = 0; n < 8; ++n) oacc[a][n] = (f32x4){0.f, 0.f, 0.f, 0.f};
  float m_st[2] = {-1e5f, -1e5f};
  float l_part[2] = {0.f, 0.f};

  // stage one 32x128 K tile (8KB = 8 chunks of 1KB), all by this wave
  auto stageK = [&](int jt, int bf) {
    const int j0 = jt * 32;
#pragma unroll
    for (int c = 0; c < 8; ++c) {
      const int row = c * 4 + g;
      const int off = (q15 * 16) ^ ((row & 7) << 4);
      const size_t gb = (kbase + j0 + row) * 128;
      g2l16((const char*)(Kh + gb) + off, (char*)(KS[bf]) + c * 1024);
    }
  };
  auto loadV = [&](int jt, bf16x8 (&vf)[8]) {
    const int j0 = jt * 32;
#pragma unroll
    for (int nf = 0; nf < 8; ++nf)
      vf[nf] = *(const bf16x8*)
          &Vth[(vrow0 + nf * 16 + q15) * (size_t)NB + vcol0 + j0 + g * 8];
  };
  // QK^T for one tile from KS[slot] into sacc
  auto QKT = [&](int slot, f32x4 (&sacc)[2][2]) {
#pragma unroll
    for (int jf = 0; jf < 2; ++jf)
#pragma unroll
      for (int qf2 = 0; qf2 < 2; ++qf2) sacc[jf][qf2] = (f32x4){0.f, 0.f, 0.f, 0.f};
#pragma unroll
    for (int ks = 0; ks < 4; ++ks) {
      bf16x8 ka[2];
#pragma unroll
      for (int jf = 0; jf < 2; ++jf) {
        const int row = jf * 16 + q15;
        const int off = (row * 256 + ks * 64 + g * 16) ^ ((row & 7) << 4);
        ka[jf] = *(const bf16x8*)((const char*)(KS[slot]) + off);
      }
#pragma unroll
      for (int jf = 0; jf < 2; ++jf)
#pragma unroll
        for (int qf2 = 0; qf2 < 2; ++qf2)
          sacc[jf][qf2] = __builtin_amdgcn_mfma_f32_16x16x32_bf16(
              ka[jf], qfr[qf2][ks], sacc[jf][qf2], 0, 0, 0);
    }
  };
  // softmax + PV for one tile (no internal waits; V must be drained)
  auto SOFTPV = [&](int it, int j0, f32x4 (&sacc)[2][2], bf16x8 (&vc)[8]) {
    const float jb2 = (float)(j0 + 4 * g - (T - 1));
    unsigned Fw[2][4];
#pragma unroll
    for (int qf2 = 0; qf2 < 2; ++qf2) {
      const int qg = qw0 + qf2 * 16 + q15;
      float sv[2][4];
      float mt = -1e30f;
#pragma unroll
      for (int jf = 0; jf < 2; ++jf)
#pragma unroll
        for (int r = 0; r < 4; ++r) {
          float x = fmaf(slope2, jb2 + (float)(jf * 16 + r), sacc[jf][qf2][r]);
          if (maskable && it < 2) {
            const int jg = j0 + jf * 16 + 4 * g + r;
            x = (jg > qg) ? -1e30f : x;
          }
          sv[jf][r] = x;
          mt = fmaxf(mt, x);
        }
      if (!__all(mt <= m_st[qf2] + 11.0f)) {
        mt = fmaxf(mt, __shfl_xor(mt, 16));
        mt = fmaxf(mt, __shfl_xor(mt, 32));
        const float mnew = fmaxf(m_st[qf2], mt);
        const float scl = exp2f(m_st[qf2] - mnew);
        l_part[qf2] *= scl;
        m_st[qf2] = mnew;
#pragma unroll
        for (int r = 0; r < 4; ++r) {
          const float sc = __shfl(scl, g * 4 + r);
#pragma unroll
          for (int nf = 0; nf < 8; ++nf) oacc[qf2][nf][r] *= sc;
        }
      }
      float rs = 0.f;
      float p[2][4];
#pragma unroll
      for (int jf = 0; jf < 2; ++jf)
#pragma unroll
        for (int r = 0; r < 4; ++r) {
          p[jf][r] = exp2f(sv[jf][r] - m_st[qf2]);
          rs += p[jf][r];
        }
      l_part[qf2] += rs;
      const unsigned W00 = cvtpk(p[0][0], p[0][1]), W01 = cvtpk(p[0][2], p[0][3]);
      const unsigned W10 = cvtpk(p[1][0], p[1][1]), W11 = cvtpk(p[1][2], p[1][3]);
      const int srcA = q15 + ((g & 1) << 5);
      const int srcB = srcA + 16;
      const unsigned A0 = (unsigned)__shfl((int)W00, srcA);
      const unsigned A1 = (unsigned)__shfl((int)W01, srcA);
      const unsigned B0 = (unsigned)__shfl((int)W00, srcB);
      const unsigned B1 = (unsigned)__shfl((int)W01, srcB);
      const unsigned C0 = (unsigned)__shfl((int)W10, srcA);
      const unsigned C1 = (unsigned)__shfl((int)W11, srcA);
      const unsigned D0 = (unsigned)__shfl((int)W10, srcB);
      const unsigned D1 = (unsigned)__shfl((int)W11, srcB);
      const bool hi2 = g >= 2;
      Fw[qf2][0] = hi2 ? C0 : A0;
      Fw[qf2][1] = hi2 ? C1 : A1;
      Fw[qf2][2] = hi2 ? D0 : B0;
      Fw[qf2][3] = hi2 ? D1 : B1;
    }
    union { unsigned uu[4]; bf16x8 v; } pa0, pa1;
#pragma unroll
    for (int w = 0; w < 4; ++w) { pa0.uu[w] = Fw[0][w]; pa1.uu[w] = Fw[1][w]; }
    __builtin_amdgcn_s_setprio(1);
#pragma unroll
    for (int nf = 0; nf < 8; ++nf) {
      oacc[0][nf] = __builtin_amdgcn_mfma_f32_16x16x32_bf16(pa0.v, vc[nf], oacc[0][nf], 0, 0, 0);
      oacc[1][nf] = __builtin_amdgcn_mfma_f32_16x16x32_bf16(pa1.v, vc[nf], oacc[1][nf], 0, 0, 0);
    }
    __builtin_amdgcn_s_setprio(0);
  };

  // ---- prologue: pinned issue order [Q][K0,K1][V0] ----
  bf16x8 vfA[8], vfB[8];
  __builtin_amdgcn_sched_barrier(0);
  stageK(hi - 1, 0);
  if (ns > 1) stageK(hi - 2, 1);
  __builtin_amdgcn_sched_barrier(0);
  loadV(hi - 1, vfA);
  // outstanding: ns>1: Q(8)+K0(8)+K1(8)+V0(8)=32 -> vmcnt(16) drains Q,K0
  //              ns==1: Q(8)+K0(8)+V0(8)=24      -> vmcnt(8)  drains Q,K0
  if (ns > 1) { asm volatile("s_waitcnt vmcnt(16)" ::: "memory"); }
  else        { asm volatile("s_waitcnt vmcnt(8)"  ::: "memory"); }
  __builtin_amdgcn_sched_barrier(0);

  int cur = 0;   // slot of tile it: it % 3

  int it = 0;
  while (it + 2 <= ns) {
    // ---- pair (t0=it, t1=it+1); entry: vfA=V(t0); outstanding {V(t0),K(t0+1)}
    const int jt0 = hi - 1 - it, jt1 = jt0 - 1;
    const int j0a = jt0 * 32, j0b = jt1 * 32;
    const int cur1 = (cur == 2) ? 0 : cur + 1;
    const int cur2 = (cur1 == 2) ? 0 : cur1 + 1;
    const bool e2 = (it + 2 < ns);
    const bool e3 = (it + 3 < ns);

    // sub0 issues: V(t1)->vfB [8], K(t0+2)->cur2 [8 if e2]
    loadV(jt1, vfB);
    if (e2) stageK(jt0 - 2, cur2);
    __builtin_amdgcn_sched_barrier(0);
    if (e2) { asm volatile("s_waitcnt vmcnt(16)" ::: "memory"); }
    else    { asm volatile("s_waitcnt vmcnt(8)"  ::: "memory"); }
    __builtin_amdgcn_sched_barrier(0);

    // QK for BOTH tiles: QK(t1) MFMAs drain under SM(t0)'s VALU below.
    f32x4 sacc0[2][2], sacc1[2][2];
    __builtin_amdgcn_s_setprio(1);
    QKT(cur, sacc0);
    QKT(cur1, sacc1);
    __builtin_amdgcn_s_setprio(0);

    SOFTPV(it, j0a, sacc0, vfA);       // uses V(t0) (drained)

    // sub1 issues (after PV(t0) consumed vfA): V(t0+2)->vfA, K(t0+3)->cur
    if (e2) loadV(jt0 - 2, vfA);
    if (e3) stageK(jt0 - 3, cur);
    __builtin_amdgcn_sched_barrier(0);
    if (e2 && e3)      { asm volatile("s_waitcnt vmcnt(16)" ::: "memory"); }
    else if (e2)       { asm volatile("s_waitcnt vmcnt(8)"  ::: "memory"); }
    else               { asm volatile("s_waitcnt vmcnt(0)"  ::: "memory"); }
    __builtin_amdgcn_sched_barrier(0);

    SOFTPV(it + 1, j0b, sacc1, vfB);   // uses V(t1) (drained)

    cur = cur2;  // cur advanced by 2 (mod 3)
    it += 2;
  }
  if (it < ns) {
    // singleton tail: outstanding {V(it)} (or V0 for ns==1); no prefetch
    const int jt = hi - 1 - it;
    asm volatile("s_waitcnt vmcnt(0)" ::: "memory");
    __builtin_amdgcn_sched_barrier(0);
    f32x4 sacc0[2][2];
    __builtin_amdgcn_s_setprio(1);
    QKT(cur, sacc0);
    __builtin_amdgcn_s_setprio(0);
    SOFTPV(it, jt * 32, sacc0, vfA);
  }

  // ---- epilogue ----
  float lrow[2];
#pragma unroll
  for (int qf2 = 0; qf2 < 2; ++qf2) {
    float lr = l_part[qf2];
    lr += __shfl_xor(lr, 16);
    lr += __shfl_xor(lr, 32);
    lrow[qf2] = lr;
  }

  if (normStore) {
#pragma unroll
    for (int qf2 = 0; qf2 < 2; ++qf2) {
      const float inv = 1.0f / lrow[qf2];
#pragma unroll
      for (int r = 0; r < 4; ++r) {
        const float iv = __shfl(inv, g * 4 + r);
        const int qrow = qw0 + qf2 * 16 + g * 4 + r;
        const size_t ob = ((size_t)b * T + qrow) * 2048 + h * 128;
#pragma unroll
        for (int nf = 0; nf < 8; ++nf)
          Oh[ob + nf * 16 + q15] = f2bf(oacc[qf2][nf][r] * iv);
      }
    }
  } else {
    const int sp = s - 16;
    const size_t sbase = ((size_t)(bh * 16 + sp) * 2 + half) * 64;
    if (g == 0) {
#pragma unroll
      for (int qf2 = 0; qf2 < 2; ++qf2) {
        mArr[sbase + wid * 32 + qf2 * 16 + q15] = m_st[qf2];
        lArr[sbase + wid * 32 + qf2 * 16 + q15] = lrow[qf2];
      }
    }
    const size_t obase = sbase * 128;
#pragma unroll
    for (int qf2 = 0; qf2 < 2; ++qf2)
#pragma unroll
      for (int r = 0; r < 4; ++r) {
        const int row = wid * 32 + qf2 * 16 + g * 4 + r;
#pragma unroll
        for (int nf = 0; nf < 8; ++nf)
          Obuf[obase + (size_t)row * 128 + nf * 16 + q15] = oacc[qf2][nf][r];
      }
  }
}

// ---------------------------------------------------------------------------
// Combine split-K halves; skips strips whose low half was band-empty.
// ---------------------------------------------------------------------------
__global__ __launch_bounds__(128) void combine_halves(
    const float* __restrict__ Obuf, const float* __restrict__ mArr,
    const float* __restrict__ lArr, u16* __restrict__ Oh, int T) {
  const int idx = blockIdx.x;
  const int row = idx & 63;
  const int sp = (idx >> 6) & 15;
  const int bh = idx >> 10;
  const int d = threadIdx.x;
  const int s = sp + 16;
  const int b = bh >> 4, h = bh & 15;
  const float slope2 = exp2f(-0.5f * (float)(h + 1)) * 1.44269504f;
  if (band_jmin(s, slope2) >= s + 1) return;   // high half stored directly
  const size_t sbase = ((size_t)(bh * 16 + sp) * 2) * 64;
  const float m1 = mArr[sbase + row],      l1 = lArr[sbase + row];
  const float m2 = mArr[sbase + 64 + row], l2 = lArr[sbase + 64 + row];
  const float M = fmaxf(m1, m2);
  const float w1 = exp2f(m1 - M), w2 = exp2f(m2 - M);
  const float inv = 1.0f / (l1 * w1 + l2 * w2);
  const size_t ob = sbase * 128;
  const float o1 = Obuf[ob + (size_t)row * 128 + d];
  const float o2 = Obuf[ob + 8192 + (size_t)row * 128 + d];
  const float v = (o1 * w1 + o2 * w2) * inv;
  const int qrow = s * 64 + row;
  Oh[((size_t)b * T + qrow) * 2048 + h * 128 + d] = f2bf(v);
}

// ============================================================================
// Fallback f32 path (round-0, proven): used only if ws_size is insufficient.
// ============================================================================
#define TM 128
#define BKG 8

template <int QKV>
__global__ __launch_bounds__(256) void gemm_f32(
    const float* __restrict__ A, const float* __restrict__ W,
    const float* __restrict__ bias, float* __restrict__ out,
    int M, int N, int K, int T) {
  __shared__ float As[BKG][TM];
  __shared__ float Bs[BKG][TM];
  const int tid = threadIdx.x;
  const int tx = tid & 15, ty = tid >> 4;
  const int m0 = blockIdx.y * TM, n0 = blockIdx.x * TM;
  float acc[8][8];
#pragma unroll
  for (int i = 0; i < 8; ++i)
#pragma unroll
    for (int j = 0; j < 8; ++j) acc[i][j] = 0.f;
  const int arow = tid >> 1, acol = (tid & 1) * 4;
  const int brow = tid >> 5, bcol = (tid & 31) * 4;
  for (int k0 = 0; k0 < K; k0 += BKG) {
    const float4 av = *(const float4*)&A[(size_t)(m0 + arow) * K + k0 + acol];
    const float4 bv = *(const float4*)&W[(size_t)(k0 + brow) * N + n0 + bcol];
    __syncthreads();
    As[acol + 0][arow] = av.x; As[acol + 1][arow] = av.y;
    As[acol + 2][arow] = av.z; As[acol + 3][arow] = av.w;
    *(float4*)&Bs[brow][bcol] = bv;
    __syncthreads();
#pragma unroll
    for (int kk = 0; kk < BKG; ++kk) {
      const float4 a0 = *(const float4*)&As[kk][ty * 4];
      const float4 a1 = *(const float4*)&As[kk][64 + ty * 4];
      const float4 b0 = *(const float4*)&Bs[kk][tx * 4];
      const float4 b1 = *(const float4*)&Bs[kk][64 + tx * 4];
      const float af[8] = {a0.x, a0.y, a0.z, a0.w, a1.x, a1.y, a1.z, a1.w};
      const float bf[8] = {b0.x, b0.y, b0.z, b0.w, b1.x, b1.y, b1.z, b1.w};
#pragma unroll
      for (int i = 0; i < 8; ++i)
#pragma unroll
        for (int j = 0; j < 8; ++j) acc[i][j] += af[i] * bf[j];
    }
  }
#pragma unroll
  for (int a = 0; a < 2; ++a)
#pragma unroll
    for (int i = 0; i < 4; ++i) {
      const int row = m0 + a * 64 + ty * 4 + i;
      const int bb = row / T, t = row % T;
#pragma unroll
      for (int bj = 0; bj < 2; ++bj) {
        const int col = n0 + bj * 64 + tx * 4;
        float4 r;
        r.x = acc[a * 4 + i][bj * 4 + 0] + bias[col + 0];
        r.y = acc[a * 4 + i][bj * 4 + 1] + bias[col + 1];
        r.z = acc[a * 4 + i][bj * 4 + 2] + bias[col + 2];
        r.w = acc[a * 4 + i][bj * 4 + 3] + bias[col + 3];
        if (QKV) {
          const int hh = col >> 7, dd = col & 127;
          *(float4*)&out[(((size_t)bb * 16 + hh) * T + t) * 128 + dd] = r;
        } else {
          *(float4*)&out[(size_t)row * N + col] = r;
        }
      }
    }
}

#define QT 32
#define KT 32
#define DP 132

__global__ __launch_bounds__(256) void flash_f32(
    const float* __restrict__ Q, const float* __restrict__ K,
    const float* __restrict__ V, float* __restrict__ O, int T) {
  __shared__ float Qs[QT][DP];
  __shared__ float Ks[KT][DP];
  __shared__ float Vs[KT][DP];
  __shared__ float Ps[QT][KT + 1];
  const int tid = threadIdx.x;
  const int jh = tid & 15, ih = tid >> 4;
  const int bh = blockIdx.y;
  const int h = bh & 15;
  const int q0 = blockIdx.x * QT;
  const float slope = exp2f(-0.5f * (float)(h + 1));
  const float rsD = 0.08838834764831845f;
  {
    const float* Qg = Q + ((size_t)bh * T + q0) * 128;
    const int r = tid >> 3, p = tid & 7;
#pragma unroll
    for (int u = 0; u < 4; ++u)
      *(float4*)&Qs[r][(p + 8 * u) * 4] = *(const float4*)&Qg[r * 128 + (p + 8 * u) * 4];
  }
  float m_st[2] = {-1e30f, -1e30f};
  float l_st[2] = {0.f, 0.f};
  float accv[2][8] = {};
  const int ktiles = blockIdx.x + 1;
  for (int kt = 0; kt < ktiles; ++kt) {
    const int j0 = kt * KT;
    const float* Kg = K + ((size_t)bh * T + j0) * 128;
    const float* Vg = V + ((size_t)bh * T + j0) * 128;
    __syncthreads();
    {
      const int r = tid >> 3, p = tid & 7;
#pragma unroll
      for (int u = 0; u < 4; ++u) {
        *(float4*)&Ks[r][(p + 8 * u) * 4] = *(const float4*)&Kg[r * 128 + (p + 8 * u) * 4];
        *(float4*)&Vs[r][(p + 8 * u) * 4] = *(const float4*)&Vg[r * 128 + (p + 8 * u) * 4];
      }
    }
    __syncthreads();
    float s00 = 0.f, s01 = 0.f, s10 = 0.f, s11 = 0.f;
#pragma unroll 8
    for (int d4 = 0; d4 < 32; ++d4) {
      const float4 qa = *(const float4*)&Qs[2 * ih + 0][4 * d4];
      const float4 qb = *(const float4*)&Qs[2 * ih + 1][4 * d4];
      const float4 ka = *(const float4*)&Ks[2 * jh + 0][4 * d4];
      const float4 kb = *(const float4*)&Ks[2 * jh + 1][4 * d4];
      s00 += qa.x * ka.x + qa.y * ka.y + qa.z * ka.z + qa.w * ka.w;
      s01 += qa.x * kb.x + qa.y * kb.y + qa.z * kb.z + qa.w * kb.w;
      s10 += qb.x * ka.x + qb.y * ka.y + qb.z * ka.z + qb.w * ka.w;
      s11 += qb.x * kb.x + qb.y * kb.y + qb.z * kb.z + qb.w * kb.w;
    }
    float sc[2][2] = {{s00, s01}, {s10, s11}};
    float mt[2];
#pragma unroll
    for (int r = 0; r < 2; ++r) {
      const int qg = q0 + 2 * ih + r;
#pragma unroll
      for (int c = 0; c < 2; ++c) {
        const int jg = j0 + 2 * jh + c;
        const float svv = sc[r][c] * rsD + slope * (float)(jg - (T - 1));
        sc[r][c] = (jg > qg) ? -1e30f : svv;
      }
      mt[r] = fmaxf(sc[r][0], sc[r][1]);
    }
#pragma unroll
    for (int m = 1; m < 16; m <<= 1) {
      mt[0] = fmaxf(mt[0], __shfl_xor(mt[0], m));
      mt[1] = fmaxf(mt[1], __shfl_xor(mt[1], m));
    }
#pragma unroll
    for (int r = 0; r < 2; ++r) {
      const float mnew = fmaxf(m_st[r], mt[r]);
      const float scl = (m_st[r] > -1e29f) ? expf(m_st[r] - mnew) : 0.f;
      const float p0 = expf(sc[r][0] - mnew);
      const float p1 = expf(sc[r][1] - mnew);
      float rs = p0 + p1;
#pragma unroll
      for (int m = 1; m < 16; m <<= 1) rs += __shfl_xor(rs, m);
      l_st[r] = l_st[r] * scl + rs;
      m_st[r] = mnew;
#pragma unroll
      for (int d = 0; d < 8; ++d) accv[r][d] *= scl;
      Ps[2 * ih + r][2 * jh + 0] = p0;
      Ps[2 * ih + r][2 * jh + 1] = p1;
    }
    __syncthreads();
#pragma unroll 4
    for (int j = 0; j < KT; ++j) {
      const float p0 = Ps[2 * ih + 0][j];
      const float p1 = Ps[2 * ih + 1][j];
      const float4 v0 = *(const float4*)&Vs[j][8 * jh];
      const float4 v1 = *(const float4*)&Vs[j][8 * jh + 4];
      accv[0][0] += p0 * v0.x; accv[0][1] += p0 * v0.y;
      accv[0][2] += p0 * v0.z; accv[0][3] += p0 * v0.w;
      accv[0][4] += p0 * v1.x; accv[0][5] += p0 * v1.y;
      accv[0][6] += p0 * v1.z; accv[0][7] += p0 * v1.w;
      accv[1][0] += p1 * v0.x; accv[1][1] += p1 * v0.y;
      accv[1][2] += p1 * v0.z; accv[1][3] += p1 * v0.w;
      accv[1][4] += p1 * v1.x; accv[1][5] += p1 * v1.y;
      accv[1][6] += p1 * v1.z; accv[1][7] += p1 * v1.w;
    }
  }
  const int b = bh >> 4;
#pragma unroll
  for (int r = 0; r < 2; ++r) {
    const int qg = q0 + 2 * ih + r;
    const float inv = 1.0f / l_st[r];
    float4 o0, o1;
    o0.x = accv[r][0] * inv; o0.y = accv[r][1] * inv;
    o0.z = accv[r][2] * inv; o0.w = accv[r][3] * inv;
    o1.x = accv[r][4] * inv; o1.y = accv[r][5] * inv;
    o1.z = accv[r][6] * inv; o1.w = accv[r][7] * inv;
    float* dst = O + ((size_t)b * T + qg) * 2048 + h * 128 + 8 * jh;
    *(float4*)&dst[0] = o0;
    *(float4*)&dst[4] = o1;
  }
}

// ============================================================================
extern "C" void kernel_launch(void* const* d_in, const int* in_sizes, int n_in,
                              void* d_out, int out_size, void* d_ws,
                              size_t ws_size, hipStream_t stream) {
  const float* x  = (const float*)d_in[0];
  const float* Wq = (const float*)d_in[1];
  const float* bq = (const float*)d_in[2];
  const float* Wk = (const float*)d_in[3];
  const float* bk = (const float*)d_in[4];
  const float* Wv = (const float*)d_in[5];
  const float* bv = (const float*)d_in[6];
  const float* Wo = (const float*)d_in[7];
  const float* bo = (const float*)d_in[8];
  float* out = (float*)d_out;

  const int C = 2048, T = 2048, H = 16;
  const int M = in_sizes[0] / C;  // B*T
  const int B = M / T;
  const int BH = B * H;
  const size_t MC = (size_t)M * C, CC = (size_t)C * C;
  const size_t splitO = (size_t)BH * 16 * 2 * 8192;        // f32 elems
  const size_t splitML = (size_t)BH * 16 * 2 * 64;         // f32 elems
  const size_t need = (5 * MC + 4 * CC) * sizeof(u16) +
                      (splitO + 2 * splitML) * sizeof(float);

  // rsD * log2(e): puts QK^T logits in exp2 domain
  const float QSC = 0.08838834764831845f * 1.44269504088896f;

  if (ws_size >= need && (M % 256) == 0) {
    u16* p = (u16*)d_ws;
    u16* xh   = p; p += MC;
    u16* wqth = p; p += CC;   // wqth/wkth contiguous -> merged QK GEMM
    u16* wkth = p; p += CC;
    u16* wvth = p; p += CC;
    u16* woth = p; p += CC;
    u16* qh   = p; p += MC;
    u16* kh   = p; p += MC;
    u16* vth  = p; p += MC;
    u16* oh   = p; p += MC;
    float* Obuf = (float*)p;
    float* mArr = Obuf + splitO;
    float* lArr = mArr + splitML;

    split_f32<<<1024, 256, 0, stream>>>(x, xh, (int)(MC / 4));
    dim3 tg(C / 64, C / 64, 4);
    tsplit4_f32<<<tg, 256, 0, stream>>>(Wq, Wk, Wv, Wo, wqth, wkth, wvth,
                                        woth, C, C, QSC);

    // merged Q+K projection: [M x 4096] = xh @ [wqth|wkth]^T
    // 256x128 tiles -> (32,16) = 512 blocks -> 2 blocks/CU, XCD-swizzled
    dim3 gqk(2 * C / 128, M / 256);
    gemm256x128<3><<<gqk, 512, 0, stream>>>(xh, wqth, bq, bk, QSC, qh, kh,
                                            nullptr, M, 2 * C, C);
    // V^T = Wv^T @ x^T : out [C][M] (+bv by row) — (32,8) = 256 blocks
    dim3 gv(M / 128, C / 256);
    gemm256x128<2><<<gv, 512, 0, stream>>>(wvth, xh, bv, nullptr, 1.f, vth,
                                           nullptr, nullptr, C, M, C);

    attn_splitk<<<96 * BH, 64, 0, stream>>>(qh, kh, vth, oh, Obuf, mArr,
                                            lArr, T, M, BH);
    combine_halves<<<BH * 16 * 64, 128, 0, stream>>>(Obuf, mArr, lArr, oh, T);

    // final o @ Wo — (16,16) = 256 blocks
    dim3 gq(C / 128, M / 256);
    gemm256x128<0><<<gq, 512, 0, stream>>>(oh, woth, bo, nullptr, 1.f,
                                           nullptr, nullptr, out, M, C, C);
  } else {
    // f32 fallback (round-0 path)
    float* Qw = (float*)d_ws;
    float* Kw = Qw + MC;
    float* Vw = Kw + MC;
    float* Ow = Vw + MC;
    dim3 ggrid(C / TM, M / TM);
    gemm_f32<1><<<ggrid, 256, 0, stream>>>(x, Wq, bq, Qw, M, C, C, T);
    gemm_f32<1><<<ggrid, 256, 0, stream>>>(x, Wk, bk, Kw, M, C, C, T);
    gemm_f32<1><<<ggrid, 256, 0, stream>>>(x, Wv, bv, Vw, M, C, C, T);
    dim3 fgrid(T / QT, B * H);
    flash_f32<<<fgrid, 256, 0, stream>>>(Qw, Kw, Vw, Ow, T);
    gemm_f32<0><<<ggrid, 256, 0, stream>>>(Ow, Wo, bo, out, M, C, C, T);
  }
}

// Round 17
// 274.689 us; speedup vs baseline: 1.0688x; 1.0104x over previous
//
#include <hip/hip_runtime.h>
#include <math.h>

// ============================================================================
// CausalAttention (B=2, T=2048, C=2048, H=16, D=128) with ALiBi.
// Round 31: refine the GEMM XCD swizzle from linear chunks to 2x4 RECTANGLE
// chunks. r30's linear chunk minimized A-footprint but gave each XCD ALL of
// B (QK: 2+16=18MB/XCD; FETCH went 74->93MB even as dur nudged down).
// Rectangle by in [(x>>2)*gh,+gh), bx in [(x&3)*gw,+gw) with gh=gy/2,
// gw=gx/4 (exact for grids (32,16),(32,8),(16,16)) balances footprint:
// QK 8+4=12MB/XCD, V^T 8MB. Bijective product decomposition, zero
// correctness risk. Everything else = r30 (277.6us best; attn 83.2 pair-ILP,
// QK 82.6 @ MfmaUtil 35%).
// ============================================================================

typedef unsigned short u16;
using bf16x8 = __attribute__((ext_vector_type(8))) short;
using f32x4  = __attribute__((ext_vector_type(4))) float;

__device__ __forceinline__ u16 f2bf(float f) {
  union { float f; unsigned u; } c; c.f = f;
  unsigned r = c.u + 0x7fffu + ((c.u >> 16) & 1u);   // RTN-even
  return (u16)(r >> 16);
}
__device__ __forceinline__ float bf2f(u16 b) {
  union { unsigned u; float f; } c; c.u = ((unsigned)b) << 16; return c.f;
}
__device__ __forceinline__ unsigned cvtpk(float a, float b) {
  unsigned r;
  asm("v_cvt_pk_bf16_f32 %0, %1, %2" : "=v"(r) : "v"(a), "v"(b));
  return r;
}
__device__ __forceinline__ void g2l16(const void* g, void* l) {
  __builtin_amdgcn_global_load_lds(
      (const __attribute__((address_space(1))) void*)g,
      (__attribute__((address_space(3))) void*)l, 16, 0, 0);
}

// band: drop tiles whose every column is > dist below the strip's first row
__device__ __forceinline__ int band_jmin(int s, float slope2) {
  const int idist = (int)(36.0f / slope2);
  const int cut = 64 * s - idist - 31;
  return (cut > 0) ? (cut >> 5) : 0;
}

// heaviest-first unit order: units sorted by serial tile count descending.
__device__ const unsigned char uord[48] = {
  15, 16, 32, 17, 33, 14, 18, 34, 19, 35,
  13, 20, 36, 21, 37, 12, 22, 38, 23, 39,
  11, 24, 40, 25, 41, 10, 26, 42, 27, 43,
   9, 28, 44, 29, 45,  8, 30, 46, 31, 47,
   7,  6,  5,  4,  3,  2,  1,  0};

// ---------------------------------------------------------------------------
// f32 -> bf16 cast, vectorized
// ---------------------------------------------------------------------------
__global__ __launch_bounds__(256) void split_f32(const float* __restrict__ in,
                                                 u16* __restrict__ hi, int n4) {
  for (int i = blockIdx.x * 256 + threadIdx.x; i < n4; i += gridDim.x * 256) {
    const float4 v = ((const float4*)in)[i];
    ushort4 h;
    h.x = f2bf(v.x); h.y = f2bf(v.y); h.z = f2bf(v.z); h.w = f2bf(v.w);
    ((ushort4*)hi)[i] = h;
  }
}

// ---------------------------------------------------------------------------
// Fused transpose + scale + cast for all 4 weights: z selects the matrix.
// ---------------------------------------------------------------------------
__global__ __launch_bounds__(256) void tsplit4_f32(
    const float* __restrict__ W0, const float* __restrict__ W1,
    const float* __restrict__ W2, const float* __restrict__ W3,
    u16* __restrict__ D0, u16* __restrict__ D1,
    u16* __restrict__ D2, u16* __restrict__ D3,
    int N, int K, float sc0) {
  __shared__ float tile[64][68];
  const int z = blockIdx.z;
  const float* W = (z == 0) ? W0 : (z == 1) ? W1 : (z == 2) ? W2 : W3;
  u16* Wth = (z == 0) ? D0 : (z == 1) ? D1 : (z == 2) ? D2 : D3;
  const float sc = (z == 0) ? sc0 : 1.f;
  const int tid = threadIdx.x;
  const int k0 = blockIdx.y * 64, n0 = blockIdx.x * 64;
  const int rr = tid >> 4, cc = (tid & 15) * 4;
#pragma unroll
  for (int u = 0; u < 4; ++u) {
    const float4 v = *(const float4*)&W[(size_t)(k0 + rr + 16 * u) * N + n0 + cc];
    tile[rr + 16 * u][cc + 0] = v.x;
    tile[rr + 16 * u][cc + 1] = v.y;
    tile[rr + 16 * u][cc + 2] = v.z;
    tile[rr + 16 * u][cc + 3] = v.w;
  }
  __syncthreads();
#pragma unroll
  for (int u = 0; u < 4; ++u) {
    const int nn = rr + 16 * u;
    ushort4 h;
    h.x = f2bf(tile[cc + 0][nn] * sc);
    h.y = f2bf(tile[cc + 1][nn] * sc);
    h.z = f2bf(tile[cc + 2][nn] * sc);
    h.w = f2bf(tile[cc + 3][nn] * sc);
    *(ushort4*)&Wth[(size_t)(n0 + nn) * K + k0 + cc] = h;
  }
}

// ---------------------------------------------------------------------------
// 256x128-tile bf16 GEMM, BK=32, ring-3 LDS, counted vmcnt (r18 proven).
// r31: 2x4 rectangle XCD chunking (bijective; needs gy%2==0, gx%4==0 —
// true for all three grids). Balances per-XCD A+B footprint.
// MODE 0: f32 out (+bias[col]*bsc); MODE 2: bf16 out (+bias[row]*bsc);
// MODE 3: merged QK scatter (+bias[col&2047]*bsc or bias2).
// ---------------------------------------------------------------------------
template <int MODE>
__global__ __launch_bounds__(512, 4) void gemm256x128(
    const u16* __restrict__ Ah, const u16* __restrict__ Bth,
    const float* __restrict__ bias, const float* __restrict__ bias2,
    float bsc, u16* __restrict__ outH, u16* __restrict__ outH2,
    float* __restrict__ outF, int MM, int NN, int KK) {
  __shared__ u16 LA[3][8192];   // ring: 256 rows x 32 (64B rows)
  __shared__ u16 LB[3][4096];   // ring: 128 rows x 32

  const int tid = threadIdx.x;
  const int wave = tid >> 6, lane = tid & 63;
  const int g = lane >> 4, q15 = lane & 15;
  const int wr = wave >> 1, wc = wave & 1;     // 4M x 2N
  // 2x4 rectangle XCD chunking: XCD x owns by in [(x>>2)*gh,+gh),
  // bx in [(x&3)*gw,+gw); w = lin>>3 walks the rectangle row-major.
  const int lin = blockIdx.y * gridDim.x + blockIdx.x;
  const int gh = gridDim.y >> 1;
  const int gw = gridDim.x >> 2;
  const int xcd = lin & 7;
  const int w = lin >> 3;
  const int by = (xcd >> 2) * gh + (w / gw);
  const int bx = (xcd & 3) * gw + (w % gw);
  const int m0 = by * 256, n0 = bx * 128;
  const int NT = KK >> 5;
  const int sxg = ((g ^ ((q15 >> 1) & 3)) << 4);

  f32x4 acc[4][4];
#pragma unroll
  for (int f = 0; f < 4; ++f)
#pragma unroll
    for (int j = 0; j < 4; ++j) acc[f][j] = (f32x4){0.f, 0.f, 0.f, 0.f};

  auto stageA = [&](int t, int rbuf) {
#pragma unroll
    for (int l = 0; l < 2; ++l) {
      const int ch = l * 512 + tid;
      const int row = ch >> 2, slot = ch & 3;
      const size_t ga = (size_t)(m0 + row) * KK + t * 32 +
                        ((slot ^ ((row >> 1) & 3)) * 8);
      g2l16(Ah + ga, (char*)(LA[rbuf]) + ch * 16);
    }
  };
  auto stageB = [&](int t, int rbuf) {
    const int ch = tid;
    const int row = ch >> 2, slot = ch & 3;
    const size_t gb = (size_t)(n0 + row) * KK + t * 32 +
                      ((slot ^ ((row >> 1) & 3)) * 8);
    g2l16(Bth + gb, (char*)(LB[rbuf]) + ch * 16);
  };

  // prologue: stage tiles 0,1 (6 ops/thread), drain tile 0 only
  stageA(0, 0); stageB(0, 0);
  __builtin_amdgcn_sched_barrier(0);
  if (NT > 1) { stageA(1, 1); stageB(1, 1); }
  __builtin_amdgcn_sched_barrier(0);
  if (NT > 1) { asm volatile("s_waitcnt vmcnt(3)" ::: "memory"); }
  else        { asm volatile("s_waitcnt vmcnt(0)" ::: "memory"); }
  __builtin_amdgcn_sched_barrier(0);
  __builtin_amdgcn_s_barrier();

  int rb = 0, rb2 = 2;
  for (int t = 0; t < NT; ++t) {
    const char* baseA = (const char*)(LA[rb]);
    const char* baseB = (const char*)(LB[rb]);

    bf16x8 af[4], bf[4];
#pragma unroll
    for (int f = 0; f < 4; ++f)
      af[f] = *(const bf16x8*)(baseA + (wr * 64 + f * 16 + q15) * 64 + sxg);
#pragma unroll
    for (int j = 0; j < 4; ++j)
      bf[j] = *(const bf16x8*)(baseB + (wc * 64 + j * 16 + q15) * 64 + sxg);
    if (t + 2 < NT) { stageA(t + 2, rb2); stageB(t + 2, rb2); }
    __builtin_amdgcn_sched_barrier(0);
    __builtin_amdgcn_s_barrier();
    asm volatile("s_waitcnt lgkmcnt(0)" ::: "memory");
    __builtin_amdgcn_sched_barrier(0);
    __builtin_amdgcn_s_setprio(1);
#pragma unroll
    for (int f = 0; f < 4; ++f)
#pragma unroll
      for (int j = 0; j < 4; ++j)
        acc[f][j] = __builtin_amdgcn_mfma_f32_16x16x32_bf16(
            af[f], bf[j], acc[f][j], 0, 0, 0);
    __builtin_amdgcn_s_setprio(0);
    if (t + 1 < NT) {
      if (t + 2 < NT) { asm volatile("s_waitcnt vmcnt(3)" ::: "memory"); }
      else            { asm volatile("s_waitcnt vmcnt(0)" ::: "memory"); }
    }
    __builtin_amdgcn_sched_barrier(0);
    __builtin_amdgcn_s_barrier();
    rb  = (rb  == 2) ? 0 : rb  + 1;
    rb2 = (rb2 == 2) ? 0 : rb2 + 1;
  }

#pragma unroll
  for (int f = 0; f < 4; ++f)
#pragma unroll
    for (int j = 0; j < 4; ++j)
#pragma unroll
      for (int r = 0; r < 4; ++r) {
        const int row = m0 + wr * 64 + f * 16 + g * 4 + r;
        const int col = n0 + wc * 64 + j * 16 + q15;
        const float v = acc[f][j][r];
        if (MODE == 0) {
          outF[(size_t)row * NN + col] = v + bias[col] * bsc;
        } else if (MODE == 2) {
          outH[(size_t)row * NN + col] = f2bf(v + bias[row] * bsc);
        } else {  // MODE 3: merged QK scatter
          const int sel = col >> 11;
          const int c2 = col & 2047;
          const float vv = v + (sel ? bias2[c2] : bias[c2] * bsc);
          const int bb = row >> 11, tt = row & 2047;
          const int hh = c2 >> 7, dd = c2 & 127;
          (sel ? outH2 : outH)[(((size_t)bb * 16 + hh) * 2048 + tt) * 128 + dd] =
              f2bf(vv);
        }
      }
}

// ---------------------------------------------------------------------------
// Banded split-K flash attention with ALiBi. r27: tile-pair ILP on top of
// the r24/r26 structure (1-wave blocks, XCD-pair decode, uord, setprio,
// K LDS ring-3, V reg-dbuf, counted vmcnt).
// ---------------------------------------------------------------------------
__global__ __launch_bounds__(64) void attn_splitk(
    const u16* __restrict__ Qh, const u16* __restrict__ Kh,
    const u16* __restrict__ Vth, u16* __restrict__ Oh,
    float* __restrict__ Obuf, float* __restrict__ mArr,
    float* __restrict__ lArr, int T, int NB, int BH) {
  __shared__ u16 KS[3][4096];   // 32 x 128, 256B rows, XOR ((row&7)<<4)

  const int tid = threadIdx.x;
  const int lane = tid & 63;
  const int g = lane >> 4, q15 = lane & 15;
  const int L = blockIdx.x;
  // XCD-co-located pair decode: halves are (L, L+8) -> same XCD (mod 8)
  const int LL = (L & 7) | ((L >> 4) << 3);
  const int wid = (L >> 3) & 1;

  int bh, u;
  if (BH == 32) {
    const int k = LL >> 8;       // round 0..5
    const int c = LL & 255;      // CU-slot within round
    bh = (c + 5 * k) & 31;
    u = uord[k * 8 + (c >> 5)];
  } else {
    bh = LL / 48;
    u = uord[LL % 48];
  }
  int s, half;
  if (u < 16)      { s = u;      half = 2; }   // full strip
  else if (u < 32) { s = 47 - u; half = 0; }   // low half (no diagonal)
  else             { s = 63 - u; half = 1; }   // high half (diagonal)

  const int b = bh >> 4, h = bh & 15;
  const float slope2 = exp2f(-0.5f * (float)(h + 1)) * 1.44269504f;
  const int jmin = band_jmin(s, slope2);
  const bool loEmpty = (jmin >= s + 1);

  if (half == 0 && loEmpty) return;            // nothing to do

  int lo, hi;
  if (half == 2)      { lo = jmin;                hi = 2 * s + 2; }
  else if (half == 0) { lo = jmin;                hi = s + 1; }
  else                { lo = loEmpty ? jmin : (s + 1); hi = 2 * s + 2; }
  const int ns = hi - lo;                      // >= 1
  const bool maskable = (half != 0);
  const bool normStore = (half == 2) || (half == 1 && loEmpty);

  const int qw0 = s * 64 + wid * 32;
  const size_t vrow0 = (size_t)h * 128;
  const size_t vcol0 = (size_t)b * T;
  const size_t kbase = (size_t)bh * T;

  // ---- Q loads (8 globals, issued first / oldest in vmcnt order) ----
  bf16x8 qfr[2][4];
#pragma unroll
  for (int qf2 = 0; qf2 < 2; ++qf2) {
    const size_t rb = ((size_t)bh * T + qw0 + qf2 * 16 + q15) * 128;
#pragma unroll
    for (int ks = 0; ks < 4; ++ks)
      qfr[qf2][ks] = *(const bf16x8*)&Qh[rb + ks * 32 + g * 8];
  }

  f32x4 oacc[2][8];
#pragma unroll
  for (int a = 0; a < 2; ++a)
#pragma unroll
    for (int n = 0; n < 8; ++n) oacc[a][n] = (f32x4){0.f, 0.f, 0.f, 0.f};
  float m_st[2] = {-1e5f, -1e5f};
  float l_part[2] = {0.f, 0.f};

  // stage one 32x128 K tile (8KB = 8 chunks of 1KB), all by this wave
  auto stageK = [&](int jt, int bf) {
    const int j0 = jt * 32;
#pragma unroll
    for (int c = 0; c < 8; ++c) {
      const int row = c * 4 + g;
      const int off = (q15 * 16) ^ ((row & 7) << 4);
      const size_t gb = (kbase + j0 + row) * 128;
      g2l16((const char*)(Kh + gb) + off, (char*)(KS[bf]) + c * 1024);
    }
  };
  auto loadV = [&](int jt, bf16x8 (&vf)[8]) {
    const int j0 = jt * 32;
#pragma unroll
    for (int nf = 0; nf < 8; ++nf)
      vf[nf] = *(const bf16x8*)
          &Vth[(vrow0 + nf * 16 + q15) * (size_t)NB + vcol0 + j0 + g * 8];
  };
  // QK^T for one tile from KS[slot] into sacc
  auto QKT = [&](int slot, f32x4 (&sacc)[2][2]) {
#pragma unroll
    for (int jf = 0; jf < 2; ++jf)
#pragma unroll
      for (int qf2 = 0; qf2 < 2; ++qf2) sacc[jf][qf2] = (f32x4){0.f, 0.f, 0.f, 0.f};
#pragma unroll
    for (int ks = 0; ks < 4; ++ks) {
      bf16x8 ka[2];
#pragma unroll
      for (int jf = 0; jf < 2; ++jf) {
        const int row = jf * 16 + q15;
        const int off = (row * 256 + ks * 64 + g * 16) ^ ((row & 7) << 4);
        ka[jf] = *(const bf16x8*)((const char*)(KS[slot]) + off);
      }
#pragma unroll
      for (int jf = 0; jf < 2; ++jf)
#pragma unroll
        for (int qf2 = 0; qf2 < 2; ++qf2)
          sacc[jf][qf2] = __builtin_amdgcn_mfma_f32_16x16x32_bf16(
              ka[jf], qfr[qf2][ks], sacc[jf][qf2], 0, 0, 0);
    }
  };
  // softmax + PV for one tile (no internal waits; V must be drained)
  auto SOFTPV = [&](int it, int j0, f32x4 (&sacc)[2][2], bf16x8 (&vc)[8]) {
    const float jb2 = (float)(j0 + 4 * g - (T - 1));
    unsigned Fw[2][4];
#pragma unroll
    for (int qf2 = 0; qf2 < 2; ++qf2) {
      const int qg = qw0 + qf2 * 16 + q15;
      float sv[2][4];
      float mt = -1e30f;
#pragma unroll
      for (int jf = 0; jf < 2; ++jf)
#pragma unroll
        for (int r = 0; r < 4; ++r) {
          float x = fmaf(slope2, jb2 + (float)(jf * 16 + r), sacc[jf][qf2][r]);
          if (maskable && it < 2) {
            const int jg = j0 + jf * 16 + 4 * g + r;
            x = (jg > qg) ? -1e30f : x;
          }
          sv[jf][r] = x;
          mt = fmaxf(mt, x);
        }
      if (!__all(mt <= m_st[qf2] + 11.0f)) {
        mt = fmaxf(mt, __shfl_xor(mt, 16));
        mt = fmaxf(mt, __shfl_xor(mt, 32));
        const float mnew = fmaxf(m_st[qf2], mt);
        const float scl = exp2f(m_st[qf2] - mnew);
        l_part[qf2] *= scl;
        m_st[qf2] = mnew;
#pragma unroll
        for (int r = 0; r < 4; ++r) {
          const float sc = __shfl(scl, g * 4 + r);
#pragma unroll
          for (int nf = 0; nf < 8; ++nf) oacc[qf2][nf][r] *= sc;
        }
      }
      float rs = 0.f;
      float p[2][4];
#pragma unroll
      for (int jf = 0; jf < 2; ++jf)
#pragma unroll
        for (int r = 0; r < 4; ++r) {
          p[jf][r] = exp2f(sv[jf][r] - m_st[qf2]);
          rs += p[jf][r];
        }
      l_part[qf2] += rs;
      const unsigned W00 = cvtpk(p[0][0], p[0][1]), W01 = cvtpk(p[0][2], p[0][3]);
      const unsigned W10 = cvtpk(p[1][0], p[1][1]), W11 = cvtpk(p[1][2], p[1][3]);
      const int srcA = q15 + ((g & 1) << 5);
      const int srcB = srcA + 16;
      const unsigned A0 = (unsigned)__shfl((int)W00, srcA);
      const unsigned A1 = (unsigned)__shfl((int)W01, srcA);
      const unsigned B0 = (unsigned)__shfl((int)W00, srcB);
      const unsigned B1 = (unsigned)__shfl((int)W01, srcB);
      const unsigned C0 = (unsigned)__shfl((int)W10, srcA);
      const unsigned C1 = (unsigned)__shfl((int)W11, srcA);
      const unsigned D0 = (unsigned)__shfl((int)W10, srcB);
      const unsigned D1 = (unsigned)__shfl((int)W11, srcB);
      const bool hi2 = g >= 2;
      Fw[qf2][0] = hi2 ? C0 : A0;
      Fw[qf2][1] = hi2 ? C1 : A1;
      Fw[qf2][2] = hi2 ? D0 : B0;
      Fw[qf2][3] = hi2 ? D1 : B1;
    }
    union { unsigned uu[4]; bf16x8 v; } pa0, pa1;
#pragma unroll
    for (int w = 0; w < 4; ++w) { pa0.uu[w] = Fw[0][w]; pa1.uu[w] = Fw[1][w]; }
    __builtin_amdgcn_s_setprio(1);
#pragma unroll
    for (int nf = 0; nf < 8; ++nf) {
      oacc[0][nf] = __builtin_amdgcn_mfma_f32_16x16x32_bf16(pa0.v, vc[nf], oacc[0][nf], 0, 0, 0);
      oacc[1][nf] = __builtin_amdgcn_mfma_f32_16x16x32_bf16(pa1.v, vc[nf], oacc[1][nf], 0, 0, 0);
    }
    __builtin_amdgcn_s_setprio(0);
  };

  // ---- prologue: pinned issue order [Q][K0,K1][V0] ----
  bf16x8 vfA[8], vfB[8];
  __builtin_amdgcn_sched_barrier(0);
  stageK(hi - 1, 0);
  if (ns > 1) stageK(hi - 2, 1);
  __builtin_amdgcn_sched_barrier(0);
  loadV(hi - 1, vfA);
  // outstanding: ns>1: Q(8)+K0(8)+K1(8)+V0(8)=32 -> vmcnt(16) drains Q,K0
  //              ns==1: Q(8)+K0(8)+V0(8)=24      -> vmcnt(8)  drains Q,K0
  if (ns > 1) { asm volatile("s_waitcnt vmcnt(16)" ::: "memory"); }
  else        { asm volatile("s_waitcnt vmcnt(8)"  ::: "memory"); }
  __builtin_amdgcn_sched_barrier(0);

  int cur = 0;   // slot of tile it: it % 3

  int it = 0;
  while (it + 2 <= ns) {
    // ---- pair (t0=it, t1=it+1); entry: vfA=V(t0); outstanding {V(t0),K(t0+1)}
    const int jt0 = hi - 1 - it, jt1 = jt0 - 1;
    const int j0a = jt0 * 32, j0b = jt1 * 32;
    const int cur1 = (cur == 2) ? 0 : cur + 1;
    const int cur2 = (cur1 == 2) ? 0 : cur1 + 1;
    const bool e2 = (it + 2 < ns);
    const bool e3 = (it + 3 < ns);

    // sub0 issues: V(t1)->vfB [8], K(t0+2)->cur2 [8 if e2]
    loadV(jt1, vfB);
    if (e2) stageK(jt0 - 2, cur2);
    __builtin_amdgcn_sched_barrier(0);
    if (e2) { asm volatile("s_waitcnt vmcnt(16)" ::: "memory"); }
    else    { asm volatile("s_waitcnt vmcnt(8)"  ::: "memory"); }
    __builtin_amdgcn_sched_barrier(0);

    // QK for BOTH tiles: QK(t1) MFMAs drain under SM(t0)'s VALU below.
    f32x4 sacc0[2][2], sacc1[2][2];
    __builtin_amdgcn_s_setprio(1);
    QKT(cur, sacc0);
    QKT(cur1, sacc1);
    __builtin_amdgcn_s_setprio(0);

    SOFTPV(it, j0a, sacc0, vfA);       // uses V(t0) (drained)

    // sub1 issues (after PV(t0) consumed vfA): V(t0+2)->vfA, K(t0+3)->cur
    if (e2) loadV(jt0 - 2, vfA);
    if (e3) stageK(jt0 - 3, cur);
    __builtin_amdgcn_sched_barrier(0);
    if (e2 && e3)      { asm volatile("s_waitcnt vmcnt(16)" ::: "memory"); }
    else if (e2)       { asm volatile("s_waitcnt vmcnt(8)"  ::: "memory"); }
    else               { asm volatile("s_waitcnt vmcnt(0)"  ::: "memory"); }
    __builtin_amdgcn_sched_barrier(0);

    SOFTPV(it + 1, j0b, sacc1, vfB);   // uses V(t1) (drained)

    cur = cur2;  // cur advanced by 2 (mod 3)
    it += 2;
  }
  if (it < ns) {
    // singleton tail: outstanding {V(it)} (or V0 for ns==1); no prefetch
    const int jt = hi - 1 - it;
    asm volatile("s_waitcnt vmcnt(0)" ::: "memory");
    __builtin_amdgcn_sched_barrier(0);
    f32x4 sacc0[2][2];
    __builtin_amdgcn_s_setprio(1);
    QKT(cur, sacc0);
    __builtin_amdgcn_s_setprio(0);
    SOFTPV(it, jt * 32, sacc0, vfA);
  }

  // ---- epilogue ----
  float lrow[2];
#pragma unroll
  for (int qf2 = 0; qf2 < 2; ++qf2) {
    float lr = l_part[qf2];
    lr += __shfl_xor(lr, 16);
    lr += __shfl_xor(lr, 32);
    lrow[qf2] = lr;
  }

  if (normStore) {
#pragma unroll
    for (int qf2 = 0; qf2 < 2; ++qf2) {
      const float inv = 1.0f / lrow[qf2];
#pragma unroll
      for (int r = 0; r < 4; ++r) {
        const float iv = __shfl(inv, g * 4 + r);
        const int qrow = qw0 + qf2 * 16 + g * 4 + r;
        const size_t ob = ((size_t)b * T + qrow) * 2048 + h * 128;
#pragma unroll
        for (int nf = 0; nf < 8; ++nf)
          Oh[ob + nf * 16 + q15] = f2bf(oacc[qf2][nf][r] * iv);
      }
    }
  } else {
    const int sp = s - 16;
    const size_t sbase = ((size_t)(bh * 16 + sp) * 2 + half) * 64;
    if (g == 0) {
#pragma unroll
      for (int qf2 = 0; qf2 < 2; ++qf2) {
        mArr[sbase + wid * 32 + qf2 * 16 + q15] = m_st[qf2];
        lArr[sbase + wid * 32 + qf2 * 16 + q15] = lrow[qf2];
      }
    }
    const size_t obase = sbase * 128;
#pragma unroll
    for (int qf2 = 0; qf2 < 2; ++qf2)
#pragma unroll
      for (int r = 0; r < 4; ++r) {
        const int row = wid * 32 + qf2 * 16 + g * 4 + r;
#pragma unroll
        for (int nf = 0; nf < 8; ++nf)
          Obuf[obase + (size_t)row * 128 + nf * 16 + q15] = oacc[qf2][nf][r];
      }
  }
}

// ---------------------------------------------------------------------------
// Combine split-K halves; skips strips whose low half was band-empty.
// ---------------------------------------------------------------------------
__global__ __launch_bounds__(128) void combine_halves(
    const float* __restrict__ Obuf, const float* __restrict__ mArr,
    const float* __restrict__ lArr, u16* __restrict__ Oh, int T) {
  const int idx = blockIdx.x;
  const int row = idx & 63;
  const int sp = (idx >> 6) & 15;
  const int bh = idx >> 10;
  const int d = threadIdx.x;
  const int s = sp + 16;
  const int b = bh >> 4, h = bh & 15;
  const float slope2 = exp2f(-0.5f * (float)(h + 1)) * 1.44269504f;
  if (band_jmin(s, slope2) >= s + 1) return;   // high half stored directly
  const size_t sbase = ((size_t)(bh * 16 + sp) * 2) * 64;
  const float m1 = mArr[sbase + row],      l1 = lArr[sbase + row];
  const float m2 = mArr[sbase + 64 + row], l2 = lArr[sbase + 64 + row];
  const float M = fmaxf(m1, m2);
  const float w1 = exp2f(m1 - M), w2 = exp2f(m2 - M);
  const float inv = 1.0f / (l1 * w1 + l2 * w2);
  const size_t ob = sbase * 128;
  const float o1 = Obuf[ob + (size_t)row * 128 + d];
  const float o2 = Obuf[ob + 8192 + (size_t)row * 128 + d];
  const float v = (o1 * w1 + o2 * w2) * inv;
  const int qrow = s * 64 + row;
  Oh[((size_t)b * T + qrow) * 2048 + h * 128 + d] = f2bf(v);
}

// ============================================================================
// Fallback f32 path (round-0, proven): used only if ws_size is insufficient.
// ============================================================================
#define TM 128
#define BKG 8

template <int QKV>
__global__ __launch_bounds__(256) void gemm_f32(
    const float* __restrict__ A, const float* __restrict__ W,
    const float* __restrict__ bias, float* __restrict__ out,
    int M, int N, int K, int T) {
  __shared__ float As[BKG][TM];
  __shared__ float Bs[BKG][TM];
  const int tid = threadIdx.x;
  const int tx = tid & 15, ty = tid >> 4;
  const int m0 = blockIdx.y * TM, n0 = blockIdx.x * TM;
  float acc[8][8];
#pragma unroll
  for (int i = 0; i < 8; ++i)
#pragma unroll
    for (int j = 0; j < 8; ++j) acc[i][j] = 0.f;
  const int arow = tid >> 1, acol = (tid & 1) * 4;
  const int brow = tid >> 5, bcol = (tid & 31) * 4;
  for (int k0 = 0; k0 < K; k0 += BKG) {
    const float4 av = *(const float4*)&A[(size_t)(m0 + arow) * K + k0 + acol];
    const float4 bv = *(const float4*)&W[(size_t)(k0 + brow) * N + n0 + bcol];
    __syncthreads();
    As[acol + 0][arow] = av.x; As[acol + 1][arow] = av.y;
    As[acol + 2][arow] = av.z; As[acol + 3][arow] = av.w;
    *(float4*)&Bs[brow][bcol] = bv;
    __syncthreads();
#pragma unroll
    for (int kk = 0; kk < BKG; ++kk) {
      const float4 a0 = *(const float4*)&As[kk][ty * 4];
      const float4 a1 = *(const float4*)&As[kk][64 + ty * 4];
      const float4 b0 = *(const float4*)&Bs[kk][tx * 4];
      const float4 b1 = *(const float4*)&Bs[kk][64 + tx * 4];
      const float af[8] = {a0.x, a0.y, a0.z, a0.w, a1.x, a1.y, a1.z, a1.w};
      const float bf[8] = {b0.x, b0.y, b0.z, b0.w, b1.x, b1.y, b1.z, b1.w};
#pragma unroll
      for (int i = 0; i < 8; ++i)
#pragma unroll
        for (int j = 0; j < 8; ++j) acc[i][j] += af[i] * bf[j];
    }
  }
#pragma unroll
  for (int a = 0; a < 2; ++a)
#pragma unroll
    for (int i = 0; i < 4; ++i) {
      const int row = m0 + a * 64 + ty * 4 + i;
      const int bb = row / T, t = row % T;
#pragma unroll
      for (int bj = 0; bj < 2; ++bj) {
        const int col = n0 + bj * 64 + tx * 4;
        float4 r;
        r.x = acc[a * 4 + i][bj * 4 + 0] + bias[col + 0];
        r.y = acc[a * 4 + i][bj * 4 + 1] + bias[col + 1];
        r.z = acc[a * 4 + i][bj * 4 + 2] + bias[col + 2];
        r.w = acc[a * 4 + i][bj * 4 + 3] + bias[col + 3];
        if (QKV) {
          const int hh = col >> 7, dd = col & 127;
          *(float4*)&out[(((size_t)bb * 16 + hh) * T + t) * 128 + dd] = r;
        } else {
          *(float4*)&out[(size_t)row * N + col] = r;
        }
      }
    }
}

#define QT 32
#define KT 32
#define DP 132

__global__ __launch_bounds__(256) void flash_f32(
    const float* __restrict__ Q, const float* __restrict__ K,
    const float* __restrict__ V, float* __restrict__ O, int T) {
  __shared__ float Qs[QT][DP];
  __shared__ float Ks[KT][DP];
  __shared__ float Vs[KT][DP];
  __shared__ float Ps[QT][KT + 1];
  const int tid = threadIdx.x;
  const int jh = tid & 15, ih = tid >> 4;
  const int bh = blockIdx.y;
  const int h = bh & 15;
  const int q0 = blockIdx.x * QT;
  const float slope = exp2f(-0.5f * (float)(h + 1));
  const float rsD = 0.08838834764831845f;
  {
    const float* Qg = Q + ((size_t)bh * T + q0) * 128;
    const int r = tid >> 3, p = tid & 7;
#pragma unroll
    for (int u = 0; u < 4; ++u)
      *(float4*)&Qs[r][(p + 8 * u) * 4] = *(const float4*)&Qg[r * 128 + (p + 8 * u) * 4];
  }
  float m_st[2] = {-1e30f, -1e30f};
  float l_st[2] = {0.f, 0.f};
  float accv[2][8] = {};
  const int ktiles = blockIdx.x + 1;
  for (int kt = 0; kt < ktiles; ++kt) {
    const int j0 = kt * KT;
    const float* Kg = K + ((size_t)bh * T + j0) * 128;
    const float* Vg = V + ((size_t)bh * T + j0) * 128;
    __syncthreads();
    {
      const int r = tid >> 3, p = tid & 7;
#pragma unroll
      for (int u = 0; u < 4; ++u) {
        *(float4*)&Ks[r][(p + 8 * u) * 4] = *(const float4*)&Kg[r * 128 + (p + 8 * u) * 4];
        *(float4*)&Vs[r][(p + 8 * u) * 4] = *(const float4*)&Vg[r * 128 + (p + 8 * u) * 4];
      }
    }
    __syncthreads();
    float s00 = 0.f, s01 = 0.f, s10 = 0.f, s11 = 0.f;
#pragma unroll 8
    for (int d4 = 0; d4 < 32; ++d4) {
      const float4 qa = *(const float4*)&Qs[2 * ih + 0][4 * d4];
      const float4 qb = *(const float4*)&Qs[2 * ih + 1][4 * d4];
      const float4 ka = *(const float4*)&Ks[2 * jh + 0][4 * d4];
      const float4 kb = *(const float4*)&Ks[2 * jh + 1][4 * d4];
      s00 += qa.x * ka.x + qa.y * ka.y + qa.z * ka.z + qa.w * ka.w;
      s01 += qa.x * kb.x + qa.y * kb.y + qa.z * kb.z + qa.w * kb.w;
      s10 += qb.x * ka.x + qb.y * ka.y + qb.z * ka.z + qb.w * ka.w;
      s11 += qb.x * kb.x + qb.y * kb.y + qb.z * kb.z + qb.w * kb.w;
    }
    float sc[2][2] = {{s00, s01}, {s10, s11}};
    float mt[2];
#pragma unroll
    for (int r = 0; r < 2; ++r) {
      const int qg = q0 + 2 * ih + r;
#pragma unroll
      for (int c = 0; c < 2; ++c) {
        const int jg = j0 + 2 * jh + c;
        const float svv = sc[r][c] * rsD + slope * (float)(jg - (T - 1));
        sc[r][c] = (jg > qg) ? -1e30f : svv;
      }
      mt[r] = fmaxf(sc[r][0], sc[r][1]);
    }
#pragma unroll
    for (int m = 1; m < 16; m <<= 1) {
      mt[0] = fmaxf(mt[0], __shfl_xor(mt[0], m));
      mt[1] = fmaxf(mt[1], __shfl_xor(mt[1], m));
    }
#pragma unroll
    for (int r = 0; r < 2; ++r) {
      const float mnew = fmaxf(m_st[r], mt[r]);
      const float scl = (m_st[r] > -1e29f) ? expf(m_st[r] - mnew) : 0.f;
      const float p0 = expf(sc[r][0] - mnew);
      const float p1 = expf(sc[r][1] - mnew);
      float rs = p0 + p1;
#pragma unroll
      for (int m = 1; m < 16; m <<= 1) rs += __shfl_xor(rs, m);
      l_st[r] = l_st[r] * scl + rs;
      m_st[r] = mnew;
#pragma unroll
      for (int d = 0; d < 8; ++d) accv[r][d] *= scl;
      Ps[2 * ih + r][2 * jh + 0] = p0;
      Ps[2 * ih + r][2 * jh + 1] = p1;
    }
    __syncthreads();
#pragma unroll 4
    for (int j = 0; j < KT; ++j) {
      const float p0 = Ps[2 * ih + 0][j];
      const float p1 = Ps[2 * ih + 1][j];
      const float4 v0 = *(const float4*)&Vs[j][8 * jh];
      const float4 v1 = *(const float4*)&Vs[j][8 * jh + 4];
      accv[0][0] += p0 * v0.x; accv[0][1] += p0 * v0.y;
      accv[0][2] += p0 * v0.z; accv[0][3] += p0 * v0.w;
      accv[0][4] += p0 * v1.x; accv[0][5] += p0 * v1.y;
      accv[0][6] += p0 * v1.z; accv[0][7] += p0 * v1.w;
      accv[1][0] += p1 * v0.x; accv[1][1] += p1 * v0.y;
      accv[1][2] += p1 * v0.z; accv[1][3] += p1 * v0.w;
      accv[1][4] += p1 * v1.x; accv[1][5] += p1 * v1.y;
      accv[1][6] += p1 * v1.z; accv[1][7] += p1 * v1.w;
    }
  }
  const int b = bh >> 4;
#pragma unroll
  for (int r = 0; r < 2; ++r) {
    const int qg = q0 + 2 * ih + r;
    const float inv = 1.0f / l_st[r];
    float4 o0, o1;
    o0.x = accv[r][0] * inv; o0.y = accv[r][1] * inv;
    o0.z = accv[r][2] * inv; o0.w = accv[r][3] * inv;
    o1.x = accv[r][4] * inv; o1.y = accv[r][5] * inv;
    o1.z = accv[r][6] * inv; o1.w = accv[r][7] * inv;
    float* dst = O + ((size_t)b * T + qg) * 2048 + h * 128 + 8 * jh;
    *(float4*)&dst[0] = o0;
    *(float4*)&dst[4] = o1;
  }
}

// ============================================================================
extern "C" void kernel_launch(void* const* d_in, const int* in_sizes, int n_in,
                              void* d_out, int out_size, void* d_ws,
                              size_t ws_size, hipStream_t stream) {
  const float* x  = (const float*)d_in[0];
  const float* Wq = (const float*)d_in[1];
  const float* bq = (const float*)d_in[2];
  const float* Wk = (const float*)d_in[3];
  const float* bk = (const float*)d_in[4];
  const float* Wv = (const float*)d_in[5];
  const float* bv = (const float*)d_in[6];
  const float* Wo = (const float*)d_in[7];
  const float* bo = (const float*)d_in[8];
  float* out = (float*)d_out;

  const int C = 2048, T = 2048, H = 16;
  const int M = in_sizes[0] / C;  // B*T
  const int B = M / T;
  const int BH = B * H;
  const size_t MC = (size_t)M * C, CC = (size_t)C * C;
  const size_t splitO = (size_t)BH * 16 * 2 * 8192;        // f32 elems
  const size_t splitML = (size_t)BH * 16 * 2 * 64;         // f32 elems
  const size_t need = (5 * MC + 4 * CC) * sizeof(u16) +
                      (splitO + 2 * splitML) * sizeof(float);

  // rsD * log2(e): puts QK^T logits in exp2 domain
  const float QSC = 0.08838834764831845f * 1.44269504088896f;

  if (ws_size >= need && (M % 256) == 0) {
    u16* p = (u16*)d_ws;
    u16* xh   = p; p += MC;
    u16* wqth = p; p += CC;   // wqth/wkth contiguous -> merged QK GEMM
    u16* wkth = p; p += CC;
    u16* wvth = p; p += CC;
    u16* woth = p; p += CC;
    u16* qh   = p; p += MC;
    u16* kh   = p; p += MC;
    u16* vth  = p; p += MC;
    u16* oh   = p; p += MC;
    float* Obuf = (float*)p;
    float* mArr = Obuf + splitO;
    float* lArr = mArr + splitML;

    split_f32<<<1024, 256, 0, stream>>>(x, xh, (int)(MC / 4));
    dim3 tg(C / 64, C / 64, 4);
    tsplit4_f32<<<tg, 256, 0, stream>>>(Wq, Wk, Wv, Wo, wqth, wkth, wvth,
                                        woth, C, C, QSC);

    // merged Q+K projection: [M x 4096] = xh @ [wqth|wkth]^T
    // 256x128 tiles -> (32,16) = 512 blocks -> 2 blocks/CU, rect-swizzled
    dim3 gqk(2 * C / 128, M / 256);
    gemm256x128<3><<<gqk, 512, 0, stream>>>(xh, wqth, bq, bk, QSC, qh, kh,
                                            nullptr, M, 2 * C, C);
    // V^T = Wv^T @ x^T : out [C][M] (+bv by row) — (32,8) = 256 blocks
    dim3 gv(M / 128, C / 256);
    gemm256x128<2><<<gv, 512, 0, stream>>>(wvth, xh, bv, nullptr, 1.f, vth,
                                           nullptr, nullptr, C, M, C);

    attn_splitk<<<96 * BH, 64, 0, stream>>>(qh, kh, vth, oh, Obuf, mArr,
                                            lArr, T, M, BH);
    combine_halves<<<BH * 16 * 64, 128, 0, stream>>>(Obuf, mArr, lArr, oh, T);

    // final o @ Wo — (16,16) = 256 blocks
    dim3 gq(C / 128, M / 256);
    gemm256x128<0><<<gq, 512, 0, stream>>>(oh, woth, bo, nullptr, 1.f,
                                           nullptr, nullptr, out, M, C, C);
  } else {
    // f32 fallback (round-0 path)
    float* Qw = (float*)d_ws;
    float* Kw = Qw + MC;
    float* Vw = Kw + MC;
    float* Ow = Vw + MC;
    dim3 ggrid(C / TM, M / TM);
    gemm_f32<1><<<ggrid, 256, 0, stream>>>(x, Wq, bq, Qw, M, C, C, T);
    gemm_f32<1><<<ggrid, 256, 0, stream>>>(x, Wk, bk, Kw, M, C, C, T);
    gemm_f32<1><<<ggrid, 256, 0, stream>>>(x, Wv, bv, Vw, M, C, C, T);
    dim3 fgrid(T / QT, B * H);
    flash_f32<<<fgrid, 256, 0, stream>>>(Qw, Kw, Vw, Ow, T);
    gemm_f32<0><<<ggrid, 256, 0, stream>>>(Ow, Wo, bo, out, M, C, C, T);
  }
}

// Round 18
// 274.252 us; speedup vs baseline: 1.0705x; 1.0016x over previous
//
#include <hip/hip_runtime.h>
#include <math.h>

// ============================================================================
// CausalAttention (B=2, T=2048, C=2048, H=16, D=128) with ALiBi.
// Round 32: fuse split_f32 (1024 blk) + tsplit4_f32 (4096 blk) into one
// 5120-block dispatch (role = blockIdx%5: 4 tsplit-subblocks + 1 split per
// group of 5). Both memory-bound + data-independent -> one launch boundary
// removed, grid tails co-scheduled. Bodies unchanged (pure re-indexing).
// Everything else = r31 (274.7us best: QK FETCH 93->49MB via 2x4 rectangle
// XCD chunking; attn 83.2 pair-ILP; QK 83 @ MfmaUtil 34%).
// ============================================================================

typedef unsigned short u16;
using bf16x8 = __attribute__((ext_vector_type(8))) short;
using f32x4  = __attribute__((ext_vector_type(4))) float;

__device__ __forceinline__ u16 f2bf(float f) {
  union { float f; unsigned u; } c; c.f = f;
  unsigned r = c.u + 0x7fffu + ((c.u >> 16) & 1u);   // RTN-even
  return (u16)(r >> 16);
}
__device__ __forceinline__ float bf2f(u16 b) {
  union { unsigned u; float f; } c; c.u = ((unsigned)b) << 16; return c.f;
}
__device__ __forceinline__ unsigned cvtpk(float a, float b) {
  unsigned r;
  asm("v_cvt_pk_bf16_f32 %0, %1, %2" : "=v"(r) : "v"(a), "v"(b));
  return r;
}
__device__ __forceinline__ void g2l16(const void* g, void* l) {
  __builtin_amdgcn_global_load_lds(
      (const __attribute__((address_space(1))) void*)g,
      (__attribute__((address_space(3))) void*)l, 16, 0, 0);
}

// band: drop tiles whose every column is > dist below the strip's first row
__device__ __forceinline__ int band_jmin(int s, float slope2) {
  const int idist = (int)(36.0f / slope2);
  const int cut = 64 * s - idist - 31;
  return (cut > 0) ? (cut >> 5) : 0;
}

// heaviest-first unit order: units sorted by serial tile count descending.
__device__ const unsigned char uord[48] = {
  15, 16, 32, 17, 33, 14, 18, 34, 19, 35,
  13, 20, 36, 21, 37, 12, 22, 38, 23, 39,
  11, 24, 40, 25, 41, 10, 26, 42, 27, 43,
   9, 28, 44, 29, 45,  8, 30, 46, 31, 47,
   7,  6,  5,  4,  3,  2,  1,  0};

// ---------------------------------------------------------------------------
// Fused preprocessing: role blockIdx%5==4 -> f32->bf16 cast of x (1024
// virtual blocks, grid-stride); else -> transpose+scale+cast of one weight
// 64x64 tile (4096 virtual blocks: id = grp*4+rem, z = id>>10).
// ---------------------------------------------------------------------------
__global__ __launch_bounds__(256) void prep_all(
    const float* __restrict__ in, u16* __restrict__ hi, int n4,
    const float* __restrict__ W0, const float* __restrict__ W1,
    const float* __restrict__ W2, const float* __restrict__ W3,
    u16* __restrict__ D0, u16* __restrict__ D1,
    u16* __restrict__ D2, u16* __restrict__ D3,
    int N, int K, float sc0) {
  __shared__ float tile[64][68];
  const int grp = blockIdx.x / 5, rem = blockIdx.x % 5;
  const int tid = threadIdx.x;

  if (rem == 4) {
    // ---- split_f32 role (virtual grid 1024) ----
    for (int i = grp * 256 + tid; i < n4; i += 1024 * 256) {
      const float4 v = ((const float4*)in)[i];
      ushort4 h;
      h.x = f2bf(v.x); h.y = f2bf(v.y); h.z = f2bf(v.z); h.w = f2bf(v.w);
      ((ushort4*)hi)[i] = h;
    }
    return;
  }

  // ---- tsplit4 role (virtual grid 4096: 32x32 tiles x 4 matrices) ----
  const int id = grp * 4 + rem;
  const int z = id >> 10;
  const int rem2 = id & 1023;
  const float* W = (z == 0) ? W0 : (z == 1) ? W1 : (z == 2) ? W2 : W3;
  u16* Wth = (z == 0) ? D0 : (z == 1) ? D1 : (z == 2) ? D2 : D3;
  const float sc = (z == 0) ? sc0 : 1.f;
  const int k0 = (rem2 >> 5) * 64, n0 = (rem2 & 31) * 64;
  const int rr = tid >> 4, cc = (tid & 15) * 4;
#pragma unroll
  for (int u = 0; u < 4; ++u) {
    const float4 v = *(const float4*)&W[(size_t)(k0 + rr + 16 * u) * N + n0 + cc];
    tile[rr + 16 * u][cc + 0] = v.x;
    tile[rr + 16 * u][cc + 1] = v.y;
    tile[rr + 16 * u][cc + 2] = v.z;
    tile[rr + 16 * u][cc + 3] = v.w;
  }
  __syncthreads();
#pragma unroll
  for (int u = 0; u < 4; ++u) {
    const int nn = rr + 16 * u;
    ushort4 h;
    h.x = f2bf(tile[cc + 0][nn] * sc);
    h.y = f2bf(tile[cc + 1][nn] * sc);
    h.z = f2bf(tile[cc + 2][nn] * sc);
    h.w = f2bf(tile[cc + 3][nn] * sc);
    *(ushort4*)&Wth[(size_t)(n0 + nn) * K + k0 + cc] = h;
  }
}

// ---------------------------------------------------------------------------
// 256x128-tile bf16 GEMM, BK=32, ring-3 LDS, counted vmcnt (r18 proven).
// r31: 2x4 rectangle XCD chunking (bijective; needs gy%2==0, gx%4==0 —
// true for all three grids). Balances per-XCD A+B footprint.
// MODE 0: f32 out (+bias[col]*bsc); MODE 2: bf16 out (+bias[row]*bsc);
// MODE 3: merged QK scatter (+bias[col&2047]*bsc or bias2).
// ---------------------------------------------------------------------------
template <int MODE>
__global__ __launch_bounds__(512, 4) void gemm256x128(
    const u16* __restrict__ Ah, const u16* __restrict__ Bth,
    const float* __restrict__ bias, const float* __restrict__ bias2,
    float bsc, u16* __restrict__ outH, u16* __restrict__ outH2,
    float* __restrict__ outF, int MM, int NN, int KK) {
  __shared__ u16 LA[3][8192];   // ring: 256 rows x 32 (64B rows)
  __shared__ u16 LB[3][4096];   // ring: 128 rows x 32

  const int tid = threadIdx.x;
  const int wave = tid >> 6, lane = tid & 63;
  const int g = lane >> 4, q15 = lane & 15;
  const int wr = wave >> 1, wc = wave & 1;     // 4M x 2N
  // 2x4 rectangle XCD chunking: XCD x owns by in [(x>>2)*gh,+gh),
  // bx in [(x&3)*gw,+gw); w = lin>>3 walks the rectangle row-major.
  const int lin = blockIdx.y * gridDim.x + blockIdx.x;
  const int gh = gridDim.y >> 1;
  const int gw = gridDim.x >> 2;
  const int xcd = lin & 7;
  const int w = lin >> 3;
  const int by = (xcd >> 2) * gh + (w / gw);
  const int bx = (xcd & 3) * gw + (w % gw);
  const int m0 = by * 256, n0 = bx * 128;
  const int NT = KK >> 5;
  const int sxg = ((g ^ ((q15 >> 1) & 3)) << 4);

  f32x4 acc[4][4];
#pragma unroll
  for (int f = 0; f < 4; ++f)
#pragma unroll
    for (int j = 0; j < 4; ++j) acc[f][j] = (f32x4){0.f, 0.f, 0.f, 0.f};

  auto stageA = [&](int t, int rbuf) {
#pragma unroll
    for (int l = 0; l < 2; ++l) {
      const int ch = l * 512 + tid;
      const int row = ch >> 2, slot = ch & 3;
      const size_t ga = (size_t)(m0 + row) * KK + t * 32 +
                        ((slot ^ ((row >> 1) & 3)) * 8);
      g2l16(Ah + ga, (char*)(LA[rbuf]) + ch * 16);
    }
  };
  auto stageB = [&](int t, int rbuf) {
    const int ch = tid;
    const int row = ch >> 2, slot = ch & 3;
    const size_t gb = (size_t)(n0 + row) * KK + t * 32 +
                      ((slot ^ ((row >> 1) & 3)) * 8);
    g2l16(Bth + gb, (char*)(LB[rbuf]) + ch * 16);
  };

  // prologue: stage tiles 0,1 (6 ops/thread), drain tile 0 only
  stageA(0, 0); stageB(0, 0);
  __builtin_amdgcn_sched_barrier(0);
  if (NT > 1) { stageA(1, 1); stageB(1, 1); }
  __builtin_amdgcn_sched_barrier(0);
  if (NT > 1) { asm volatile("s_waitcnt vmcnt(3)" ::: "memory"); }
  else        { asm volatile("s_waitcnt vmcnt(0)" ::: "memory"); }
  __builtin_amdgcn_sched_barrier(0);
  __builtin_amdgcn_s_barrier();

  int rb = 0, rb2 = 2;
  for (int t = 0; t < NT; ++t) {
    const char* baseA = (const char*)(LA[rb]);
    const char* baseB = (const char*)(LB[rb]);

    bf16x8 af[4], bf[4];
#pragma unroll
    for (int f = 0; f < 4; ++f)
      af[f] = *(const bf16x8*)(baseA + (wr * 64 + f * 16 + q15) * 64 + sxg);
#pragma unroll
    for (int j = 0; j < 4; ++j)
      bf[j] = *(const bf16x8*)(baseB + (wc * 64 + j * 16 + q15) * 64 + sxg);
    if (t + 2 < NT) { stageA(t + 2, rb2); stageB(t + 2, rb2); }
    __builtin_amdgcn_sched_barrier(0);
    __builtin_amdgcn_s_barrier();
    asm volatile("s_waitcnt lgkmcnt(0)" ::: "memory");
    __builtin_amdgcn_sched_barrier(0);
    __builtin_amdgcn_s_setprio(1);
#pragma unroll
    for (int f = 0; f < 4; ++f)
#pragma unroll
      for (int j = 0; j < 4; ++j)
        acc[f][j] = __builtin_amdgcn_mfma_f32_16x16x32_bf16(
            af[f], bf[j], acc[f][j], 0, 0, 0);
    __builtin_amdgcn_s_setprio(0);
    if (t + 1 < NT) {
      if (t + 2 < NT) { asm volatile("s_waitcnt vmcnt(3)" ::: "memory"); }
      else            { asm volatile("s_waitcnt vmcnt(0)" ::: "memory"); }
    }
    __builtin_amdgcn_sched_barrier(0);
    __builtin_amdgcn_s_barrier();
    rb  = (rb  == 2) ? 0 : rb  + 1;
    rb2 = (rb2 == 2) ? 0 : rb2 + 1;
  }

#pragma unroll
  for (int f = 0; f < 4; ++f)
#pragma unroll
    for (int j = 0; j < 4; ++j)
#pragma unroll
      for (int r = 0; r < 4; ++r) {
        const int row = m0 + wr * 64 + f * 16 + g * 4 + r;
        const int col = n0 + wc * 64 + j * 16 + q15;
        const float v = acc[f][j][r];
        if (MODE == 0) {
          outF[(size_t)row * NN + col] = v + bias[col] * bsc;
        } else if (MODE == 2) {
          outH[(size_t)row * NN + col] = f2bf(v + bias[row] * bsc);
        } else {  // MODE 3: merged QK scatter
          const int sel = col >> 11;
          const int c2 = col & 2047;
          const float vv = v + (sel ? bias2[c2] : bias[c2] * bsc);
          const int bb = row >> 11, tt = row & 2047;
          const int hh = c2 >> 7, dd = c2 & 127;
          (sel ? outH2 : outH)[(((size_t)bb * 16 + hh) * 2048 + tt) * 128 + dd] =
              f2bf(vv);
        }
      }
}

// ---------------------------------------------------------------------------
// Banded split-K flash attention with ALiBi. r27: tile-pair ILP on top of
// the r24/r26 structure (1-wave blocks, XCD-pair decode, uord, setprio,
// K LDS ring-3, V reg-dbuf, counted vmcnt).
// ---------------------------------------------------------------------------
__global__ __launch_bounds__(64) void attn_splitk(
    const u16* __restrict__ Qh, const u16* __restrict__ Kh,
    const u16* __restrict__ Vth, u16* __restrict__ Oh,
    float* __restrict__ Obuf, float* __restrict__ mArr,
    float* __restrict__ lArr, int T, int NB, int BH) {
  __shared__ u16 KS[3][4096];   // 32 x 128, 256B rows, XOR ((row&7)<<4)

  const int tid = threadIdx.x;
  const int lane = tid & 63;
  const int g = lane >> 4, q15 = lane & 15;
  const int L = blockIdx.x;
  // XCD-co-located pair decode: halves are (L, L+8) -> same XCD (mod 8)
  const int LL = (L & 7) | ((L >> 4) << 3);
  const int wid = (L >> 3) & 1;

  int bh, u;
  if (BH == 32) {
    const int k = LL >> 8;       // round 0..5
    const int c = LL & 255;      // CU-slot within round
    bh = (c + 5 * k) & 31;
    u = uord[k * 8 + (c >> 5)];
  } else {
    bh = LL / 48;
    u = uord[LL % 48];
  }
  int s, half;
  if (u < 16)      { s = u;      half = 2; }   // full strip
  else if (u < 32) { s = 47 - u; half = 0; }   // low half (no diagonal)
  else             { s = 63 - u; half = 1; }   // high half (diagonal)

  const int b = bh >> 4, h = bh & 15;
  const float slope2 = exp2f(-0.5f * (float)(h + 1)) * 1.44269504f;
  const int jmin = band_jmin(s, slope2);
  const bool loEmpty = (jmin >= s + 1);

  if (half == 0 && loEmpty) return;            // nothing to do

  int lo, hi;
  if (half == 2)      { lo = jmin;                hi = 2 * s + 2; }
  else if (half == 0) { lo = jmin;                hi = s + 1; }
  else                { lo = loEmpty ? jmin : (s + 1); hi = 2 * s + 2; }
  const int ns = hi - lo;                      // >= 1
  const bool maskable = (half != 0);
  const bool normStore = (half == 2) || (half == 1 && loEmpty);

  const int qw0 = s * 64 + wid * 32;
  const size_t vrow0 = (size_t)h * 128;
  const size_t vcol0 = (size_t)b * T;
  const size_t kbase = (size_t)bh * T;

  // ---- Q loads (8 globals, issued first / oldest in vmcnt order) ----
  bf16x8 qfr[2][4];
#pragma unroll
  for (int qf2 = 0; qf2 < 2; ++qf2) {
    const size_t rb = ((size_t)bh * T + qw0 + qf2 * 16 + q15) * 128;
#pragma unroll
    for (int ks = 0; ks < 4; ++ks)
      qfr[qf2][ks] = *(const bf16x8*)&Qh[rb + ks * 32 + g * 8];
  }

  f32x4 oacc[2][8];
#pragma unroll
  for (int a = 0; a < 2; ++a)
#pragma unroll
    for (int n = 0; n < 8; ++n) oacc[a][n] = (f32x4){0.f, 0.f, 0.f, 0.f};
  float m_st[2] = {-1e5f, -1e5f};
  float l_part[2] = {0.f, 0.f};

  // stage one 32x128 K tile (8KB = 8 chunks of 1KB), all by this wave
  auto stageK = [&](int jt, int bf) {
    const int j0 = jt * 32;
#pragma unroll
    for (int c = 0; c < 8; ++c) {
      const int row = c * 4 + g;
      const int off = (q15 * 16) ^ ((row & 7) << 4);
      const size_t gb = (kbase + j0 + row) * 128;
      g2l16((const char*)(Kh + gb) + off, (char*)(KS[bf]) + c * 1024);
    }
  };
  auto loadV = [&](int jt, bf16x8 (&vf)[8]) {
    const int j0 = jt * 32;
#pragma unroll
    for (int nf = 0; nf < 8; ++nf)
      vf[nf] = *(const bf16x8*)
          &Vth[(vrow0 + nf * 16 + q15) * (size_t)NB + vcol0 + j0 + g * 8];
  };
  // QK^T for one tile from KS[slot] into sacc
  auto QKT = [&](int slot, f32x4 (&sacc)[2][2]) {
#pragma unroll
    for (int jf = 0; jf < 2; ++jf)
#pragma unroll
      for (int qf2 = 0; qf2 < 2; ++qf2) sacc[jf][qf2] = (f32x4){0.f, 0.f, 0.f, 0.f};
#pragma unroll
    for (int ks = 0; ks < 4; ++ks) {
      bf16x8 ka[2];
#pragma unroll
      for (int jf = 0; jf < 2; ++jf) {
        const int row = jf * 16 + q15;
        const int off = (row * 256 + ks * 64 + g * 16) ^ ((row & 7) << 4);
        ka[jf] = *(const bf16x8*)((const char*)(KS[slot]) + off);
      }
#pragma unroll
      for (int jf = 0; jf < 2; ++jf)
#pragma unroll
        for (int qf2 = 0; qf2 < 2; ++qf2)
          sacc[jf][qf2] = __builtin_amdgcn_mfma_f32_16x16x32_bf16(
              ka[jf], qfr[qf2][ks], sacc[jf][qf2], 0, 0, 0);
    }
  };
  // softmax + PV for one tile (no internal waits; V must be drained)
  auto SOFTPV = [&](int it, int j0, f32x4 (&sacc)[2][2], bf16x8 (&vc)[8]) {
    const float jb2 = (float)(j0 + 4 * g - (T - 1));
    unsigned Fw[2][4];
#pragma unroll
    for (int qf2 = 0; qf2 < 2; ++qf2) {
      const int qg = qw0 + qf2 * 16 + q15;
      float sv[2][4];
      float mt = -1e30f;
#pragma unroll
      for (int jf = 0; jf < 2; ++jf)
#pragma unroll
        for (int r = 0; r < 4; ++r) {
          float x = fmaf(slope2, jb2 + (float)(jf * 16 + r), sacc[jf][qf2][r]);
          if (maskable && it < 2) {
            const int jg = j0 + jf * 16 + 4 * g + r;
            x = (jg > qg) ? -1e30f : x;
          }
          sv[jf][r] = x;
          mt = fmaxf(mt, x);
        }
      if (!__all(mt <= m_st[qf2] + 11.0f)) {
        mt = fmaxf(mt, __shfl_xor(mt, 16));
        mt = fmaxf(mt, __shfl_xor(mt, 32));
        const float mnew = fmaxf(m_st[qf2], mt);
        const float scl = exp2f(m_st[qf2] - mnew);
        l_part[qf2] *= scl;
        m_st[qf2] = mnew;
#pragma unroll
        for (int r = 0; r < 4; ++r) {
          const float sc = __shfl(scl, g * 4 + r);
#pragma unroll
          for (int nf = 0; nf < 8; ++nf) oacc[qf2][nf][r] *= sc;
        }
      }
      float rs = 0.f;
      float p[2][4];
#pragma unroll
      for (int jf = 0; jf < 2; ++jf)
#pragma unroll
        for (int r = 0; r < 4; ++r) {
          p[jf][r] = exp2f(sv[jf][r] - m_st[qf2]);
          rs += p[jf][r];
        }
      l_part[qf2] += rs;
      const unsigned W00 = cvtpk(p[0][0], p[0][1]), W01 = cvtpk(p[0][2], p[0][3]);
      const unsigned W10 = cvtpk(p[1][0], p[1][1]), W11 = cvtpk(p[1][2], p[1][3]);
      const int srcA = q15 + ((g & 1) << 5);
      const int srcB = srcA + 16;
      const unsigned A0 = (unsigned)__shfl((int)W00, srcA);
      const unsigned A1 = (unsigned)__shfl((int)W01, srcA);
      const unsigned B0 = (unsigned)__shfl((int)W00, srcB);
      const unsigned B1 = (unsigned)__shfl((int)W01, srcB);
      const unsigned C0 = (unsigned)__shfl((int)W10, srcA);
      const unsigned C1 = (unsigned)__shfl((int)W11, srcA);
      const unsigned D0 = (unsigned)__shfl((int)W10, srcB);
      const unsigned D1 = (unsigned)__shfl((int)W11, srcB);
      const bool hi2 = g >= 2;
      Fw[qf2][0] = hi2 ? C0 : A0;
      Fw[qf2][1] = hi2 ? C1 : A1;
      Fw[qf2][2] = hi2 ? D0 : B0;
      Fw[qf2][3] = hi2 ? D1 : B1;
    }
    union { unsigned uu[4]; bf16x8 v; } pa0, pa1;
#pragma unroll
    for (int w = 0; w < 4; ++w) { pa0.uu[w] = Fw[0][w]; pa1.uu[w] = Fw[1][w]; }
    __builtin_amdgcn_s_setprio(1);
#pragma unroll
    for (int nf = 0; nf < 8; ++nf) {
      oacc[0][nf] = __builtin_amdgcn_mfma_f32_16x16x32_bf16(pa0.v, vc[nf], oacc[0][nf], 0, 0, 0);
      oacc[1][nf] = __builtin_amdgcn_mfma_f32_16x16x32_bf16(pa1.v, vc[nf], oacc[1][nf], 0, 0, 0);
    }
    __builtin_amdgcn_s_setprio(0);
  };

  // ---- prologue: pinned issue order [Q][K0,K1][V0] ----
  bf16x8 vfA[8], vfB[8];
  __builtin_amdgcn_sched_barrier(0);
  stageK(hi - 1, 0);
  if (ns > 1) stageK(hi - 2, 1);
  __builtin_amdgcn_sched_barrier(0);
  loadV(hi - 1, vfA);
  // outstanding: ns>1: Q(8)+K0(8)+K1(8)+V0(8)=32 -> vmcnt(16) drains Q,K0
  //              ns==1: Q(8)+K0(8)+V0(8)=24      -> vmcnt(8)  drains Q,K0
  if (ns > 1) { asm volatile("s_waitcnt vmcnt(16)" ::: "memory"); }
  else        { asm volatile("s_waitcnt vmcnt(8)"  ::: "memory"); }
  __builtin_amdgcn_sched_barrier(0);

  int cur = 0;   // slot of tile it: it % 3

  int it = 0;
  while (it + 2 <= ns) {
    // ---- pair (t0=it, t1=it+1); entry: vfA=V(t0); outstanding {V(t0),K(t0+1)}
    const int jt0 = hi - 1 - it, jt1 = jt0 - 1;
    const int j0a = jt0 * 32, j0b = jt1 * 32;
    const int cur1 = (cur == 2) ? 0 : cur + 1;
    const int cur2 = (cur1 == 2) ? 0 : cur1 + 1;
    const bool e2 = (it + 2 < ns);
    const bool e3 = (it + 3 < ns);

    // sub0 issues: V(t1)->vfB [8], K(t0+2)->cur2 [8 if e2]
    loadV(jt1, vfB);
    if (e2) stageK(jt0 - 2, cur2);
    __builtin_amdgcn_sched_barrier(0);
    if (e2) { asm volatile("s_waitcnt vmcnt(16)" ::: "memory"); }
    else    { asm volatile("s_waitcnt vmcnt(8)"  ::: "memory"); }
    __builtin_amdgcn_sched_barrier(0);

    // QK for BOTH tiles: QK(t1) MFMAs drain under SM(t0)'s VALU below.
    f32x4 sacc0[2][2], sacc1[2][2];
    __builtin_amdgcn_s_setprio(1);
    QKT(cur, sacc0);
    QKT(cur1, sacc1);
    __builtin_amdgcn_s_setprio(0);

    SOFTPV(it, j0a, sacc0, vfA);       // uses V(t0) (drained)

    // sub1 issues (after PV(t0) consumed vfA): V(t0+2)->vfA, K(t0+3)->cur
    if (e2) loadV(jt0 - 2, vfA);
    if (e3) stageK(jt0 - 3, cur);
    __builtin_amdgcn_sched_barrier(0);
    if (e2 && e3)      { asm volatile("s_waitcnt vmcnt(16)" ::: "memory"); }
    else if (e2)       { asm volatile("s_waitcnt vmcnt(8)"  ::: "memory"); }
    else               { asm volatile("s_waitcnt vmcnt(0)"  ::: "memory"); }
    __builtin_amdgcn_sched_barrier(0);

    SOFTPV(it + 1, j0b, sacc1, vfB);   // uses V(t1) (drained)

    cur = cur2;  // cur advanced by 2 (mod 3)
    it += 2;
  }
  if (it < ns) {
    // singleton tail: outstanding {V(it)} (or V0 for ns==1); no prefetch
    const int jt = hi - 1 - it;
    asm volatile("s_waitcnt vmcnt(0)" ::: "memory");
    __builtin_amdgcn_sched_barrier(0);
    f32x4 sacc0[2][2];
    __builtin_amdgcn_s_setprio(1);
    QKT(cur, sacc0);
    __builtin_amdgcn_s_setprio(0);
    SOFTPV(it, jt * 32, sacc0, vfA);
  }

  // ---- epilogue ----
  float lrow[2];
#pragma unroll
  for (int qf2 = 0; qf2 < 2; ++qf2) {
    float lr = l_part[qf2];
    lr += __shfl_xor(lr, 16);
    lr += __shfl_xor(lr, 32);
    lrow[qf2] = lr;
  }

  if (normStore) {
#pragma unroll
    for (int qf2 = 0; qf2 < 2; ++qf2) {
      const float inv = 1.0f / lrow[qf2];
#pragma unroll
      for (int r = 0; r < 4; ++r) {
        const float iv = __shfl(inv, g * 4 + r);
        const int qrow = qw0 + qf2 * 16 + g * 4 + r;
        const size_t ob = ((size_t)b * T + qrow) * 2048 + h * 128;
#pragma unroll
        for (int nf = 0; nf < 8; ++nf)
          Oh[ob + nf * 16 + q15] = f2bf(oacc[qf2][nf][r] * iv);
      }
    }
  } else {
    const int sp = s - 16;
    const size_t sbase = ((size_t)(bh * 16 + sp) * 2 + half) * 64;
    if (g == 0) {
#pragma unroll
      for (int qf2 = 0; qf2 < 2; ++qf2) {
        mArr[sbase + wid * 32 + qf2 * 16 + q15] = m_st[qf2];
        lArr[sbase + wid * 32 + qf2 * 16 + q15] = lrow[qf2];
      }
    }
    const size_t obase = sbase * 128;
#pragma unroll
    for (int qf2 = 0; qf2 < 2; ++qf2)
#pragma unroll
      for (int r = 0; r < 4; ++r) {
        const int row = wid * 32 + qf2 * 16 + g * 4 + r;
#pragma unroll
        for (int nf = 0; nf < 8; ++nf)
          Obuf[obase + (size_t)row * 128 + nf * 16 + q15] = oacc[qf2][nf][r];
      }
  }
}

// ---------------------------------------------------------------------------
// Combine split-K halves; skips strips whose low half was band-empty.
// ---------------------------------------------------------------------------
__global__ __launch_bounds__(128) void combine_halves(
    const float* __restrict__ Obuf, const float* __restrict__ mArr,
    const float* __restrict__ lArr, u16* __restrict__ Oh, int T) {
  const int idx = blockIdx.x;
  const int row = idx & 63;
  const int sp = (idx >> 6) & 15;
  const int bh = idx >> 10;
  const int d = threadIdx.x;
  const int s = sp + 16;
  const int b = bh >> 4, h = bh & 15;
  const float slope2 = exp2f(-0.5f * (float)(h + 1)) * 1.44269504f;
  if (band_jmin(s, slope2) >= s + 1) return;   // high half stored directly
  const size_t sbase = ((size_t)(bh * 16 + sp) * 2) * 64;
  const float m1 = mArr[sbase + row],      l1 = lArr[sbase + row];
  const float m2 = mArr[sbase + 64 + row], l2 = lArr[sbase + 64 + row];
  const float M = fmaxf(m1, m2);
  const float w1 = exp2f(m1 - M), w2 = exp2f(m2 - M);
  const float inv = 1.0f / (l1 * w1 + l2 * w2);
  const size_t ob = sbase * 128;
  const float o1 = Obuf[ob + (size_t)row * 128 + d];
  const float o2 = Obuf[ob + 8192 + (size_t)row * 128 + d];
  const float v = (o1 * w1 + o2 * w2) * inv;
  const int qrow = s * 64 + row;
  Oh[((size_t)b * T + qrow) * 2048 + h * 128 + d] = f2bf(v);
}

// ============================================================================
// Fallback f32 path (round-0, proven): used only if ws_size is insufficient.
// ============================================================================
#define TM 128
#define BKG 8

template <int QKV>
__global__ __launch_bounds__(256) void gemm_f32(
    const float* __restrict__ A, const float* __restrict__ W,
    const float* __restrict__ bias, float* __restrict__ out,
    int M, int N, int K, int T) {
  __shared__ float As[BKG][TM];
  __shared__ float Bs[BKG][TM];
  const int tid = threadIdx.x;
  const int tx = tid & 15, ty = tid >> 4;
  const int m0 = blockIdx.y * TM, n0 = blockIdx.x * TM;
  float acc[8][8];
#pragma unroll
  for (int i = 0; i < 8; ++i)
#pragma unroll
    for (int j = 0; j < 8; ++j) acc[i][j] = 0.f;
  const int arow = tid >> 1, acol = (tid & 1) * 4;
  const int brow = tid >> 5, bcol = (tid & 31) * 4;
  for (int k0 = 0; k0 < K; k0 += BKG) {
    const float4 av = *(const float4*)&A[(size_t)(m0 + arow) * K + k0 + acol];
    const float4 bv = *(const float4*)&W[(size_t)(k0 + brow) * N + n0 + bcol];
    __syncthreads();
    As[acol + 0][arow] = av.x; As[acol + 1][arow] = av.y;
    As[acol + 2][arow] = av.z; As[acol + 3][arow] = av.w;
    *(float4*)&Bs[brow][bcol] = bv;
    __syncthreads();
#pragma unroll
    for (int kk = 0; kk < BKG; ++kk) {
      const float4 a0 = *(const float4*)&As[kk][ty * 4];
      const float4 a1 = *(const float4*)&As[kk][64 + ty * 4];
      const float4 b0 = *(const float4*)&Bs[kk][tx * 4];
      const float4 b1 = *(const float4*)&Bs[kk][64 + tx * 4];
      const float af[8] = {a0.x, a0.y, a0.z, a0.w, a1.x, a1.y, a1.z, a1.w};
      const float bf[8] = {b0.x, b0.y, b0.z, b0.w, b1.x, b1.y, b1.z, b1.w};
#pragma unroll
      for (int i = 0; i < 8; ++i)
#pragma unroll
        for (int j = 0; j < 8; ++j) acc[i][j] += af[i] * bf[j];
    }
  }
#pragma unroll
  for (int a = 0; a < 2; ++a)
#pragma unroll
    for (int i = 0; i < 4; ++i) {
      const int row = m0 + a * 64 + ty * 4 + i;
      const int bb = row / T, t = row % T;
#pragma unroll
      for (int bj = 0; bj < 2; ++bj) {
        const int col = n0 + bj * 64 + tx * 4;
        float4 r;
        r.x = acc[a * 4 + i][bj * 4 + 0] + bias[col + 0];
        r.y = acc[a * 4 + i][bj * 4 + 1] + bias[col + 1];
        r.z = acc[a * 4 + i][bj * 4 + 2] + bias[col + 2];
        r.w = acc[a * 4 + i][bj * 4 + 3] + bias[col + 3];
        if (QKV) {
          const int hh = col >> 7, dd = col & 127;
          *(float4*)&out[(((size_t)bb * 16 + hh) * T + t) * 128 + dd] = r;
        } else {
          *(float4*)&out[(size_t)row * N + col] = r;
        }
      }
    }
}

#define QT 32
#define KT 32
#define DP 132

__global__ __launch_bounds__(256) void flash_f32(
    const float* __restrict__ Q, const float* __restrict__ K,
    const float* __restrict__ V, float* __restrict__ O, int T) {
  __shared__ float Qs[QT][DP];
  __shared__ float Ks[KT][DP];
  __shared__ float Vs[KT][DP];
  __shared__ float Ps[QT][KT + 1];
  const int tid = threadIdx.x;
  const int jh = tid & 15, ih = tid >> 4;
  const int bh = blockIdx.y;
  const int h = bh & 15;
  const int q0 = blockIdx.x * QT;
  const float slope = exp2f(-0.5f * (float)(h + 1));
  const float rsD = 0.08838834764831845f;
  {
    const float* Qg = Q + ((size_t)bh * T + q0) * 128;
    const int r = tid >> 3, p = tid & 7;
#pragma unroll
    for (int u = 0; u < 4; ++u)
      *(float4*)&Qs[r][(p + 8 * u) * 4] = *(const float4*)&Qg[r * 128 + (p + 8 * u) * 4];
  }
  float m_st[2] = {-1e30f, -1e30f};
  float l_st[2] = {0.f, 0.f};
  float accv[2][8] = {};
  const int ktiles = blockIdx.x + 1;
  for (int kt = 0; kt < ktiles; ++kt) {
    const int j0 = kt * KT;
    const float* Kg = K + ((size_t)bh * T + j0) * 128;
    const float* Vg = V + ((size_t)bh * T + j0) * 128;
    __syncthreads();
    {
      const int r = tid >> 3, p = tid & 7;
#pragma unroll
      for (int u = 0; u < 4; ++u) {
        *(float4*)&Ks[r][(p + 8 * u) * 4] = *(const float4*)&Kg[r * 128 + (p + 8 * u) * 4];
        *(float4*)&Vs[r][(p + 8 * u) * 4] = *(const float4*)&Vg[r * 128 + (p + 8 * u) * 4];
      }
    }
    __syncthreads();
    float s00 = 0.f, s01 = 0.f, s10 = 0.f, s11 = 0.f;
#pragma unroll 8
    for (int d4 = 0; d4 < 32; ++d4) {
      const float4 qa = *(const float4*)&Qs[2 * ih + 0][4 * d4];
      const float4 qb = *(const float4*)&Qs[2 * ih + 1][4 * d4];
      const float4 ka = *(const float4*)&Ks[2 * jh + 0][4 * d4];
      const float4 kb = *(const float4*)&Ks[2 * jh + 1][4 * d4];
      s00 += qa.x * ka.x + qa.y * ka.y + qa.z * ka.z + qa.w * ka.w;
      s01 += qa.x * kb.x + qa.y * kb.y + qa.z * kb.z + qa.w * kb.w;
      s10 += qb.x * ka.x + qb.y * ka.y + qb.z * ka.z + qb.w * ka.w;
      s11 += qb.x * kb.x + qb.y * kb.y + qb.z * kb.z + qb.w * kb.w;
    }
    float sc[2][2] = {{s00, s01}, {s10, s11}};
    float mt[2];
#pragma unroll
    for (int r = 0; r < 2; ++r) {
      const int qg = q0 + 2 * ih + r;
#pragma unroll
      for (int c = 0; c < 2; ++c) {
        const int jg = j0 + 2 * jh + c;
        const float svv = sc[r][c] * rsD + slope * (float)(jg - (T - 1));
        sc[r][c] = (jg > qg) ? -1e30f : svv;
      }
      mt[r] = fmaxf(sc[r][0], sc[r][1]);
    }
#pragma unroll
    for (int m = 1; m < 16; m <<= 1) {
      mt[0] = fmaxf(mt[0], __shfl_xor(mt[0], m));
      mt[1] = fmaxf(mt[1], __shfl_xor(mt[1], m));
    }
#pragma unroll
    for (int r = 0; r < 2; ++r) {
      const float mnew = fmaxf(m_st[r], mt[r]);
      const float scl = (m_st[r] > -1e29f) ? expf(m_st[r] - mnew) : 0.f;
      const float p0 = expf(sc[r][0] - mnew);
      const float p1 = expf(sc[r][1] - mnew);
      float rs = p0 + p1;
#pragma unroll
      for (int m = 1; m < 16; m <<= 1) rs += __shfl_xor(rs, m);
      l_st[r] = l_st[r] * scl + rs;
      m_st[r] = mnew;
#pragma unroll
      for (int d = 0; d < 8; ++d) accv[r][d] *= scl;
      Ps[2 * ih + r][2 * jh + 0] = p0;
      Ps[2 * ih + r][2 * jh + 1] = p1;
    }
    __syncthreads();
#pragma unroll 4
    for (int j = 0; j < KT; ++j) {
      const float p0 = Ps[2 * ih + 0][j];
      const float p1 = Ps[2 * ih + 1][j];
      const float4 v0 = *(const float4*)&Vs[j][8 * jh];
      const float4 v1 = *(const float4*)&Vs[j][8 * jh + 4];
      accv[0][0] += p0 * v0.x; accv[0][1] += p0 * v0.y;
      accv[0][2] += p0 * v0.z; accv[0][3] += p0 * v0.w;
      accv[0][4] += p0 * v1.x; accv[0][5] += p0 * v1.y;
      accv[0][6] += p0 * v1.z; accv[0][7] += p0 * v1.w;
      accv[1][0] += p1 * v0.x; accv[1][1] += p1 * v0.y;
      accv[1][2] += p1 * v0.z; accv[1][3] += p1 * v0.w;
      accv[1][4] += p1 * v1.x; accv[1][5] += p1 * v1.y;
      accv[1][6] += p1 * v1.z; accv[1][7] += p1 * v1.w;
    }
  }
  const int b = bh >> 4;
#pragma unroll
  for (int r = 0; r < 2; ++r) {
    const int qg = q0 + 2 * ih + r;
    const float inv = 1.0f / l_st[r];
    float4 o0, o1;
    o0.x = accv[r][0] * inv; o0.y = accv[r][1] * inv;
    o0.z = accv[r][2] * inv; o0.w = accv[r][3] * inv;
    o1.x = accv[r][4] * inv; o1.y = accv[r][5] * inv;
    o1.z = accv[r][6] * inv; o1.w = accv[r][7] * inv;
    float* dst = O + ((size_t)b * T + qg) * 2048 + h * 128 + 8 * jh;
    *(float4*)&dst[0] = o0;
    *(float4*)&dst[4] = o1;
  }
}

// ============================================================================
extern "C" void kernel_launch(void* const* d_in, const int* in_sizes, int n_in,
                              void* d_out, int out_size, void* d_ws,
                              size_t ws_size, hipStream_t stream) {
  const float* x  = (const float*)d_in[0];
  const float* Wq = (const float*)d_in[1];
  const float* bq = (const float*)d_in[2];
  const float* Wk = (const float*)d_in[3];
  const float* bk = (const float*)d_in[4];
  const float* Wv = (const float*)d_in[5];
  const float* bv = (const float*)d_in[6];
  const float* Wo = (const float*)d_in[7];
  const float* bo = (const float*)d_in[8];
  float* out = (float*)d_out;

  const int C = 2048, T = 2048, H = 16;
  const int M = in_sizes[0] / C;  // B*T
  const int B = M / T;
  const int BH = B * H;
  const size_t MC = (size_t)M * C, CC = (size_t)C * C;
  const size_t splitO = (size_t)BH * 16 * 2 * 8192;        // f32 elems
  const size_t splitML = (size_t)BH * 16 * 2 * 64;         // f32 elems
  const size_t need = (5 * MC + 4 * CC) * sizeof(u16) +
                      (splitO + 2 * splitML) * sizeof(float);

  // rsD * log2(e): puts QK^T logits in exp2 domain
  const float QSC = 0.08838834764831845f * 1.44269504088896f;

  if (ws_size >= need && (M % 256) == 0) {
    u16* p = (u16*)d_ws;
    u16* xh   = p; p += MC;
    u16* wqth = p; p += CC;   // wqth/wkth contiguous -> merged QK GEMM
    u16* wkth = p; p += CC;
    u16* wvth = p; p += CC;
    u16* woth = p; p += CC;
    u16* qh   = p; p += MC;
    u16* kh   = p; p += MC;
    u16* vth  = p; p += MC;
    u16* oh   = p; p += MC;
    float* Obuf = (float*)p;
    float* mArr = Obuf + splitO;
    float* lArr = mArr + splitML;

    // fused preprocessing: x cast + 4x weight transpose/cast, one dispatch
    prep_all<<<5120, 256, 0, stream>>>(x, xh, (int)(MC / 4),
                                       Wq, Wk, Wv, Wo, wqth, wkth, wvth,
                                       woth, C, C, QSC);

    // merged Q+K projection: [M x 4096] = xh @ [wqth|wkth]^T
    // 256x128 tiles -> (32,16) = 512 blocks -> 2 blocks/CU, rect-swizzled
    dim3 gqk(2 * C / 128, M / 256);
    gemm256x128<3><<<gqk, 512, 0, stream>>>(xh, wqth, bq, bk, QSC, qh, kh,
                                            nullptr, M, 2 * C, C);
    // V^T = Wv^T @ x^T : out [C][M] (+bv by row) — (32,8) = 256 blocks
    dim3 gv(M / 128, C / 256);
    gemm256x128<2><<<gv, 512, 0, stream>>>(wvth, xh, bv, nullptr, 1.f, vth,
                                           nullptr, nullptr, C, M, C);

    attn_splitk<<<96 * BH, 64, 0, stream>>>(qh, kh, vth, oh, Obuf, mArr,
                                            lArr, T, M, BH);
    combine_halves<<<BH * 16 * 64, 128, 0, stream>>>(Obuf, mArr, lArr, oh, T);

    // final o @ Wo — (16,16) = 256 blocks
    dim3 gq(C / 128, M / 256);
    gemm256x128<0><<<gq, 512, 0, stream>>>(oh, woth, bo, nullptr, 1.f,
                                           nullptr, nullptr, out, M, C, C);
  } else {
    // f32 fallback (round-0 path)
    float* Qw = (float*)d_ws;
    float* Kw = Qw + MC;
    float* Vw = Kw + MC;
    float* Ow = Vw + MC;
    dim3 ggrid(C / TM, M / TM);
    gemm_f32<1><<<ggrid, 256, 0, stream>>>(x, Wq, bq, Qw, M, C, C, T);
    gemm_f32<1><<<ggrid, 256, 0, stream>>>(x, Wk, bk, Kw, M, C, C, T);
    gemm_f32<1><<<ggrid, 256, 0, stream>>>(x, Wv, bv, Vw, M, C, C, T);
    dim3 fgrid(T / QT, B * H);
    flash_f32<<<fgrid, 256, 0, stream>>>(Qw, Kw, Vw, Ow, T);
    gemm_f32<0><<<ggrid, 256, 0, stream>>>(Ow, Wo, bo, out, M, C, C, T);
  }
}